// Round 5
// baseline (2567.768 us; speedup 1.0000x reference)
//
#include <hip/hip_runtime.h>

#define DF 128
#define NGRAPH 8

typedef __attribute__((ext_vector_type(8))) short bf16x8;
typedef __attribute__((ext_vector_type(4))) float f32x4;

constexpr unsigned ENC_NEGINF = 0x007FFFFFu;  // enc(-inf)

__device__ __forceinline__ unsigned enc_f(float f) {
  unsigned u = __float_as_uint(f);
  return (u & 0x80000000u) ? ~u : (u | 0x80000000u);
}
__device__ __forceinline__ float dec_f(unsigned k) {
  unsigned u = (k & 0x80000000u) ? (k & 0x7FFFFFFFu) : ~k;
  return __uint_as_float(u);
}
__device__ __forceinline__ float sigm(float x) { return 1.f / (1.f + __expf(-x)); }
__device__ __forceinline__ unsigned short f2bf(float f) {  // RNE f32->bf16
  unsigned u = __float_as_uint(f);
  u += 0x7FFFu + ((u >> 16) & 1u);
  return (unsigned short)(u >> 16);
}
__device__ __forceinline__ float bf2f(unsigned short u) {
  return __uint_as_float(((unsigned)u) << 16);
}

// load 8 consecutive f32 (32B-aligned) -> bf16x8
__device__ __forceinline__ bf16x8 cvt8(const float* __restrict__ p) {
  float4 a = *(const float4*)p;
  float4 b = *(const float4*)(p + 4);
  bf16x8 r;
  r[0] = (short)f2bf(a.x); r[1] = (short)f2bf(a.y);
  r[2] = (short)f2bf(a.z); r[3] = (short)f2bf(a.w);
  r[4] = (short)f2bf(b.x); r[5] = (short)f2bf(b.y);
  r[6] = (short)f2bf(b.z); r[7] = (short)f2bf(b.w);
  return r;
}

// ---------------- generic fill ----------------
__global__ void k_fill_u32(unsigned* __restrict__ p, unsigned v, long long n) {
  long long i = (long long)blockIdx.x * blockDim.x + threadIdx.x;
  long long st = (long long)gridDim.x * blockDim.x;
  for (; i < n; i += st) p[i] = v;
}

// ---------------- weight pre-conversion to MFMA fragment order ----------------
// slot s in [0, 8*nks*64): ct=s/(nks*64), ks=(s/64)%nks, l=s&63
// holds W[ct*16+(l&15)][ks*32+(l>>4)*8 .. +8] as bf16x8
__global__ __launch_bounds__(512) void k_wconv(
    const float* __restrict__ Us, const float* __restrict__ Vs,
    const float* __restrict__ As, const float* __restrict__ Bs,
    const float* __restrict__ Cs, const float* __restrict__ gsw,
    const float* __restrict__ gdw, const float* __restrict__ Ow,
    short* __restrict__ out) {
  int b = blockIdx.x;
  const float* W;
  if (b < 3) W = Us + b * 16384;
  else if (b < 6) W = Vs + (b - 3) * 16384;
  else if (b < 9) W = As + (b - 6) * 16384;
  else if (b < 12) W = Bs + (b - 9) * 16384;
  else if (b < 15) W = Cs + (b - 12) * 16384;
  else if (b == 15) W = gsw;
  else if (b == 16) W = gdw;
  else W = Ow;
  short* o = out + (size_t)b * 2048 * 8;
  for (int s = threadIdx.x; s < 2048; s += 512) {
    int ct = s >> 8, ks = (s >> 6) & 3, l = s & 63;
    int row = ct * 16 + (l & 15), k0 = ks * 32 + (l >> 4) * 8;
    *(bf16x8*)&o[s * 8] = cvt8(W + (size_t)row * DF + k0);
  }
}

__global__ __launch_bounds__(512) void k_wconv_w1(const float* __restrict__ W1,
                                                  short* __restrict__ out) {
  int s = blockIdx.x * 512 + threadIdx.x;  // grid 12 -> 6144 slots
  int ct = s / 768, ks = (s >> 6) % 12, l = s & 63;
  int row = ct * 16 + (l & 15), k0 = ks * 32 + (l >> 4) * 8;
  *(bf16x8*)&out[(size_t)s * 8] = cvt8(W1 + (size_t)row * 384 + k0);
}

// ---------------- embeddings ----------------
__global__ __launch_bounds__(128) void k_node_embed(
    const float* __restrict__ hin, const float* __restrict__ w,
    const float* __restrict__ b, float* __restrict__ h0, int rows) {
  __shared__ float Wt[64 * DF];
  __shared__ float ar[4][64];
  int tid = threadIdx.x;
  for (int i = tid; i < 64 * DF; i += 128) Wt[(i & 63) * DF + (i >> 6)] = w[i];
  float bb = b[tid];
  __syncthreads();
  for (int r0 = blockIdx.x * 4; r0 < rows; r0 += gridDim.x * 4) {
    for (int i = tid; i < 256; i += 128) ar[i >> 6][i & 63] = hin[(size_t)r0 * 64 + i];
    __syncthreads();
    float a0 = bb, a1 = bb, a2 = bb, a3 = bb;
#pragma unroll 8
    for (int k = 0; k < 64; ++k) {
      float wv = Wt[k * DF + tid];
      a0 = fmaf(ar[0][k], wv, a0); a1 = fmaf(ar[1][k], wv, a1);
      a2 = fmaf(ar[2][k], wv, a2); a3 = fmaf(ar[3][k], wv, a3);
    }
    h0[(size_t)r0 * DF + tid] = a0;
    h0[(size_t)(r0 + 1) * DF + tid] = a1;
    h0[(size_t)(r0 + 2) * DF + tid] = a2;
    h0[(size_t)(r0 + 3) * DF + tid] = a3;
    __syncthreads();
  }
}

__global__ __launch_bounds__(128) void k_edge_embed(
    const float* __restrict__ ein, const float* __restrict__ w,
    const float* __restrict__ b, unsigned short* __restrict__ e0u, int rows) {
  __shared__ float Wt[16 * DF];
  __shared__ float ar[4][16];
  int tid = threadIdx.x;
  for (int i = tid; i < 16 * DF; i += 128) Wt[(i & 15) * DF + (i >> 4)] = w[i];
  float bb = b[tid];
  __syncthreads();
  for (int r0 = blockIdx.x * 4; r0 < rows; r0 += gridDim.x * 4) {
    if (tid < 64) ar[tid >> 4][tid & 15] = ein[(size_t)r0 * 16 + tid];
    __syncthreads();
    float a0 = bb, a1 = bb, a2 = bb, a3 = bb;
#pragma unroll
    for (int k = 0; k < 16; ++k) {
      float wv = Wt[k * DF + tid];
      a0 = fmaf(ar[0][k], wv, a0); a1 = fmaf(ar[1][k], wv, a1);
      a2 = fmaf(ar[2][k], wv, a2); a3 = fmaf(ar[3][k], wv, a3);
    }
    e0u[(size_t)r0 * DF + tid] = f2bf(a0);
    e0u[(size_t)(r0 + 1) * DF + tid] = f2bf(a1);
    e0u[(size_t)(r0 + 2) * DF + tid] = f2bf(a2);
    e0u[(size_t)(r0 + 3) * DF + tid] = f2bf(a3);
    __syncthreads();
  }
}

// ---------------- MFMA [rows,128] @ W^T (+bias), frag weights ----------------
template <int OUTBF>
__global__ __launch_bounds__(512) void k_gemm_mfma(
    const float* __restrict__ A, const short* __restrict__ Wf,
    const float* __restrict__ bias, void* __restrict__ outv, int rows) {
  __shared__ short Wb[2048 * 8];  // 32 KB
  int tid = threadIdx.x;
  for (int s = tid; s < 2048; s += 512)
    *(bf16x8*)&Wb[s * 8] = *(const bf16x8*)&Wf[(size_t)s * 8];
  __syncthreads();
  float* outf = (float*)outv;
  unsigned short* outb = (unsigned short*)outv;
  int wid = tid >> 6, lane = tid & 63, q = lane >> 4, m = lane & 15;
  int ntiles = (rows + 127) >> 7;
  for (int t = blockIdx.x; t < ntiles; t += gridDim.x) {
    int r0 = t * 128 + wid * 16;
    int rr = r0 + m;
    if (rr >= rows) rr = rows - 1;
    const float* ap = A + (size_t)rr * DF + q * 8;
    bf16x8 a[4];
#pragma unroll
    for (int ks = 0; ks < 4; ++ks) a[ks] = cvt8(ap + 32 * ks);
#pragma unroll
    for (int ct = 0; ct < 8; ++ct) {
      f32x4 acc = {0.f, 0.f, 0.f, 0.f};
#pragma unroll
      for (int ks = 0; ks < 4; ++ks) {
        bf16x8 b = *(const bf16x8*)&Wb[((ct * 4 + ks) * 64 + lane) * 8];
        acc = __builtin_amdgcn_mfma_f32_16x16x32_bf16(a[ks], b, acc, 0, 0, 0);
      }
      int col = ct * 16 + m;
      float bb = bias ? bias[col] : 0.f;
#pragma unroll
      for (int j = 0; j < 4; ++j) {
        int row = r0 + q * 4 + j;
        if (row < rows) {
          if (OUTBF) outb[(size_t)row * DF + col] = f2bf(acc[j] + bb);
          else outf[(size_t)row * DF + col] = acc[j] + bb;
        }
      }
    }
  }
}

// ---------------- fused 4-output node GEMM (V,U,B,C) ----------------
__global__ __launch_bounds__(512) void k_gemm4_mfma(
    const float* __restrict__ h0, const short* __restrict__ Vf,
    const short* __restrict__ Uf, const short* __restrict__ Bf,
    const short* __restrict__ Cf, unsigned short* __restrict__ hVb,
    float* __restrict__ hU, unsigned short* __restrict__ hBb,
    unsigned short* __restrict__ hCb, int rows) {
  __shared__ short Wl[4 * 2048 * 8];  // 128 KB
  int tid = threadIdx.x;
  for (int s = tid; s < 2048; s += 512) {
    *(bf16x8*)&Wl[(size_t)s * 8] = *(const bf16x8*)&Vf[(size_t)s * 8];
    *(bf16x8*)&Wl[(size_t)(2048 + s) * 8] = *(const bf16x8*)&Uf[(size_t)s * 8];
    *(bf16x8*)&Wl[(size_t)(4096 + s) * 8] = *(const bf16x8*)&Bf[(size_t)s * 8];
    *(bf16x8*)&Wl[(size_t)(6144 + s) * 8] = *(const bf16x8*)&Cf[(size_t)s * 8];
  }
  __syncthreads();
  int wid = tid >> 6, lane = tid & 63, q = lane >> 4, m = lane & 15;
  int ntiles = (rows + 127) >> 7;
  for (int t = blockIdx.x; t < ntiles; t += gridDim.x) {
    int r0 = t * 128 + wid * 16;
    int rr = r0 + m;
    if (rr >= rows) rr = rows - 1;
    const float* ap = h0 + (size_t)rr * DF + q * 8;
    bf16x8 a[4];
#pragma unroll
    for (int ks = 0; ks < 4; ++ks) a[ks] = cvt8(ap + 32 * ks);
#pragma unroll
    for (int w = 0; w < 4; ++w) {
#pragma unroll
      for (int ct = 0; ct < 8; ++ct) {
        f32x4 acc = {0.f, 0.f, 0.f, 0.f};
#pragma unroll
        for (int ks = 0; ks < 4; ++ks) {
          bf16x8 b = *(const bf16x8*)&Wl[((w * 2048) + (ct * 4 + ks) * 64 + lane) * 8];
          acc = __builtin_amdgcn_mfma_f32_16x16x32_bf16(a[ks], b, acc, 0, 0, 0);
        }
        int col = ct * 16 + m;
#pragma unroll
        for (int j = 0; j < 4; ++j) {
          int row = r0 + q * 4 + j;
          if (row < rows) {
            if (w == 1) hU[(size_t)row * DF + col] = acc[j];
            else {
              unsigned short v = f2bf(acc[j]);
              unsigned short* o = (w == 0) ? hVb : ((w == 2) ? hBb : hCb);
              o[(size_t)row * DF + col] = v;
            }
          }
        }
      }
    }
  }
}

// ---------------- MFMA edge pass (graph-local): x = e@As^T + hB[dst] + hC[src] ----------------
template <int APPLY>
__global__ __launch_bounds__(512) void k_edge_mfma(
    unsigned short* __restrict__ e0u, const short* __restrict__ Af,
    const unsigned short* __restrict__ hBb, const unsigned short* __restrict__ hCb,
    const int* __restrict__ src, const int* __restrict__ dst,
    float* __restrict__ stat, int Eg) {
  __shared__ short Wb[2048 * 8];     // 32 KB
  __shared__ float xt[8][16 * 132];  // 66 KB
  int tid = threadIdx.x;
  for (int s = tid; s < 2048; s += 512)
    *(bf16x8*)&Wb[s * 8] = *(const bf16x8*)&Af[(size_t)s * 8];
  int wid = tid >> 6, lane = tid & 63, q = lane >> 4, m = lane & 15;
  int g = blockIdx.x & 7, sub = blockIdx.x >> 3, nsub = gridDim.x >> 3;
  int gbase = g * Eg, gend = gbase + Eg;
  int tpg = (Eg + 127) >> 7;
  float* xw = xt[wid];
  float ps0 = 0.f, ps1 = 0.f, pq0 = 0.f, pq1 = 0.f;
  __syncthreads();
  for (int t = sub; t < tpg; t += nsub) {
    int r0 = gbase + t * 128 + wid * 16;
    int edge = r0 + m;
    bool ok = edge < gend;
    int ec = ok ? edge : gend - 1;
    const unsigned short* ep = e0u + (size_t)ec * DF + q * 8;
    bf16x8 a[4];
#pragma unroll
    for (int ks = 0; ks < 4; ++ks) a[ks] = *(const bf16x8*)(ep + 32 * ks);
#pragma unroll
    for (int ct = 0; ct < 8; ++ct) {
      f32x4 acc = {0.f, 0.f, 0.f, 0.f};
#pragma unroll
      for (int ks = 0; ks < 4; ++ks) {
        bf16x8 b = *(const bf16x8*)&Wb[((ct * 4 + ks) * 64 + lane) * 8];
        acc = __builtin_amdgcn_mfma_f32_16x16x32_bf16(a[ks], b, acc, 0, 0, 0);
      }
#pragma unroll
      for (int j = 0; j < 4; ++j) xw[(q * 4 + j) * 132 + ct * 16 + m] = acc[j];
    }
    __syncthreads();
    int sidx = src[ec], didx = dst[ec];
    const unsigned short* pb = hBb + (size_t)didx * DF;
    const unsigned short* pc = hCb + (size_t)sidx * DF;
#pragma unroll
    for (int ks = 0; ks < 4; ++ks) {
      int c0 = q * 8 + 32 * ks;
      float* xp = &xw[m * 132 + c0];
      bf16x8 gb = *(const bf16x8*)(pb + c0);
      bf16x8 gc = *(const bf16x8*)(pc + c0);
      float x[8];
#pragma unroll
      for (int i = 0; i < 8; ++i)
        x[i] = xp[i] + bf2f((unsigned short)gb[i]) + bf2f((unsigned short)gc[i]);
      if (APPLY) {
        bf16x8 nv;
#pragma unroll
        for (int i = 0; i < 8; ++i) {
          float mm = stat[768 + c0 + i], iv = stat[896 + c0 + i];
          nv[i] = (short)f2bf(bf2f((unsigned short)a[ks][i]) + fmaxf((x[i] - mm) * iv, 0.f));
        }
        if (ok) *(bf16x8*)(e0u + (size_t)ec * DF + c0) = nv;
      } else {
#pragma unroll
        for (int i = 0; i < 8; ++i) xp[i] = ok ? x[i] : 0.f;
      }
    }
    if (!APPLY) {
      __syncthreads();
#pragma unroll 4
      for (int r = 0; r < 16; ++r) {
        float2 v = *(float2*)&xw[r * 132 + 2 * lane];
        ps0 += v.x; ps1 += v.y;
        pq0 += v.x * v.x; pq1 += v.y * v.y;
      }
    }
    __syncthreads();
  }
  if (!APPLY) {
    atomicAdd(&stat[512 + 2 * lane], ps0);
    atomicAdd(&stat[512 + 2 * lane + 1], ps1);
    atomicAdd(&stat[640 + 2 * lane], pq0);
    atomicAdd(&stat[640 + 2 * lane + 1], pq1);
  }
}

// ---------------- layer: m = hV[src]*sigmoid(e); segment_max (graph-local) ----------------
__global__ __launch_bounds__(256) void k_edge_max(
    const unsigned short* __restrict__ hVb, const unsigned short* __restrict__ e0u,
    const int* __restrict__ src, const int* __restrict__ dst,
    unsigned* __restrict__ agg_u, int Eg) {
  int g = blockIdx.x & 7, sub = blockIdx.x >> 3, nsub = gridDim.x >> 3;
  int gbase = g * Eg, gend = gbase + Eg;
  int tpg = (Eg + 127) >> 7;
  int tid = threadIdx.x;
  for (int t = sub; t < tpg; t += nsub) {
    int ebase = gbase + t * 128;
    for (int k = tid; k < 16384; k += 256) {
      int e = ebase + (k >> 7);
      if (e >= gend) break;
      int d = k & 127;
      float mm = bf2f(hVb[(size_t)src[e] * DF + d]) * sigm(bf2f(e0u[(size_t)e * DF + d]));
      atomicMax(&agg_u[(size_t)dst[e] * DF + d], enc_f(mm));
    }
  }
}

// tmp_h = hU + decode(agg); accumulate node BN stats
__global__ __launch_bounds__(128) void k_node_pre_bn(
    float* __restrict__ hU, const unsigned* __restrict__ agg_u,
    float* __restrict__ stat, int rows) {
  int tid = threadIdx.x;
  float ps = 0.f, pq = 0.f;
  for (int n = blockIdx.x; n < rows; n += gridDim.x) {
    size_t idx = (size_t)n * DF + tid;
    unsigned k = agg_u[idx];
    float a = (k == ENC_NEGINF) ? 0.f : dec_f(k);
    float t = hU[idx] + a;
    hU[idx] = t;
    ps += t; pq += t * t;
  }
  atomicAdd(&stat[tid], ps);
  atomicAdd(&stat[128 + tid], pq);
}

// finalize BN stats
__global__ void k_bn_finalize(float* __restrict__ stat, float nN, float nE) {
  int tid = threadIdx.x;
  if (tid < 128) {
    float mean = stat[tid] / nN;
    float var = stat[128 + tid] / nN - mean * mean;
    stat[256 + tid] = mean;
    stat[384 + tid] = rsqrtf(fmaxf(var, 0.f) + 1e-5f);
  } else {
    int d = tid - 128;
    float mean = stat[512 + d] / nE;
    float var = stat[640 + d] / nE - mean * mean;
    stat[768 + d] = mean;
    stat[896 + d] = rsqrtf(fmaxf(var, 0.f) + 1e-5f);
  }
}

__global__ __launch_bounds__(256) void k_node_update(
    float* __restrict__ h0, const float* __restrict__ hU,
    const float* __restrict__ stat, long long total) {
  long long i = (long long)blockIdx.x * blockDim.x + threadIdx.x;
  long long st = (long long)gridDim.x * blockDim.x;
  for (; i < total; i += st) {
    int d = (int)(i & 127);
    float t = (hU[i] - stat[256 + d]) * stat[384 + d];
    h0[i] += fmaxf(t, 0.f);
  }
}

// ---------------- GATv2 (graph-local) ----------------
__global__ __launch_bounds__(256) void k_gat_score(
    const unsigned short* __restrict__ fsb, const unsigned short* __restrict__ fdb,
    const int* __restrict__ src, const int* __restrict__ dst,
    const float* __restrict__ attn, float* __restrict__ score,
    unsigned* __restrict__ smax_u, int Eg) {
  int g = blockIdx.x & 7, sub = blockIdx.x >> 3, nsub = gridDim.x >> 3;
  int gbase = g * Eg, gend = gbase + Eg;
  int tpg = (Eg + 127) >> 7;
  int tid = threadIdx.x;
  for (int t = sub; t < tpg; t += nsub) {
    int ebase = gbase + t * 128;
    for (int k = tid; k < 1024; k += 256) {
      int e = ebase + (k >> 3);
      if (e >= gend) break;
      int mh = k & 7;
      int s = src[e], dn = dst[e];
      const unsigned short* ps = fsb + (size_t)s * DF + mh * 16;
      const unsigned short* pd = fdb + (size_t)dn * DF + mh * 16;
      const float* pa = attn + mh * 16;
      bf16x8 s0 = *(const bf16x8*)ps;
      bf16x8 s1 = *(const bf16x8*)(ps + 8);
      bf16x8 d0 = *(const bf16x8*)pd;
      bf16x8 d1 = *(const bf16x8*)(pd + 8);
      float acc = 0.f;
#pragma unroll
      for (int kk = 0; kk < 8; ++kk) {
        float z = bf2f((unsigned short)s0[kk]) + bf2f((unsigned short)d0[kk]);
        z = (z > 0.f) ? z : 0.2f * z;
        acc = fmaf(z, pa[kk], acc);
        float z2 = bf2f((unsigned short)s1[kk]) + bf2f((unsigned short)d1[kk]);
        z2 = (z2 > 0.f) ? z2 : 0.2f * z2;
        acc = fmaf(z2, pa[kk + 8], acc);
      }
      score[(size_t)e * 8 + mh] = acc;
      atomicMax(&smax_u[(size_t)dn * 8 + mh], enc_f(acc));
    }
  }
}

__global__ __launch_bounds__(256) void k_gat_p(
    float* __restrict__ score, const unsigned* __restrict__ smax_u,
    const int* __restrict__ dst, float* __restrict__ denom, int Eg) {
  int g = blockIdx.x & 7, sub = blockIdx.x >> 3, nsub = gridDim.x >> 3;
  int gbase = g * Eg, gend = gbase + Eg;
  int tpg = (Eg + 127) >> 7;
  int tid = threadIdx.x;
  for (int t = sub; t < tpg; t += nsub) {
    int ebase = gbase + t * 128;
    for (int k = tid; k < 1024; k += 256) {
      int e = ebase + (k >> 3);
      if (e >= gend) break;
      int mh = k & 7;
      int dn = dst[e];
      float p = __expf(score[(size_t)e * 8 + mh] - dec_f(smax_u[(size_t)dn * 8 + mh]));
      score[(size_t)e * 8 + mh] = p;
      atomicAdd(&denom[(size_t)dn * 8 + mh], p);
    }
  }
}

__global__ __launch_bounds__(256) void k_gat_rst(
    const float* __restrict__ score, const float* __restrict__ denom,
    const unsigned short* __restrict__ fsb, const int* __restrict__ src,
    const int* __restrict__ dst, float* __restrict__ rst, int Eg) {
  int g = blockIdx.x & 7, sub = blockIdx.x >> 3, nsub = gridDim.x >> 3;
  int gbase = g * Eg, gend = gbase + Eg;
  int tpg = (Eg + 127) >> 7;
  int tid = threadIdx.x;
  for (int t = sub; t < tpg; t += nsub) {
    int ebase = gbase + t * 128;
    for (int k = tid; k < 16384; k += 256) {
      int e = ebase + (k >> 7);
      if (e >= gend) break;
      int d = k & 127, mh = d >> 4;
      int s = src[e], dn = dst[e];
      float a = score[(size_t)e * 8 + mh] / denom[(size_t)dn * 8 + mh];
      atomicAdd(&rst[(size_t)dn * DF + d], a * bf2f(fsb[(size_t)s * DF + d]));
    }
  }
}

// bias2 = O_b + gat_bias @ O_w^T
__global__ void k_bias2(const float* __restrict__ gat_bias,
                        const float* __restrict__ O_w,
                        const float* __restrict__ O_b, float* __restrict__ bias2) {
  int d = threadIdx.x;
  float acc = O_b[d];
  for (int k = 0; k < DF; ++k) acc = fmaf(gat_bias[k], O_w[(size_t)d * DF + k], acc);
  bias2[d] = acc;
}

// ---------------- readout ----------------
__global__ __launch_bounds__(128) void k_moy(
    const unsigned short* __restrict__ h2b, const int* __restrict__ ng,
    float* __restrict__ moy, float* __restrict__ cnt, int rows) {
  int tid = threadIdx.x;
  int per = (rows + gridDim.x - 1) / gridDim.x;
  int n0 = blockIdx.x * per;
  int n1 = min(rows, n0 + per);
  if (n0 >= n1) return;
  int cur = ng[n0];
  float acc = 0.f; int c = 0;
  for (int n = n0; n < n1; ++n) {
    int g = ng[n];
    if (g != cur) {
      atomicAdd(&moy[cur * DF + tid], acc);
      if (tid == 0) atomicAdd(&cnt[cur], (float)c);
      acc = 0.f; c = 0; cur = g;
    }
    acc += bf2f(h2b[(size_t)n * DF + tid]);
    ++c;
  }
  atomicAdd(&moy[cur * DF + tid], acc);
  if (tid == 0) atomicAdd(&cnt[cur], (float)c);
}

__global__ void k_moy_div(const float* __restrict__ moy, const float* __restrict__ cnt,
                          unsigned short* __restrict__ moyb) {
  int i = blockIdx.x * DF + threadIdx.x;
  moyb[i] = f2bf(moy[i] / cnt[blockIdx.x]);
}

// ---------------- fused MFMA head (graph-local, spill-free) ----------------
// y = relu([moy|h_src|h_dst] @ W1^T + b1); out = sigmoid(y.W2 + b2)
__global__ __launch_bounds__(1024) void k_final_mfma(
    const unsigned short* __restrict__ h2b, const unsigned short* __restrict__ moyb,
    const int* __restrict__ src, const int* __restrict__ dst,
    const short* __restrict__ W1f, const float* __restrict__ W1b,
    const float* __restrict__ W2, const float* __restrict__ W2b,
    float* __restrict__ out, int Eg) {
  __shared__ short Wb[6144 * 8];  // 96 KB
  int tid = threadIdx.x;
  for (int s = tid; s < 6144; s += 1024)
    *(bf16x8*)&Wb[s * 8] = *(const bf16x8*)&W1f[(size_t)s * 8];
  __syncthreads();
  int wid = tid >> 6, lane = tid & 63, q = lane >> 4, m = lane & 15;
  int g = blockIdx.x & 7, sub = blockIdx.x >> 3, nsub = gridDim.x >> 3;
  int gbase = g * Eg, gend = gbase + Eg;
  int tpg = (Eg + 255) >> 8;  // 256 edges per block-tile (16 waves x 16)
  const unsigned short* mrow = moyb + (size_t)g * DF;
  float w2b = W2b[0];
  float bb[8], ww[8];
#pragma unroll
  for (int ct = 0; ct < 8; ++ct) {
    bb[ct] = W1b[ct * 16 + m];
    ww[ct] = W2[ct * 16 + m];
  }
  for (int t = sub; t < tpg; t += nsub) {
    int r0 = gbase + t * 256 + wid * 16;
    int edge = r0 + m;
    int ec = (edge < gend) ? edge : gend - 1;
    int s = src[ec], d = dst[ec];
    const unsigned short* rs = h2b + (size_t)s * DF;
    const unsigned short* rd = h2b + (size_t)d * DF;
    f32x4 c[8];
#pragma unroll
    for (int ct = 0; ct < 8; ++ct) c[ct] = (f32x4){0.f, 0.f, 0.f, 0.f};
#pragma unroll
    for (int ks = 0; ks < 12; ++ks) {
      const unsigned short* p =
          (ks < 4) ? (mrow + ks * 32 + q * 8)
                   : ((ks < 8) ? (rs + (ks - 4) * 32 + q * 8) : (rd + (ks - 8) * 32 + q * 8));
      bf16x8 av = *(const bf16x8*)p;
#pragma unroll
      for (int ct = 0; ct < 8; ++ct) {
        bf16x8 b = *(const bf16x8*)&Wb[((ct * 12 + ks) * 64 + lane) * 8];
        c[ct] = __builtin_amdgcn_mfma_f32_16x16x32_bf16(av, b, c[ct], 0, 0, 0);
      }
    }
    float v0 = 0.f, v1 = 0.f, v2 = 0.f, v3 = 0.f;
#pragma unroll
    for (int ct = 0; ct < 8; ++ct) {
      v0 += fmaxf(c[ct][0] + bb[ct], 0.f) * ww[ct];
      v1 += fmaxf(c[ct][1] + bb[ct], 0.f) * ww[ct];
      v2 += fmaxf(c[ct][2] + bb[ct], 0.f) * ww[ct];
      v3 += fmaxf(c[ct][3] + bb[ct], 0.f) * ww[ct];
    }
#pragma unroll
    for (int mask = 1; mask <= 8; mask <<= 1) {
      v0 += __shfl_xor(v0, mask, 64);
      v1 += __shfl_xor(v1, mask, 64);
      v2 += __shfl_xor(v2, mask, 64);
      v3 += __shfl_xor(v3, mask, 64);
    }
    if (m == 0) {
      int rb = r0 + q * 4;
      if (rb < gend) out[rb] = sigm(v0 + w2b);
      if (rb + 1 < gend) out[rb + 1] = sigm(v1 + w2b);
      if (rb + 2 < gend) out[rb + 2] = sigm(v2 + w2b);
      if (rb + 3 < gend) out[rb + 3] = sigm(v3 + w2b);
    }
  }
}

extern "C" void kernel_launch(void* const* d_in, const int* in_sizes, int n_in,
                              void* d_out, int out_size, void* d_ws, size_t ws_size,
                              hipStream_t stream) {
  const float* h_in = (const float*)d_in[0];
  const float* e_in = (const float*)d_in[1];
  const int* src = (const int*)d_in[2];
  const int* dst = (const int*)d_in[3];
  const int* node_graph = (const int*)d_in[4];
  const int* edge_graph = (const int*)d_in[5];
  const float* emb_n_w = (const float*)d_in[6];
  const float* emb_n_b = (const float*)d_in[7];
  const float* emb_e_w = (const float*)d_in[8];
  const float* emb_e_b = (const float*)d_in[9];
  const float* Us = (const float*)d_in[10];
  const float* Vs = (const float*)d_in[11];
  const float* As = (const float*)d_in[12];
  const float* Bs = (const float*)d_in[13];
  const float* Cs = (const float*)d_in[14];
  const float* gat_src_w = (const float*)d_in[15];
  const float* gat_src_b = (const float*)d_in[16];
  const float* gat_dst_w = (const float*)d_in[17];
  const float* gat_dst_b = (const float*)d_in[18];
  const float* gat_attn = (const float*)d_in[19];
  const float* gat_bias = (const float*)d_in[20];
  const float* O_w = (const float*)d_in[21];
  const float* O_b = (const float*)d_in[22];
  const float* W1_w = (const float*)d_in[23];
  const float* W1_b = (const float*)d_in[24];
  const float* W2_w = (const float*)d_in[25];
  const float* W2_b = (const float*)d_in[26];
  float* out = (float*)d_out;

  const int N = in_sizes[0] / 64;   // 30000
  const int E = in_sizes[1] / 16;   // 360000
  const int Eg = E / NGRAPH;        // 45000

  const size_t sz_e0 = (size_t)E * DF * sizeof(unsigned short);
  const size_t sz_node = (size_t)N * DF * sizeof(float);
  const size_t sz_nodeb = (size_t)N * DF * sizeof(unsigned short);
  const size_t sz_score = (size_t)E * 8 * sizeof(float);
  const size_t sz_n8 = (size_t)N * 8 * sizeof(float);
  const size_t sz_wfrag = 18 * 2048 * 8 * sizeof(short);   // 576 KB
  const size_t sz_w1frag = 6144 * 8 * sizeof(short);       // 96 KB
  const size_t sz_misc = 4096 * sizeof(float);
  const size_t needed = sz_e0 + 3 * sz_node + 4 * sz_nodeb + sz_score + 2 * sz_n8 +
                        sz_wfrag + sz_w1frag + sz_misc;
  if (ws_size < needed) {
    k_fill_u32<<<256, 256, 0, stream>>>((unsigned*)out, 0xBF800000u, (long long)out_size);
    return;
  }

  char* wp = (char*)d_ws;
  auto alloc = [&](size_t bytes) { void* p = wp; wp += bytes; return p; };
  unsigned short* e0u = (unsigned short*)alloc(sz_e0);
  float* h0 = (float*)alloc(sz_node);
  float* hU = (float*)alloc(sz_node);
  unsigned* agg_u = (unsigned*)alloc(sz_node);  // also rst (f32)
  unsigned short* hVb = (unsigned short*)alloc(sz_nodeb);
  unsigned short* hBb = (unsigned short*)alloc(sz_nodeb);
  unsigned short* hCb = (unsigned short*)alloc(sz_nodeb);
  unsigned short* h2b = (unsigned short*)alloc(sz_nodeb);
  float* score = (float*)alloc(sz_score);
  unsigned* smax_u = (unsigned*)alloc(sz_n8);
  float* denom = (float*)alloc(sz_n8);
  short* wfrag = (short*)alloc(sz_wfrag);
  short* w1frag = (short*)alloc(sz_w1frag);
  float* misc = (float*)alloc(sz_misc);
  float* stat = misc;                                     // [0,1024)
  float* bias2 = misc + 1024;                             // [1024,1152)
  float* moy = misc + 1152;                               // [1152,2176)
  float* cnt = misc + 2176;                               // [2176,2184)
  unsigned short* moyb = (unsigned short*)(misc + 2304);  // 1024 bf16

  // frag-weight indices: U_l=l, V_l=3+l, A_l=6+l, B_l=9+l, C_l=12+l, gsw=15, gdw=16, Ow=17
  auto WF = [&](int idx) { return wfrag + (size_t)idx * 2048 * 8; };

  k_wconv<<<18, 512, 0, stream>>>(Us, Vs, As, Bs, Cs, gat_src_w, gat_dst_w, O_w, wfrag);
  k_wconv_w1<<<12, 512, 0, stream>>>(W1_w, w1frag);

  const int gN = (N + 127) / 128;
  k_node_embed<<<2048, 128, 0, stream>>>(h_in, emb_n_w, emb_n_b, h0, N);
  k_edge_embed<<<4096, 128, 0, stream>>>(e_in, emb_e_w, emb_e_b, e0u, E);

  for (int l = 0; l < 3; ++l) {
    k_gemm4_mfma<<<gN, 512, 0, stream>>>(h0, WF(3 + l), WF(l), WF(9 + l), WF(12 + l),
                                         hVb, hU, hBb, hCb, N);
    k_fill_u32<<<4096, 256, 0, stream>>>(agg_u, ENC_NEGINF, (long long)N * DF);
    k_fill_u32<<<4, 256, 0, stream>>>((unsigned*)stat, 0u, 1024);
    k_edge_max<<<512, 256, 0, stream>>>(hVb, e0u, src, dst, agg_u, Eg);
    k_node_pre_bn<<<512, 128, 0, stream>>>(hU, agg_u, stat, N);
    k_edge_mfma<0><<<256, 512, 0, stream>>>(e0u, WF(6 + l), hBb, hCb, src, dst, stat, Eg);
    k_bn_finalize<<<1, 256, 0, stream>>>(stat, (float)N, (float)E);
    k_node_update<<<2048, 256, 0, stream>>>(h0, hU, stat, (long long)N * DF);
    k_edge_mfma<1><<<256, 512, 0, stream>>>(e0u, WF(6 + l), hBb, hCb, src, dst, stat, Eg);
  }

  // GATv2: fs -> hVb, fd -> hBb
  k_gemm_mfma<1><<<gN, 512, 0, stream>>>(h0, WF(15), gat_src_b, hVb, N);
  k_gemm_mfma<1><<<gN, 512, 0, stream>>>(h0, WF(16), gat_dst_b, hBb, N);
  float* rst = (float*)agg_u;
  k_fill_u32<<<256, 256, 0, stream>>>(smax_u, ENC_NEGINF, (long long)N * 8);
  k_fill_u32<<<256, 256, 0, stream>>>((unsigned*)denom, 0u, (long long)N * 8);
  k_fill_u32<<<4096, 256, 0, stream>>>((unsigned*)rst, 0u, (long long)N * DF);
  k_fill_u32<<<2, 256, 0, stream>>>((unsigned*)moy, 0u, 1032);
  k_gat_score<<<512, 256, 0, stream>>>(hVb, hBb, src, dst, gat_attn, score, smax_u, Eg);
  k_gat_p<<<512, 256, 0, stream>>>(score, smax_u, dst, denom, Eg);
  k_gat_rst<<<512, 256, 0, stream>>>(score, denom, hVb, src, dst, rst, Eg);
  k_bias2<<<1, 128, 0, stream>>>(gat_bias, O_w, O_b, bias2);
  k_gemm_mfma<1><<<gN, 512, 0, stream>>>(rst, WF(17), bias2, h2b, N);  // h2

  // readout
  k_moy<<<128, 128, 0, stream>>>(h2b, node_graph, moy, cnt, N);
  k_moy_div<<<8, 128, 0, stream>>>(moy, cnt, moyb);
  k_final_mfma<<<256, 1024, 0, stream>>>(h2b, moyb, src, dst, w1frag, W1_b, W2_w,
                                         W2_b, out, Eg);
}

// Round 6
// 2380.631 us; speedup vs baseline: 1.0786x; 1.0786x over previous
//
#include <hip/hip_runtime.h>

#define DF 128
#define NGRAPH 8

typedef __attribute__((ext_vector_type(8))) short bf16x8;
typedef __attribute__((ext_vector_type(4))) float f32x4;

constexpr unsigned ENC_NEGINF = 0x007FFFFFu;  // enc(-inf)

__device__ __forceinline__ unsigned enc_f(float f) {
  unsigned u = __float_as_uint(f);
  return (u & 0x80000000u) ? ~u : (u | 0x80000000u);
}
__device__ __forceinline__ float dec_f(unsigned k) {
  unsigned u = (k & 0x80000000u) ? (k & 0x7FFFFFFFu) : ~k;
  return __uint_as_float(u);
}
__device__ __forceinline__ float sigm(float x) { return 1.f / (1.f + __expf(-x)); }
__device__ __forceinline__ unsigned short f2bf(float f) {  // RNE f32->bf16
  unsigned u = __float_as_uint(f);
  u += 0x7FFFu + ((u >> 16) & 1u);
  return (unsigned short)(u >> 16);
}
__device__ __forceinline__ float bf2f(unsigned short u) {
  return __uint_as_float(((unsigned)u) << 16);
}

// load 8 consecutive f32 (32B-aligned) -> bf16x8
__device__ __forceinline__ bf16x8 cvt8(const float* __restrict__ p) {
  float4 a = *(const float4*)p;
  float4 b = *(const float4*)(p + 4);
  bf16x8 r;
  r[0] = (short)f2bf(a.x); r[1] = (short)f2bf(a.y);
  r[2] = (short)f2bf(a.z); r[3] = (short)f2bf(a.w);
  r[4] = (short)f2bf(b.x); r[5] = (short)f2bf(b.y);
  r[6] = (short)f2bf(b.z); r[7] = (short)f2bf(b.w);
  return r;
}

// ---------------- generic fill ----------------
__global__ void k_fill_u32(unsigned* __restrict__ p, unsigned v, long long n) {
  long long i = (long long)blockIdx.x * blockDim.x + threadIdx.x;
  long long st = (long long)gridDim.x * blockDim.x;
  for (; i < n; i += st) p[i] = v;
}

// ---------------- weight pre-conversion to MFMA fragment order ----------------
__global__ __launch_bounds__(512) void k_wconv(
    const float* __restrict__ Us, const float* __restrict__ Vs,
    const float* __restrict__ As, const float* __restrict__ Bs,
    const float* __restrict__ Cs, const float* __restrict__ gsw,
    const float* __restrict__ gdw, const float* __restrict__ Ow,
    short* __restrict__ out) {
  int b = blockIdx.x;
  const float* W;
  if (b < 3) W = Us + b * 16384;
  else if (b < 6) W = Vs + (b - 3) * 16384;
  else if (b < 9) W = As + (b - 6) * 16384;
  else if (b < 12) W = Bs + (b - 9) * 16384;
  else if (b < 15) W = Cs + (b - 12) * 16384;
  else if (b == 15) W = gsw;
  else if (b == 16) W = gdw;
  else W = Ow;
  short* o = out + (size_t)b * 2048 * 8;
  for (int s = threadIdx.x; s < 2048; s += 512) {
    int ct = s >> 8, ks = (s >> 6) & 3, l = s & 63;
    int row = ct * 16 + (l & 15), k0 = ks * 32 + (l >> 4) * 8;
    *(bf16x8*)&o[s * 8] = cvt8(W + (size_t)row * DF + k0);
  }
}

__global__ __launch_bounds__(512) void k_wconv_w1(const float* __restrict__ W1,
                                                  short* __restrict__ out) {
  int s = blockIdx.x * 512 + threadIdx.x;  // grid 12 -> 6144 slots
  int ct = s / 768, ks = (s >> 6) % 12, l = s & 63;
  int row = ct * 16 + (l & 15), k0 = ks * 32 + (l >> 4) * 8;
  *(bf16x8*)&out[(size_t)s * 8] = cvt8(W1 + (size_t)row * 384 + k0);
}

// ---------------- embeddings ----------------
__global__ __launch_bounds__(128) void k_node_embed(
    const float* __restrict__ hin, const float* __restrict__ w,
    const float* __restrict__ b, float* __restrict__ h0, int rows) {
  __shared__ float Wt[64 * DF];
  __shared__ float ar[4][64];
  int tid = threadIdx.x;
  for (int i = tid; i < 64 * DF; i += 128) Wt[(i & 63) * DF + (i >> 6)] = w[i];
  float bb = b[tid];
  __syncthreads();
  for (int r0 = blockIdx.x * 4; r0 < rows; r0 += gridDim.x * 4) {
    for (int i = tid; i < 256; i += 128) ar[i >> 6][i & 63] = hin[(size_t)r0 * 64 + i];
    __syncthreads();
    float a0 = bb, a1 = bb, a2 = bb, a3 = bb;
#pragma unroll 8
    for (int k = 0; k < 64; ++k) {
      float wv = Wt[k * DF + tid];
      a0 = fmaf(ar[0][k], wv, a0); a1 = fmaf(ar[1][k], wv, a1);
      a2 = fmaf(ar[2][k], wv, a2); a3 = fmaf(ar[3][k], wv, a3);
    }
    h0[(size_t)r0 * DF + tid] = a0;
    h0[(size_t)(r0 + 1) * DF + tid] = a1;
    h0[(size_t)(r0 + 2) * DF + tid] = a2;
    h0[(size_t)(r0 + 3) * DF + tid] = a3;
    __syncthreads();
  }
}

__global__ __launch_bounds__(128) void k_edge_embed(
    const float* __restrict__ ein, const float* __restrict__ w,
    const float* __restrict__ b, unsigned short* __restrict__ e0u, int rows) {
  __shared__ float Wt[16 * DF];
  __shared__ float ar[4][16];
  int tid = threadIdx.x;
  for (int i = tid; i < 16 * DF; i += 128) Wt[(i & 15) * DF + (i >> 4)] = w[i];
  float bb = b[tid];
  __syncthreads();
  for (int r0 = blockIdx.x * 4; r0 < rows; r0 += gridDim.x * 4) {
    if (tid < 64) ar[tid >> 4][tid & 15] = ein[(size_t)r0 * 16 + tid];
    __syncthreads();
    float a0 = bb, a1 = bb, a2 = bb, a3 = bb;
#pragma unroll
    for (int k = 0; k < 16; ++k) {
      float wv = Wt[k * DF + tid];
      a0 = fmaf(ar[0][k], wv, a0); a1 = fmaf(ar[1][k], wv, a1);
      a2 = fmaf(ar[2][k], wv, a2); a3 = fmaf(ar[3][k], wv, a3);
    }
    e0u[(size_t)r0 * DF + tid] = f2bf(a0);
    e0u[(size_t)(r0 + 1) * DF + tid] = f2bf(a1);
    e0u[(size_t)(r0 + 2) * DF + tid] = f2bf(a2);
    e0u[(size_t)(r0 + 3) * DF + tid] = f2bf(a3);
    __syncthreads();
  }
}

// ---------------- MFMA [rows,128] @ W^T (+bias), frag weights ----------------
template <int OUTBF>
__global__ __launch_bounds__(512) void k_gemm_mfma(
    const float* __restrict__ A, const short* __restrict__ Wf,
    const float* __restrict__ bias, void* __restrict__ outv, int rows) {
  __shared__ short Wb[2048 * 8];  // 32 KB
  int tid = threadIdx.x;
  for (int s = tid; s < 2048; s += 512)
    *(bf16x8*)&Wb[s * 8] = *(const bf16x8*)&Wf[(size_t)s * 8];
  __syncthreads();
  float* outf = (float*)outv;
  unsigned short* outb = (unsigned short*)outv;
  int wid = tid >> 6, lane = tid & 63, q = lane >> 4, m = lane & 15;
  int ntiles = (rows + 127) >> 7;
  for (int t = blockIdx.x; t < ntiles; t += gridDim.x) {
    int r0 = t * 128 + wid * 16;
    int rr = r0 + m;
    if (rr >= rows) rr = rows - 1;
    const float* ap = A + (size_t)rr * DF + q * 8;
    bf16x8 a[4];
#pragma unroll
    for (int ks = 0; ks < 4; ++ks) a[ks] = cvt8(ap + 32 * ks);
#pragma unroll
    for (int ct = 0; ct < 8; ++ct) {
      f32x4 acc = {0.f, 0.f, 0.f, 0.f};
#pragma unroll
      for (int ks = 0; ks < 4; ++ks) {
        bf16x8 b = *(const bf16x8*)&Wb[((ct * 4 + ks) * 64 + lane) * 8];
        acc = __builtin_amdgcn_mfma_f32_16x16x32_bf16(a[ks], b, acc, 0, 0, 0);
      }
      int col = ct * 16 + m;
      float bb = bias ? bias[col] : 0.f;
#pragma unroll
      for (int j = 0; j < 4; ++j) {
        int row = r0 + q * 4 + j;
        if (row < rows) {
          if (OUTBF) outb[(size_t)row * DF + col] = f2bf(acc[j] + bb);
          else outf[(size_t)row * DF + col] = acc[j] + bb;
        }
      }
    }
  }
}

// ---------------- fused 4-output node GEMM (V,U,B,C) ----------------
__global__ __launch_bounds__(512) void k_gemm4_mfma(
    const float* __restrict__ h0, const short* __restrict__ Vf,
    const short* __restrict__ Uf, const short* __restrict__ Bf,
    const short* __restrict__ Cf, unsigned short* __restrict__ hVb,
    float* __restrict__ hU, unsigned short* __restrict__ hBb,
    unsigned short* __restrict__ hCb, int rows) {
  __shared__ short Wl[4 * 2048 * 8];  // 128 KB
  int tid = threadIdx.x;
  for (int s = tid; s < 2048; s += 512) {
    *(bf16x8*)&Wl[(size_t)s * 8] = *(const bf16x8*)&Vf[(size_t)s * 8];
    *(bf16x8*)&Wl[(size_t)(2048 + s) * 8] = *(const bf16x8*)&Uf[(size_t)s * 8];
    *(bf16x8*)&Wl[(size_t)(4096 + s) * 8] = *(const bf16x8*)&Bf[(size_t)s * 8];
    *(bf16x8*)&Wl[(size_t)(6144 + s) * 8] = *(const bf16x8*)&Cf[(size_t)s * 8];
  }
  __syncthreads();
  int wid = tid >> 6, lane = tid & 63, q = lane >> 4, m = lane & 15;
  int ntiles = (rows + 127) >> 7;
  for (int t = blockIdx.x; t < ntiles; t += gridDim.x) {
    int r0 = t * 128 + wid * 16;
    int rr = r0 + m;
    if (rr >= rows) rr = rows - 1;
    const float* ap = h0 + (size_t)rr * DF + q * 8;
    bf16x8 a[4];
#pragma unroll
    for (int ks = 0; ks < 4; ++ks) a[ks] = cvt8(ap + 32 * ks);
#pragma unroll
    for (int w = 0; w < 4; ++w) {
#pragma unroll
      for (int ct = 0; ct < 8; ++ct) {
        f32x4 acc = {0.f, 0.f, 0.f, 0.f};
#pragma unroll
        for (int ks = 0; ks < 4; ++ks) {
          bf16x8 b = *(const bf16x8*)&Wl[((w * 2048) + (ct * 4 + ks) * 64 + lane) * 8];
          acc = __builtin_amdgcn_mfma_f32_16x16x32_bf16(a[ks], b, acc, 0, 0, 0);
        }
        int col = ct * 16 + m;
#pragma unroll
        for (int j = 0; j < 4; ++j) {
          int row = r0 + q * 4 + j;
          if (row < rows) {
            if (w == 1) hU[(size_t)row * DF + col] = acc[j];
            else {
              unsigned short v = f2bf(acc[j]);
              unsigned short* o = (w == 0) ? hVb : ((w == 2) ? hBb : hCb);
              o[(size_t)row * DF + col] = v;
            }
          }
        }
      }
    }
  }
}

// ---------------- MFMA edge pass (graph-local): x = e@As^T + hB[dst] + hC[src] ----------------
template <int APPLY>
__global__ __launch_bounds__(512) void k_edge_mfma(
    unsigned short* __restrict__ e0u, const short* __restrict__ Af,
    const unsigned short* __restrict__ hBb, const unsigned short* __restrict__ hCb,
    const int* __restrict__ src, const int* __restrict__ dst,
    float* __restrict__ stat, int Eg) {
  __shared__ short Wb[2048 * 8];     // 32 KB
  __shared__ float xt[8][16 * 132];  // 66 KB
  int tid = threadIdx.x;
  for (int s = tid; s < 2048; s += 512)
    *(bf16x8*)&Wb[s * 8] = *(const bf16x8*)&Af[(size_t)s * 8];
  int wid = tid >> 6, lane = tid & 63, q = lane >> 4, m = lane & 15;
  int g = blockIdx.x & 7, sub = blockIdx.x >> 3, nsub = gridDim.x >> 3;
  int gbase = g * Eg, gend = gbase + Eg;
  int tpg = (Eg + 127) >> 7;
  float* xw = xt[wid];
  float ps0 = 0.f, ps1 = 0.f, pq0 = 0.f, pq1 = 0.f;
  __syncthreads();
  for (int t = sub; t < tpg; t += nsub) {
    int r0 = gbase + t * 128 + wid * 16;
    int edge = r0 + m;
    bool ok = edge < gend;
    int ec = ok ? edge : gend - 1;
    const unsigned short* ep = e0u + (size_t)ec * DF + q * 8;
    bf16x8 a[4];
#pragma unroll
    for (int ks = 0; ks < 4; ++ks) a[ks] = *(const bf16x8*)(ep + 32 * ks);
#pragma unroll
    for (int ct = 0; ct < 8; ++ct) {
      f32x4 acc = {0.f, 0.f, 0.f, 0.f};
#pragma unroll
      for (int ks = 0; ks < 4; ++ks) {
        bf16x8 b = *(const bf16x8*)&Wb[((ct * 4 + ks) * 64 + lane) * 8];
        acc = __builtin_amdgcn_mfma_f32_16x16x32_bf16(a[ks], b, acc, 0, 0, 0);
      }
#pragma unroll
      for (int j = 0; j < 4; ++j) xw[(q * 4 + j) * 132 + ct * 16 + m] = acc[j];
    }
    __syncthreads();
    int sidx = src[ec], didx = dst[ec];
    const unsigned short* pb = hBb + (size_t)didx * DF;
    const unsigned short* pc = hCb + (size_t)sidx * DF;
#pragma unroll
    for (int ks = 0; ks < 4; ++ks) {
      int c0 = q * 8 + 32 * ks;
      float* xp = &xw[m * 132 + c0];
      bf16x8 gb = *(const bf16x8*)(pb + c0);
      bf16x8 gc = *(const bf16x8*)(pc + c0);
      float x[8];
#pragma unroll
      for (int i = 0; i < 8; ++i)
        x[i] = xp[i] + bf2f((unsigned short)gb[i]) + bf2f((unsigned short)gc[i]);
      if (APPLY) {
        bf16x8 nv;
#pragma unroll
        for (int i = 0; i < 8; ++i) {
          float mm = stat[768 + c0 + i], iv = stat[896 + c0 + i];
          nv[i] = (short)f2bf(bf2f((unsigned short)a[ks][i]) + fmaxf((x[i] - mm) * iv, 0.f));
        }
        if (ok) *(bf16x8*)(e0u + (size_t)ec * DF + c0) = nv;
      } else {
#pragma unroll
        for (int i = 0; i < 8; ++i) xp[i] = ok ? x[i] : 0.f;
      }
    }
    if (!APPLY) {
      __syncthreads();
#pragma unroll 4
      for (int r = 0; r < 16; ++r) {
        float2 v = *(float2*)&xw[r * 132 + 2 * lane];
        ps0 += v.x; ps1 += v.y;
        pq0 += v.x * v.x; pq1 += v.y * v.y;
      }
    }
    __syncthreads();
  }
  if (!APPLY) {
    atomicAdd(&stat[512 + 2 * lane], ps0);
    atomicAdd(&stat[512 + 2 * lane + 1], ps1);
    atomicAdd(&stat[640 + 2 * lane], pq0);
    atomicAdd(&stat[640 + 2 * lane + 1], pq1);
  }
}

// ---------------- layer: m = hV[src]*sigmoid(e); segment_max (graph-local) ----------------
__global__ __launch_bounds__(256) void k_edge_max(
    const unsigned short* __restrict__ hVb, const unsigned short* __restrict__ e0u,
    const int* __restrict__ src, const int* __restrict__ dst,
    unsigned* __restrict__ agg_u, int Eg) {
  int g = blockIdx.x & 7, sub = blockIdx.x >> 3, nsub = gridDim.x >> 3;
  int gbase = g * Eg, gend = gbase + Eg;
  int tpg = (Eg + 127) >> 7;
  int tid = threadIdx.x;
  for (int t = sub; t < tpg; t += nsub) {
    int ebase = gbase + t * 128;
    for (int k = tid; k < 16384; k += 256) {
      int e = ebase + (k >> 7);
      if (e >= gend) break;
      int d = k & 127;
      float mm = bf2f(hVb[(size_t)src[e] * DF + d]) * sigm(bf2f(e0u[(size_t)e * DF + d]));
      atomicMax(&agg_u[(size_t)dst[e] * DF + d], enc_f(mm));
    }
  }
}

// tmp_h = hU + decode(agg); accumulate node BN stats
__global__ __launch_bounds__(128) void k_node_pre_bn(
    float* __restrict__ hU, const unsigned* __restrict__ agg_u,
    float* __restrict__ stat, int rows) {
  int tid = threadIdx.x;
  float ps = 0.f, pq = 0.f;
  for (int n = blockIdx.x; n < rows; n += gridDim.x) {
    size_t idx = (size_t)n * DF + tid;
    unsigned k = agg_u[idx];
    float a = (k == ENC_NEGINF) ? 0.f : dec_f(k);
    float t = hU[idx] + a;
    hU[idx] = t;
    ps += t; pq += t * t;
  }
  atomicAdd(&stat[tid], ps);
  atomicAdd(&stat[128 + tid], pq);
}

// finalize BN stats
__global__ void k_bn_finalize(float* __restrict__ stat, float nN, float nE) {
  int tid = threadIdx.x;
  if (tid < 128) {
    float mean = stat[tid] / nN;
    float var = stat[128 + tid] / nN - mean * mean;
    stat[256 + tid] = mean;
    stat[384 + tid] = rsqrtf(fmaxf(var, 0.f) + 1e-5f);
  } else {
    int d = tid - 128;
    float mean = stat[512 + d] / nE;
    float var = stat[640 + d] / nE - mean * mean;
    stat[768 + d] = mean;
    stat[896 + d] = rsqrtf(fmaxf(var, 0.f) + 1e-5f);
  }
}

__global__ __launch_bounds__(256) void k_node_update(
    float* __restrict__ h0, const float* __restrict__ hU,
    const float* __restrict__ stat, long long total) {
  long long i = (long long)blockIdx.x * blockDim.x + threadIdx.x;
  long long st = (long long)gridDim.x * blockDim.x;
  for (; i < total; i += st) {
    int d = (int)(i & 127);
    float t = (hU[i] - stat[256 + d]) * stat[384 + d];
    h0[i] += fmaxf(t, 0.f);
  }
}

// ---------------- GATv2 (graph-local) ----------------
__global__ __launch_bounds__(256) void k_gat_score(
    const unsigned short* __restrict__ fsb, const unsigned short* __restrict__ fdb,
    const int* __restrict__ src, const int* __restrict__ dst,
    const float* __restrict__ attn, float* __restrict__ score,
    unsigned* __restrict__ smax_u, int Eg) {
  int g = blockIdx.x & 7, sub = blockIdx.x >> 3, nsub = gridDim.x >> 3;
  int gbase = g * Eg, gend = gbase + Eg;
  int tpg = (Eg + 127) >> 7;
  int tid = threadIdx.x;
  for (int t = sub; t < tpg; t += nsub) {
    int ebase = gbase + t * 128;
    for (int k = tid; k < 1024; k += 256) {
      int e = ebase + (k >> 3);
      if (e >= gend) break;
      int mh = k & 7;
      int s = src[e], dn = dst[e];
      const unsigned short* ps = fsb + (size_t)s * DF + mh * 16;
      const unsigned short* pd = fdb + (size_t)dn * DF + mh * 16;
      const float* pa = attn + mh * 16;
      bf16x8 s0 = *(const bf16x8*)ps;
      bf16x8 s1 = *(const bf16x8*)(ps + 8);
      bf16x8 d0 = *(const bf16x8*)pd;
      bf16x8 d1 = *(const bf16x8*)(pd + 8);
      float acc = 0.f;
#pragma unroll
      for (int kk = 0; kk < 8; ++kk) {
        float z = bf2f((unsigned short)s0[kk]) + bf2f((unsigned short)d0[kk]);
        z = (z > 0.f) ? z : 0.2f * z;
        acc = fmaf(z, pa[kk], acc);
        float z2 = bf2f((unsigned short)s1[kk]) + bf2f((unsigned short)d1[kk]);
        z2 = (z2 > 0.f) ? z2 : 0.2f * z2;
        acc = fmaf(z2, pa[kk + 8], acc);
      }
      score[(size_t)e * 8 + mh] = acc;
      atomicMax(&smax_u[(size_t)dn * 8 + mh], enc_f(acc));
    }
  }
}

__global__ __launch_bounds__(256) void k_gat_p(
    float* __restrict__ score, const unsigned* __restrict__ smax_u,
    const int* __restrict__ dst, float* __restrict__ denom, int Eg) {
  int g = blockIdx.x & 7, sub = blockIdx.x >> 3, nsub = gridDim.x >> 3;
  int gbase = g * Eg, gend = gbase + Eg;
  int tpg = (Eg + 127) >> 7;
  int tid = threadIdx.x;
  for (int t = sub; t < tpg; t += nsub) {
    int ebase = gbase + t * 128;
    for (int k = tid; k < 1024; k += 256) {
      int e = ebase + (k >> 3);
      if (e >= gend) break;
      int mh = k & 7;
      int dn = dst[e];
      float p = __expf(score[(size_t)e * 8 + mh] - dec_f(smax_u[(size_t)dn * 8 + mh]));
      score[(size_t)e * 8 + mh] = p;
      atomicAdd(&denom[(size_t)dn * 8 + mh], p);
    }
  }
}

__global__ __launch_bounds__(256) void k_gat_rst(
    const float* __restrict__ score, const float* __restrict__ denom,
    const unsigned short* __restrict__ fsb, const int* __restrict__ src,
    const int* __restrict__ dst, float* __restrict__ rst, int Eg) {
  int g = blockIdx.x & 7, sub = blockIdx.x >> 3, nsub = gridDim.x >> 3;
  int gbase = g * Eg, gend = gbase + Eg;
  int tpg = (Eg + 127) >> 7;
  int tid = threadIdx.x;
  for (int t = sub; t < tpg; t += nsub) {
    int ebase = gbase + t * 128;
    for (int k = tid; k < 16384; k += 256) {
      int e = ebase + (k >> 7);
      if (e >= gend) break;
      int d = k & 127, mh = d >> 4;
      int s = src[e], dn = dst[e];
      float a = score[(size_t)e * 8 + mh] / denom[(size_t)dn * 8 + mh];
      atomicAdd(&rst[(size_t)dn * DF + d], a * bf2f(fsb[(size_t)s * DF + d]));
    }
  }
}

// bias2 = O_b + gat_bias @ O_w^T
__global__ void k_bias2(const float* __restrict__ gat_bias,
                        const float* __restrict__ O_w,
                        const float* __restrict__ O_b, float* __restrict__ bias2) {
  int d = threadIdx.x;
  float acc = O_b[d];
  for (int k = 0; k < DF; ++k) acc = fmaf(gat_bias[k], O_w[(size_t)d * DF + k], acc);
  bias2[d] = acc;
}

// ---------------- readout ----------------
__global__ __launch_bounds__(128) void k_moy(
    const unsigned short* __restrict__ h2b, const int* __restrict__ ng,
    float* __restrict__ moy, float* __restrict__ cnt, int rows) {
  int tid = threadIdx.x;
  int per = (rows + gridDim.x - 1) / gridDim.x;
  int n0 = blockIdx.x * per;
  int n1 = min(rows, n0 + per);
  if (n0 >= n1) return;
  int cur = ng[n0];
  float acc = 0.f; int c = 0;
  for (int n = n0; n < n1; ++n) {
    int g = ng[n];
    if (g != cur) {
      atomicAdd(&moy[cur * DF + tid], acc);
      if (tid == 0) atomicAdd(&cnt[cur], (float)c);
      acc = 0.f; c = 0; cur = g;
    }
    acc += bf2f(h2b[(size_t)n * DF + tid]);
    ++c;
  }
  atomicAdd(&moy[cur * DF + tid], acc);
  if (tid == 0) atomicAdd(&cnt[cur], (float)c);
}

__global__ void k_moy_div(const float* __restrict__ moy, const float* __restrict__ cnt,
                          unsigned short* __restrict__ moyb) {
  int i = blockIdx.x * DF + threadIdx.x;
  moyb[i] = f2bf(moy[i] / cnt[blockIdx.x]);
}

// ---------------- fused MFMA head (graph-local, spill-free) ----------------
// 512 thr = 8 waves; LDS 96 KB -> 1 block/CU -> 2 waves/SIMD -> up to 256 VGPR/lane.
// live state: a[12]=48 + c[8]=32 + b prefetch + addr ~ 150 regs -> no scratch.
__global__ __launch_bounds__(512, 2) void k_final_mfma(
    const unsigned short* __restrict__ h2b, const unsigned short* __restrict__ moyb,
    const int* __restrict__ src, const int* __restrict__ dst,
    const short* __restrict__ W1f, const float* __restrict__ W1b,
    const float* __restrict__ W2, const float* __restrict__ W2b,
    float* __restrict__ out, int Eg) {
  __shared__ short Wb[6144 * 8];  // 96 KB
  int tid = threadIdx.x;
  for (int s = tid; s < 6144; s += 512)
    *(bf16x8*)&Wb[s * 8] = *(const bf16x8*)&W1f[(size_t)s * 8];
  __syncthreads();
  int wid = tid >> 6, lane = tid & 63, q = lane >> 4, m = lane & 15;
  int g = blockIdx.x & 7, sub = blockIdx.x >> 3, nsub = gridDim.x >> 3;
  int gbase = g * Eg, gend = gbase + Eg;
  int tpg = (Eg + 127) >> 7;  // 128 edges per block-tile (8 waves x 16)
  const unsigned short* mrow = moyb + (size_t)g * DF;
  float w2b = W2b[0];
  float bb[8], ww[8];
#pragma unroll
  for (int ct = 0; ct < 8; ++ct) {
    bb[ct] = W1b[ct * 16 + m];
    ww[ct] = W2[ct * 16 + m];
  }
  for (int t = sub; t < tpg; t += nsub) {
    int r0 = gbase + t * 128 + wid * 16;
    int edge = r0 + m;
    int ec = (edge < gend) ? edge : gend - 1;
    int s = src[ec], d = dst[ec];
    const unsigned short* rs = h2b + (size_t)s * DF + q * 8;
    const unsigned short* rd = h2b + (size_t)d * DF + q * 8;
    bf16x8 a[12];
#pragma unroll
    for (int ks = 0; ks < 4; ++ks) {
      a[ks] = *(const bf16x8*)(mrow + ks * 32 + q * 8);
      a[4 + ks] = *(const bf16x8*)(rs + ks * 32);
      a[8 + ks] = *(const bf16x8*)(rd + ks * 32);
    }
    f32x4 c[8];
#pragma unroll
    for (int ct = 0; ct < 8; ++ct) c[ct] = (f32x4){0.f, 0.f, 0.f, 0.f};
#pragma unroll
    for (int ks = 0; ks < 12; ++ks) {
      bf16x8 av = a[ks];
#pragma unroll
      for (int ct = 0; ct < 8; ++ct) {
        bf16x8 b = *(const bf16x8*)&Wb[((ct * 12 + ks) * 64 + lane) * 8];
        c[ct] = __builtin_amdgcn_mfma_f32_16x16x32_bf16(av, b, c[ct], 0, 0, 0);
      }
    }
    float v0 = 0.f, v1 = 0.f, v2 = 0.f, v3 = 0.f;
#pragma unroll
    for (int ct = 0; ct < 8; ++ct) {
      v0 += fmaxf(c[ct][0] + bb[ct], 0.f) * ww[ct];
      v1 += fmaxf(c[ct][1] + bb[ct], 0.f) * ww[ct];
      v2 += fmaxf(c[ct][2] + bb[ct], 0.f) * ww[ct];
      v3 += fmaxf(c[ct][3] + bb[ct], 0.f) * ww[ct];
    }
#pragma unroll
    for (int mask = 1; mask <= 8; mask <<= 1) {
      v0 += __shfl_xor(v0, mask, 64);
      v1 += __shfl_xor(v1, mask, 64);
      v2 += __shfl_xor(v2, mask, 64);
      v3 += __shfl_xor(v3, mask, 64);
    }
    if (m == 0) {
      int rb = r0 + q * 4;
      if (rb < gend) out[rb] = sigm(v0 + w2b);
      if (rb + 1 < gend) out[rb + 1] = sigm(v1 + w2b);
      if (rb + 2 < gend) out[rb + 2] = sigm(v2 + w2b);
      if (rb + 3 < gend) out[rb + 3] = sigm(v3 + w2b);
    }
  }
}

extern "C" void kernel_launch(void* const* d_in, const int* in_sizes, int n_in,
                              void* d_out, int out_size, void* d_ws, size_t ws_size,
                              hipStream_t stream) {
  const float* h_in = (const float*)d_in[0];
  const float* e_in = (const float*)d_in[1];
  const int* src = (const int*)d_in[2];
  const int* dst = (const int*)d_in[3];
  const int* node_graph = (const int*)d_in[4];
  const int* edge_graph = (const int*)d_in[5];
  const float* emb_n_w = (const float*)d_in[6];
  const float* emb_n_b = (const float*)d_in[7];
  const float* emb_e_w = (const float*)d_in[8];
  const float* emb_e_b = (const float*)d_in[9];
  const float* Us = (const float*)d_in[10];
  const float* Vs = (const float*)d_in[11];
  const float* As = (const float*)d_in[12];
  const float* Bs = (const float*)d_in[13];
  const float* Cs = (const float*)d_in[14];
  const float* gat_src_w = (const float*)d_in[15];
  const float* gat_src_b = (const float*)d_in[16];
  const float* gat_dst_w = (const float*)d_in[17];
  const float* gat_dst_b = (const float*)d_in[18];
  const float* gat_attn = (const float*)d_in[19];
  const float* gat_bias = (const float*)d_in[20];
  const float* O_w = (const float*)d_in[21];
  const float* O_b = (const float*)d_in[22];
  const float* W1_w = (const float*)d_in[23];
  const float* W1_b = (const float*)d_in[24];
  const float* W2_w = (const float*)d_in[25];
  const float* W2_b = (const float*)d_in[26];
  float* out = (float*)d_out;

  const int N = in_sizes[0] / 64;   // 30000
  const int E = in_sizes[1] / 16;   // 360000
  const int Eg = E / NGRAPH;        // 45000

  const size_t sz_e0 = (size_t)E * DF * sizeof(unsigned short);
  const size_t sz_node = (size_t)N * DF * sizeof(float);
  const size_t sz_nodeb = (size_t)N * DF * sizeof(unsigned short);
  const size_t sz_score = (size_t)E * 8 * sizeof(float);
  const size_t sz_n8 = (size_t)N * 8 * sizeof(float);
  const size_t sz_wfrag = 18 * 2048 * 8 * sizeof(short);   // 576 KB
  const size_t sz_w1frag = 6144 * 8 * sizeof(short);       // 96 KB
  const size_t sz_misc = 4096 * sizeof(float);
  const size_t needed = sz_e0 + 3 * sz_node + 4 * sz_nodeb + sz_score + 2 * sz_n8 +
                        sz_wfrag + sz_w1frag + sz_misc;
  if (ws_size < needed) {
    k_fill_u32<<<256, 256, 0, stream>>>((unsigned*)out, 0xBF800000u, (long long)out_size);
    return;
  }

  char* wp = (char*)d_ws;
  auto alloc = [&](size_t bytes) { void* p = wp; wp += bytes; return p; };
  unsigned short* e0u = (unsigned short*)alloc(sz_e0);
  float* h0 = (float*)alloc(sz_node);
  float* hU = (float*)alloc(sz_node);
  unsigned* agg_u = (unsigned*)alloc(sz_node);  // also rst (f32)
  unsigned short* hVb = (unsigned short*)alloc(sz_nodeb);
  unsigned short* hBb = (unsigned short*)alloc(sz_nodeb);
  unsigned short* hCb = (unsigned short*)alloc(sz_nodeb);
  unsigned short* h2b = (unsigned short*)alloc(sz_nodeb);
  float* score = (float*)alloc(sz_score);
  unsigned* smax_u = (unsigned*)alloc(sz_n8);
  float* denom = (float*)alloc(sz_n8);
  short* wfrag = (short*)alloc(sz_wfrag);
  short* w1frag = (short*)alloc(sz_w1frag);
  float* misc = (float*)alloc(sz_misc);
  float* stat = misc;                                     // [0,1024)
  float* bias2 = misc + 1024;                             // [1024,1152)
  float* moy = misc + 1152;                               // [1152,2176)
  float* cnt = misc + 2176;                               // [2176,2184)
  unsigned short* moyb = (unsigned short*)(misc + 2304);  // 1024 bf16

  // frag-weight indices: U_l=l, V_l=3+l, A_l=6+l, B_l=9+l, C_l=12+l, gsw=15, gdw=16, Ow=17
  auto WF = [&](int idx) { return wfrag + (size_t)idx * 2048 * 8; };

  k_wconv<<<18, 512, 0, stream>>>(Us, Vs, As, Bs, Cs, gat_src_w, gat_dst_w, O_w, wfrag);
  k_wconv_w1<<<12, 512, 0, stream>>>(W1_w, w1frag);

  const int gN = (N + 127) / 128;
  k_node_embed<<<2048, 128, 0, stream>>>(h_in, emb_n_w, emb_n_b, h0, N);
  k_edge_embed<<<4096, 128, 0, stream>>>(e_in, emb_e_w, emb_e_b, e0u, E);

  for (int l = 0; l < 3; ++l) {
    k_gemm4_mfma<<<gN, 512, 0, stream>>>(h0, WF(3 + l), WF(l), WF(9 + l), WF(12 + l),
                                         hVb, hU, hBb, hCb, N);
    k_fill_u32<<<4096, 256, 0, stream>>>(agg_u, ENC_NEGINF, (long long)N * DF);
    k_fill_u32<<<4, 256, 0, stream>>>((unsigned*)stat, 0u, 1024);
    k_edge_max<<<512, 256, 0, stream>>>(hVb, e0u, src, dst, agg_u, Eg);
    k_node_pre_bn<<<512, 128, 0, stream>>>(hU, agg_u, stat, N);
    k_edge_mfma<0><<<256, 512, 0, stream>>>(e0u, WF(6 + l), hBb, hCb, src, dst, stat, Eg);
    k_bn_finalize<<<1, 256, 0, stream>>>(stat, (float)N, (float)E);
    k_node_update<<<2048, 256, 0, stream>>>(h0, hU, stat, (long long)N * DF);
    k_edge_mfma<1><<<256, 512, 0, stream>>>(e0u, WF(6 + l), hBb, hCb, src, dst, stat, Eg);
  }

  // GATv2: fs -> hVb, fd -> hBb
  k_gemm_mfma<1><<<gN, 512, 0, stream>>>(h0, WF(15), gat_src_b, hVb, N);
  k_gemm_mfma<1><<<gN, 512, 0, stream>>>(h0, WF(16), gat_dst_b, hBb, N);
  float* rst = (float*)agg_u;
  k_fill_u32<<<256, 256, 0, stream>>>(smax_u, ENC_NEGINF, (long long)N * 8);
  k_fill_u32<<<256, 256, 0, stream>>>((unsigned*)denom, 0u, (long long)N * 8);
  k_fill_u32<<<4096, 256, 0, stream>>>((unsigned*)rst, 0u, (long long)N * DF);
  k_fill_u32<<<2, 256, 0, stream>>>((unsigned*)moy, 0u, 1032);
  k_gat_score<<<512, 256, 0, stream>>>(hVb, hBb, src, dst, gat_attn, score, smax_u, Eg);
  k_gat_p<<<512, 256, 0, stream>>>(score, smax_u, dst, denom, Eg);
  k_gat_rst<<<512, 256, 0, stream>>>(score, denom, hVb, src, dst, rst, Eg);
  k_bias2<<<1, 128, 0, stream>>>(gat_bias, O_w, O_b, bias2);
  k_gemm_mfma<1><<<gN, 512, 0, stream>>>(rst, WF(17), bias2, h2b, N);  // h2

  // readout
  k_moy<<<128, 128, 0, stream>>>(h2b, node_graph, moy, cnt, N);
  k_moy_div<<<8, 128, 0, stream>>>(moy, cnt, moyb);
  k_final_mfma<<<1024, 512, 0, stream>>>(h2b, moyb, src, dst, w1frag, W1_b, W2_w,
                                         W2_b, out, Eg);
}

// Round 7
// 2264.929 us; speedup vs baseline: 1.1337x; 1.0511x over previous
//
#include <hip/hip_runtime.h>

#define DF 128
#define NGRAPH 8

typedef __attribute__((ext_vector_type(8))) short bf16x8;
typedef __attribute__((ext_vector_type(4))) float f32x4;

constexpr unsigned ENC_NEGINF = 0x007FFFFFu;  // enc(-inf)

__device__ __forceinline__ unsigned enc_f(float f) {
  unsigned u = __float_as_uint(f);
  return (u & 0x80000000u) ? ~u : (u | 0x80000000u);
}
__device__ __forceinline__ float dec_f(unsigned k) {
  unsigned u = (k & 0x80000000u) ? (k & 0x7FFFFFFFu) : ~k;
  return __uint_as_float(u);
}
__device__ __forceinline__ float sigm(float x) { return 1.f / (1.f + __expf(-x)); }
__device__ __forceinline__ unsigned short f2bf(float f) {  // RNE f32->bf16
  unsigned u = __float_as_uint(f);
  u += 0x7FFFu + ((u >> 16) & 1u);
  return (unsigned short)(u >> 16);
}
__device__ __forceinline__ float bf2f(unsigned short u) {
  return __uint_as_float(((unsigned)u) << 16);
}

// load 8 consecutive f32 (32B-aligned) -> bf16x8
__device__ __forceinline__ bf16x8 cvt8(const float* __restrict__ p) {
  float4 a = *(const float4*)p;
  float4 b = *(const float4*)(p + 4);
  bf16x8 r;
  r[0] = (short)f2bf(a.x); r[1] = (short)f2bf(a.y);
  r[2] = (short)f2bf(a.z); r[3] = (short)f2bf(a.w);
  r[4] = (short)f2bf(b.x); r[5] = (short)f2bf(b.y);
  r[6] = (short)f2bf(b.z); r[7] = (short)f2bf(b.w);
  return r;
}

// ---------------- generic fill ----------------
__global__ void k_fill_u32(unsigned* __restrict__ p, unsigned v, long long n) {
  long long i = (long long)blockIdx.x * blockDim.x + threadIdx.x;
  long long st = (long long)gridDim.x * blockDim.x;
  for (; i < n; i += st) p[i] = v;
}

// ---------------- weight pre-conversion to MFMA fragment order ----------------
__global__ __launch_bounds__(512) void k_wconv(
    const float* __restrict__ Us, const float* __restrict__ Vs,
    const float* __restrict__ As, const float* __restrict__ Bs,
    const float* __restrict__ Cs, const float* __restrict__ gsw,
    const float* __restrict__ gdw, const float* __restrict__ Ow,
    short* __restrict__ out) {
  int b = blockIdx.x;
  const float* W;
  if (b < 3) W = Us + b * 16384;
  else if (b < 6) W = Vs + (b - 3) * 16384;
  else if (b < 9) W = As + (b - 6) * 16384;
  else if (b < 12) W = Bs + (b - 9) * 16384;
  else if (b < 15) W = Cs + (b - 12) * 16384;
  else if (b == 15) W = gsw;
  else if (b == 16) W = gdw;
  else W = Ow;
  short* o = out + (size_t)b * 2048 * 8;
  for (int s = threadIdx.x; s < 2048; s += 512) {
    int ct = s >> 8, ks = (s >> 6) & 3, l = s & 63;
    int row = ct * 16 + (l & 15), k0 = ks * 32 + (l >> 4) * 8;
    *(bf16x8*)&o[s * 8] = cvt8(W + (size_t)row * DF + k0);
  }
}

__global__ __launch_bounds__(512) void k_wconv_w1(const float* __restrict__ W1,
                                                  short* __restrict__ out) {
  int s = blockIdx.x * 512 + threadIdx.x;  // grid 12 -> 6144 slots
  int ct = s / 768, ks = (s >> 6) % 12, l = s & 63;
  int row = ct * 16 + (l & 15), k0 = ks * 32 + (l >> 4) * 8;
  *(bf16x8*)&out[(size_t)s * 8] = cvt8(W1 + (size_t)row * 384 + k0);
}

// ---------------- embeddings ----------------
__global__ __launch_bounds__(128) void k_node_embed(
    const float* __restrict__ hin, const float* __restrict__ w,
    const float* __restrict__ b, float* __restrict__ h0, int rows) {
  __shared__ float Wt[64 * DF];
  __shared__ float ar[4][64];
  int tid = threadIdx.x;
  for (int i = tid; i < 64 * DF; i += 128) Wt[(i & 63) * DF + (i >> 6)] = w[i];
  float bb = b[tid];
  __syncthreads();
  for (int r0 = blockIdx.x * 4; r0 < rows; r0 += gridDim.x * 4) {
    for (int i = tid; i < 256; i += 128) ar[i >> 6][i & 63] = hin[(size_t)r0 * 64 + i];
    __syncthreads();
    float a0 = bb, a1 = bb, a2 = bb, a3 = bb;
#pragma unroll 8
    for (int k = 0; k < 64; ++k) {
      float wv = Wt[k * DF + tid];
      a0 = fmaf(ar[0][k], wv, a0); a1 = fmaf(ar[1][k], wv, a1);
      a2 = fmaf(ar[2][k], wv, a2); a3 = fmaf(ar[3][k], wv, a3);
    }
    h0[(size_t)r0 * DF + tid] = a0;
    h0[(size_t)(r0 + 1) * DF + tid] = a1;
    h0[(size_t)(r0 + 2) * DF + tid] = a2;
    h0[(size_t)(r0 + 3) * DF + tid] = a3;
    __syncthreads();
  }
}

__global__ __launch_bounds__(128) void k_edge_embed(
    const float* __restrict__ ein, const float* __restrict__ w,
    const float* __restrict__ b, unsigned short* __restrict__ e0u, int rows) {
  __shared__ float Wt[16 * DF];
  __shared__ float ar[4][16];
  int tid = threadIdx.x;
  for (int i = tid; i < 16 * DF; i += 128) Wt[(i & 15) * DF + (i >> 4)] = w[i];
  float bb = b[tid];
  __syncthreads();
  for (int r0 = blockIdx.x * 4; r0 < rows; r0 += gridDim.x * 4) {
    if (tid < 64) ar[tid >> 4][tid & 15] = ein[(size_t)r0 * 16 + tid];
    __syncthreads();
    float a0 = bb, a1 = bb, a2 = bb, a3 = bb;
#pragma unroll
    for (int k = 0; k < 16; ++k) {
      float wv = Wt[k * DF + tid];
      a0 = fmaf(ar[0][k], wv, a0); a1 = fmaf(ar[1][k], wv, a1);
      a2 = fmaf(ar[2][k], wv, a2); a3 = fmaf(ar[3][k], wv, a3);
    }
    e0u[(size_t)r0 * DF + tid] = f2bf(a0);
    e0u[(size_t)(r0 + 1) * DF + tid] = f2bf(a1);
    e0u[(size_t)(r0 + 2) * DF + tid] = f2bf(a2);
    e0u[(size_t)(r0 + 3) * DF + tid] = f2bf(a3);
    __syncthreads();
  }
}

// ---------------- MFMA [rows,128] @ W^T (+bias), frag weights ----------------
template <int OUTBF>
__global__ __launch_bounds__(512) void k_gemm_mfma(
    const float* __restrict__ A, const short* __restrict__ Wf,
    const float* __restrict__ bias, void* __restrict__ outv, int rows) {
  __shared__ short Wb[2048 * 8];  // 32 KB
  int tid = threadIdx.x;
  for (int s = tid; s < 2048; s += 512)
    *(bf16x8*)&Wb[s * 8] = *(const bf16x8*)&Wf[(size_t)s * 8];
  __syncthreads();
  float* outf = (float*)outv;
  unsigned short* outb = (unsigned short*)outv;
  int wid = tid >> 6, lane = tid & 63, q = lane >> 4, m = lane & 15;
  int ntiles = (rows + 127) >> 7;
  for (int t = blockIdx.x; t < ntiles; t += gridDim.x) {
    int r0 = t * 128 + wid * 16;
    int rr = r0 + m;
    if (rr >= rows) rr = rows - 1;
    const float* ap = A + (size_t)rr * DF + q * 8;
    bf16x8 a[4];
#pragma unroll
    for (int ks = 0; ks < 4; ++ks) a[ks] = cvt8(ap + 32 * ks);
#pragma unroll
    for (int ct = 0; ct < 8; ++ct) {
      f32x4 acc = {0.f, 0.f, 0.f, 0.f};
#pragma unroll
      for (int ks = 0; ks < 4; ++ks) {
        bf16x8 b = *(const bf16x8*)&Wb[((ct * 4 + ks) * 64 + lane) * 8];
        acc = __builtin_amdgcn_mfma_f32_16x16x32_bf16(a[ks], b, acc, 0, 0, 0);
      }
      int col = ct * 16 + m;
      float bb = bias ? bias[col] : 0.f;
#pragma unroll
      for (int j = 0; j < 4; ++j) {
        int row = r0 + q * 4 + j;
        if (row < rows) {
          if (OUTBF) outb[(size_t)row * DF + col] = f2bf(acc[j] + bb);
          else outf[(size_t)row * DF + col] = acc[j] + bb;
        }
      }
    }
  }
}

// ---------------- fused 4-output node GEMM (V,U,B,C) ----------------
__global__ __launch_bounds__(512) void k_gemm4_mfma(
    const float* __restrict__ h0, const short* __restrict__ Vf,
    const short* __restrict__ Uf, const short* __restrict__ Bf,
    const short* __restrict__ Cf, unsigned short* __restrict__ hVb,
    float* __restrict__ hU, unsigned short* __restrict__ hBb,
    unsigned short* __restrict__ hCb, int rows) {
  __shared__ short Wl[4 * 2048 * 8];  // 128 KB
  int tid = threadIdx.x;
  for (int s = tid; s < 2048; s += 512) {
    *(bf16x8*)&Wl[(size_t)s * 8] = *(const bf16x8*)&Vf[(size_t)s * 8];
    *(bf16x8*)&Wl[(size_t)(2048 + s) * 8] = *(const bf16x8*)&Uf[(size_t)s * 8];
    *(bf16x8*)&Wl[(size_t)(4096 + s) * 8] = *(const bf16x8*)&Bf[(size_t)s * 8];
    *(bf16x8*)&Wl[(size_t)(6144 + s) * 8] = *(const bf16x8*)&Cf[(size_t)s * 8];
  }
  __syncthreads();
  int wid = tid >> 6, lane = tid & 63, q = lane >> 4, m = lane & 15;
  int ntiles = (rows + 127) >> 7;
  for (int t = blockIdx.x; t < ntiles; t += gridDim.x) {
    int r0 = t * 128 + wid * 16;
    int rr = r0 + m;
    if (rr >= rows) rr = rows - 1;
    const float* ap = h0 + (size_t)rr * DF + q * 8;
    bf16x8 a[4];
#pragma unroll
    for (int ks = 0; ks < 4; ++ks) a[ks] = cvt8(ap + 32 * ks);
#pragma unroll
    for (int w = 0; w < 4; ++w) {
#pragma unroll
      for (int ct = 0; ct < 8; ++ct) {
        f32x4 acc = {0.f, 0.f, 0.f, 0.f};
#pragma unroll
        for (int ks = 0; ks < 4; ++ks) {
          bf16x8 b = *(const bf16x8*)&Wl[((w * 2048) + (ct * 4 + ks) * 64 + lane) * 8];
          acc = __builtin_amdgcn_mfma_f32_16x16x32_bf16(a[ks], b, acc, 0, 0, 0);
        }
        int col = ct * 16 + m;
#pragma unroll
        for (int j = 0; j < 4; ++j) {
          int row = r0 + q * 4 + j;
          if (row < rows) {
            if (w == 1) hU[(size_t)row * DF + col] = acc[j];
            else {
              unsigned short v = f2bf(acc[j]);
              unsigned short* o = (w == 0) ? hVb : ((w == 2) ? hBb : hCb);
              o[(size_t)row * DF + col] = v;
            }
          }
        }
      }
    }
  }
}

// ---------------- MFMA edge pass (graph-local): x = e@As^T + hB[dst] + hC[src] ----------------
template <int APPLY>
__global__ __launch_bounds__(512) void k_edge_mfma(
    unsigned short* __restrict__ e0u, const short* __restrict__ Af,
    const unsigned short* __restrict__ hBb, const unsigned short* __restrict__ hCb,
    const int* __restrict__ src, const int* __restrict__ dst,
    float* __restrict__ stat, int Eg) {
  __shared__ short Wb[2048 * 8];     // 32 KB
  __shared__ float xt[8][16 * 132];  // 66 KB
  int tid = threadIdx.x;
  for (int s = tid; s < 2048; s += 512)
    *(bf16x8*)&Wb[s * 8] = *(const bf16x8*)&Af[(size_t)s * 8];
  int wid = tid >> 6, lane = tid & 63, q = lane >> 4, m = lane & 15;
  int g = blockIdx.x & 7, sub = blockIdx.x >> 3, nsub = gridDim.x >> 3;
  int gbase = g * Eg, gend = gbase + Eg;
  int tpg = (Eg + 127) >> 7;
  float* xw = xt[wid];
  float ps0 = 0.f, ps1 = 0.f, pq0 = 0.f, pq1 = 0.f;
  __syncthreads();
  for (int t = sub; t < tpg; t += nsub) {
    int r0 = gbase + t * 128 + wid * 16;
    int edge = r0 + m;
    bool ok = edge < gend;
    int ec = ok ? edge : gend - 1;
    const unsigned short* ep = e0u + (size_t)ec * DF + q * 8;
    bf16x8 a[4];
#pragma unroll
    for (int ks = 0; ks < 4; ++ks) a[ks] = *(const bf16x8*)(ep + 32 * ks);
#pragma unroll
    for (int ct = 0; ct < 8; ++ct) {
      f32x4 acc = {0.f, 0.f, 0.f, 0.f};
#pragma unroll
      for (int ks = 0; ks < 4; ++ks) {
        bf16x8 b = *(const bf16x8*)&Wb[((ct * 4 + ks) * 64 + lane) * 8];
        acc = __builtin_amdgcn_mfma_f32_16x16x32_bf16(a[ks], b, acc, 0, 0, 0);
      }
#pragma unroll
      for (int j = 0; j < 4; ++j) xw[(q * 4 + j) * 132 + ct * 16 + m] = acc[j];
    }
    __syncthreads();
    int sidx = src[ec], didx = dst[ec];
    const unsigned short* pb = hBb + (size_t)didx * DF;
    const unsigned short* pc = hCb + (size_t)sidx * DF;
#pragma unroll
    for (int ks = 0; ks < 4; ++ks) {
      int c0 = q * 8 + 32 * ks;
      float* xp = &xw[m * 132 + c0];
      bf16x8 gb = *(const bf16x8*)(pb + c0);
      bf16x8 gc = *(const bf16x8*)(pc + c0);
      float x[8];
#pragma unroll
      for (int i = 0; i < 8; ++i)
        x[i] = xp[i] + bf2f((unsigned short)gb[i]) + bf2f((unsigned short)gc[i]);
      if (APPLY) {
        bf16x8 nv;
#pragma unroll
        for (int i = 0; i < 8; ++i) {
          float mm = stat[768 + c0 + i], iv = stat[896 + c0 + i];
          nv[i] = (short)f2bf(bf2f((unsigned short)a[ks][i]) + fmaxf((x[i] - mm) * iv, 0.f));
        }
        if (ok) *(bf16x8*)(e0u + (size_t)ec * DF + c0) = nv;
      } else {
#pragma unroll
        for (int i = 0; i < 8; ++i) xp[i] = ok ? x[i] : 0.f;
      }
    }
    if (!APPLY) {
      __syncthreads();
#pragma unroll 4
      for (int r = 0; r < 16; ++r) {
        float2 v = *(float2*)&xw[r * 132 + 2 * lane];
        ps0 += v.x; ps1 += v.y;
        pq0 += v.x * v.x; pq1 += v.y * v.y;
      }
    }
    __syncthreads();
  }
  if (!APPLY) {
    atomicAdd(&stat[512 + 2 * lane], ps0);
    atomicAdd(&stat[512 + 2 * lane + 1], ps1);
    atomicAdd(&stat[640 + 2 * lane], pq0);
    atomicAdd(&stat[640 + 2 * lane + 1], pq1);
  }
}

// ---------------- layer: m = hV[src]*sigmoid(e); segment_max (graph-local) ----------------
__global__ __launch_bounds__(256) void k_edge_max(
    const unsigned short* __restrict__ hVb, const unsigned short* __restrict__ e0u,
    const int* __restrict__ src, const int* __restrict__ dst,
    unsigned* __restrict__ agg_u, int Eg) {
  int g = blockIdx.x & 7, sub = blockIdx.x >> 3, nsub = gridDim.x >> 3;
  int gbase = g * Eg, gend = gbase + Eg;
  int tpg = (Eg + 127) >> 7;
  int tid = threadIdx.x;
  for (int t = sub; t < tpg; t += nsub) {
    int ebase = gbase + t * 128;
    for (int k = tid; k < 16384; k += 256) {
      int e = ebase + (k >> 7);
      if (e >= gend) break;
      int d = k & 127;
      float mm = bf2f(hVb[(size_t)src[e] * DF + d]) * sigm(bf2f(e0u[(size_t)e * DF + d]));
      atomicMax(&agg_u[(size_t)dst[e] * DF + d], enc_f(mm));
    }
  }
}

// tmp_h = hU + decode(agg); accumulate node BN stats
__global__ __launch_bounds__(128) void k_node_pre_bn(
    float* __restrict__ hU, const unsigned* __restrict__ agg_u,
    float* __restrict__ stat, int rows) {
  int tid = threadIdx.x;
  float ps = 0.f, pq = 0.f;
  for (int n = blockIdx.x; n < rows; n += gridDim.x) {
    size_t idx = (size_t)n * DF + tid;
    unsigned k = agg_u[idx];
    float a = (k == ENC_NEGINF) ? 0.f : dec_f(k);
    float t = hU[idx] + a;
    hU[idx] = t;
    ps += t; pq += t * t;
  }
  atomicAdd(&stat[tid], ps);
  atomicAdd(&stat[128 + tid], pq);
}

// finalize BN stats
__global__ void k_bn_finalize(float* __restrict__ stat, float nN, float nE) {
  int tid = threadIdx.x;
  if (tid < 128) {
    float mean = stat[tid] / nN;
    float var = stat[128 + tid] / nN - mean * mean;
    stat[256 + tid] = mean;
    stat[384 + tid] = rsqrtf(fmaxf(var, 0.f) + 1e-5f);
  } else {
    int d = tid - 128;
    float mean = stat[512 + d] / nE;
    float var = stat[640 + d] / nE - mean * mean;
    stat[768 + d] = mean;
    stat[896 + d] = rsqrtf(fmaxf(var, 0.f) + 1e-5f);
  }
}

__global__ __launch_bounds__(256) void k_node_update(
    float* __restrict__ h0, const float* __restrict__ hU,
    const float* __restrict__ stat, long long total) {
  long long i = (long long)blockIdx.x * blockDim.x + threadIdx.x;
  long long st = (long long)gridDim.x * blockDim.x;
  for (; i < total; i += st) {
    int d = (int)(i & 127);
    float t = (hU[i] - stat[256 + d]) * stat[384 + d];
    h0[i] += fmaxf(t, 0.f);
  }
}

// ---------------- GATv2 (graph-local) ----------------
__global__ __launch_bounds__(256) void k_gat_score(
    const unsigned short* __restrict__ fsb, const unsigned short* __restrict__ fdb,
    const int* __restrict__ src, const int* __restrict__ dst,
    const float* __restrict__ attn, float* __restrict__ score,
    unsigned* __restrict__ smax_u, int Eg) {
  int g = blockIdx.x & 7, sub = blockIdx.x >> 3, nsub = gridDim.x >> 3;
  int gbase = g * Eg, gend = gbase + Eg;
  int tpg = (Eg + 127) >> 7;
  int tid = threadIdx.x;
  for (int t = sub; t < tpg; t += nsub) {
    int ebase = gbase + t * 128;
    for (int k = tid; k < 1024; k += 256) {
      int e = ebase + (k >> 3);
      if (e >= gend) break;
      int mh = k & 7;
      int s = src[e], dn = dst[e];
      const unsigned short* ps = fsb + (size_t)s * DF + mh * 16;
      const unsigned short* pd = fdb + (size_t)dn * DF + mh * 16;
      const float* pa = attn + mh * 16;
      bf16x8 s0 = *(const bf16x8*)ps;
      bf16x8 s1 = *(const bf16x8*)(ps + 8);
      bf16x8 d0 = *(const bf16x8*)pd;
      bf16x8 d1 = *(const bf16x8*)(pd + 8);
      float acc = 0.f;
#pragma unroll
      for (int kk = 0; kk < 8; ++kk) {
        float z = bf2f((unsigned short)s0[kk]) + bf2f((unsigned short)d0[kk]);
        z = (z > 0.f) ? z : 0.2f * z;
        acc = fmaf(z, pa[kk], acc);
        float z2 = bf2f((unsigned short)s1[kk]) + bf2f((unsigned short)d1[kk]);
        z2 = (z2 > 0.f) ? z2 : 0.2f * z2;
        acc = fmaf(z2, pa[kk + 8], acc);
      }
      score[(size_t)e * 8 + mh] = acc;
      atomicMax(&smax_u[(size_t)dn * 8 + mh], enc_f(acc));
    }
  }
}

__global__ __launch_bounds__(256) void k_gat_p(
    float* __restrict__ score, const unsigned* __restrict__ smax_u,
    const int* __restrict__ dst, float* __restrict__ denom, int Eg) {
  int g = blockIdx.x & 7, sub = blockIdx.x >> 3, nsub = gridDim.x >> 3;
  int gbase = g * Eg, gend = gbase + Eg;
  int tpg = (Eg + 127) >> 7;
  int tid = threadIdx.x;
  for (int t = sub; t < tpg; t += nsub) {
    int ebase = gbase + t * 128;
    for (int k = tid; k < 1024; k += 256) {
      int e = ebase + (k >> 3);
      if (e >= gend) break;
      int mh = k & 7;
      int dn = dst[e];
      float p = __expf(score[(size_t)e * 8 + mh] - dec_f(smax_u[(size_t)dn * 8 + mh]));
      score[(size_t)e * 8 + mh] = p;
      atomicAdd(&denom[(size_t)dn * 8 + mh], p);
    }
  }
}

__global__ __launch_bounds__(256) void k_gat_rst(
    const float* __restrict__ score, const float* __restrict__ denom,
    const unsigned short* __restrict__ fsb, const int* __restrict__ src,
    const int* __restrict__ dst, float* __restrict__ rst, int Eg) {
  int g = blockIdx.x & 7, sub = blockIdx.x >> 3, nsub = gridDim.x >> 3;
  int gbase = g * Eg, gend = gbase + Eg;
  int tpg = (Eg + 127) >> 7;
  int tid = threadIdx.x;
  for (int t = sub; t < tpg; t += nsub) {
    int ebase = gbase + t * 128;
    for (int k = tid; k < 16384; k += 256) {
      int e = ebase + (k >> 7);
      if (e >= gend) break;
      int d = k & 127, mh = d >> 4;
      int s = src[e], dn = dst[e];
      float a = score[(size_t)e * 8 + mh] / denom[(size_t)dn * 8 + mh];
      atomicAdd(&rst[(size_t)dn * DF + d], a * bf2f(fsb[(size_t)s * DF + d]));
    }
  }
}

// bias2 = O_b + gat_bias @ O_w^T
__global__ void k_bias2(const float* __restrict__ gat_bias,
                        const float* __restrict__ O_w,
                        const float* __restrict__ O_b, float* __restrict__ bias2) {
  int d = threadIdx.x;
  float acc = O_b[d];
  for (int k = 0; k < DF; ++k) acc = fmaf(gat_bias[k], O_w[(size_t)d * DF + k], acc);
  bias2[d] = acc;
}

// ---------------- readout ----------------
__global__ __launch_bounds__(128) void k_moy(
    const unsigned short* __restrict__ h2b, const int* __restrict__ ng,
    float* __restrict__ moy, float* __restrict__ cnt, int rows) {
  int tid = threadIdx.x;
  int per = (rows + gridDim.x - 1) / gridDim.x;
  int n0 = blockIdx.x * per;
  int n1 = min(rows, n0 + per);
  if (n0 >= n1) return;
  int cur = ng[n0];
  float acc = 0.f; int c = 0;
  for (int n = n0; n < n1; ++n) {
    int g = ng[n];
    if (g != cur) {
      atomicAdd(&moy[cur * DF + tid], acc);
      if (tid == 0) atomicAdd(&cnt[cur], (float)c);
      acc = 0.f; c = 0; cur = g;
    }
    acc += bf2f(h2b[(size_t)n * DF + tid]);
    ++c;
  }
  atomicAdd(&moy[cur * DF + tid], acc);
  if (tid == 0) atomicAdd(&cnt[cur], (float)c);
}

__global__ void k_moy_div(const float* __restrict__ moy, const float* __restrict__ cnt,
                          unsigned short* __restrict__ moyb) {
  int i = blockIdx.x * DF + threadIdx.x;
  moyb[i] = f2bf(moy[i] / cnt[blockIdx.x]);
}

// ---------------- fused MFMA head (graph-local, low register demand) ----------------
// ks-outer / ct-inner: one A-fragment (av) live at a time; c[8] persistent accs.
// Peak live ~ 32 acc + 4 av + b-window + addrs ~ 100 regs -> no scratch at 128 budget.
__global__ __launch_bounds__(512, 2) void k_final_mfma(
    const unsigned short* __restrict__ h2b, const unsigned short* __restrict__ moyb,
    const int* __restrict__ src, const int* __restrict__ dst,
    const short* __restrict__ W1f, const float* __restrict__ W1b,
    const float* __restrict__ W2, const float* __restrict__ W2b,
    float* __restrict__ out, int Eg) {
  __shared__ short Wb[6144 * 8];  // 96 KB
  int tid = threadIdx.x;
  for (int s = tid; s < 6144; s += 512)
    *(bf16x8*)&Wb[s * 8] = *(const bf16x8*)&W1f[(size_t)s * 8];
  __syncthreads();
  int wid = tid >> 6, lane = tid & 63, q = lane >> 4, m = lane & 15;
  int g = blockIdx.x & 7, sub = blockIdx.x >> 3, nsub = gridDim.x >> 3;
  int gbase = g * Eg, gend = gbase + Eg;
  int tpg = (Eg + 127) >> 7;  // 128 edges per block-tile (8 waves x 16)
  const unsigned short* mrow = moyb + (size_t)g * DF + q * 8;
  float w2b = W2b[0];
  for (int t = sub; t < tpg; t += nsub) {
    int r0 = gbase + t * 128 + wid * 16;
    int edge = r0 + m;
    int ec = (edge < gend) ? edge : gend - 1;
    int s = src[ec], d = dst[ec];
    const unsigned short* rs = h2b + (size_t)s * DF + q * 8;
    const unsigned short* rd = h2b + (size_t)d * DF + q * 8;
    f32x4 c0 = {0.f, 0.f, 0.f, 0.f}, c1 = c0, c2 = c0, c3 = c0;
    f32x4 c4 = c0, c5 = c0, c6 = c0, c7 = c0;
#pragma unroll
    for (int seg = 0; seg < 3; ++seg) {
      const unsigned short* base = (seg == 0) ? mrow : ((seg == 1) ? rs : rd);
#pragma unroll
      for (int kk = 0; kk < 4; ++kk) {
        int ks = seg * 4 + kk;
        bf16x8 av = *(const bf16x8*)(base + kk * 32);
        const short* wrow = &Wb[(ks * 64 + lane) * 8];
        c0 = __builtin_amdgcn_mfma_f32_16x16x32_bf16(av, *(const bf16x8*)(wrow + 0 * 12 * 64 * 8), c0, 0, 0, 0);
        c1 = __builtin_amdgcn_mfma_f32_16x16x32_bf16(av, *(const bf16x8*)(wrow + 1 * 12 * 64 * 8), c1, 0, 0, 0);
        c2 = __builtin_amdgcn_mfma_f32_16x16x32_bf16(av, *(const bf16x8*)(wrow + 2 * 12 * 64 * 8), c2, 0, 0, 0);
        c3 = __builtin_amdgcn_mfma_f32_16x16x32_bf16(av, *(const bf16x8*)(wrow + 3 * 12 * 64 * 8), c3, 0, 0, 0);
        c4 = __builtin_amdgcn_mfma_f32_16x16x32_bf16(av, *(const bf16x8*)(wrow + 4 * 12 * 64 * 8), c4, 0, 0, 0);
        c5 = __builtin_amdgcn_mfma_f32_16x16x32_bf16(av, *(const bf16x8*)(wrow + 5 * 12 * 64 * 8), c5, 0, 0, 0);
        c6 = __builtin_amdgcn_mfma_f32_16x16x32_bf16(av, *(const bf16x8*)(wrow + 6 * 12 * 64 * 8), c6, 0, 0, 0);
        c7 = __builtin_amdgcn_mfma_f32_16x16x32_bf16(av, *(const bf16x8*)(wrow + 7 * 12 * 64 * 8), c7, 0, 0, 0);
      }
    }
    float v0 = 0.f, v1 = 0.f, v2 = 0.f, v3 = 0.f;
#pragma unroll
    for (int ct = 0; ct < 8; ++ct) {
      f32x4 cc = (ct == 0) ? c0 : (ct == 1) ? c1 : (ct == 2) ? c2 : (ct == 3) ? c3
                 : (ct == 4) ? c4 : (ct == 5) ? c5 : (ct == 6) ? c6 : c7;
      int col = ct * 16 + m;
      float bb = W1b[col], ww = W2[col];
      v0 += fmaxf(cc[0] + bb, 0.f) * ww;
      v1 += fmaxf(cc[1] + bb, 0.f) * ww;
      v2 += fmaxf(cc[2] + bb, 0.f) * ww;
      v3 += fmaxf(cc[3] + bb, 0.f) * ww;
    }
#pragma unroll
    for (int mask = 1; mask <= 8; mask <<= 1) {
      v0 += __shfl_xor(v0, mask, 64);
      v1 += __shfl_xor(v1, mask, 64);
      v2 += __shfl_xor(v2, mask, 64);
      v3 += __shfl_xor(v3, mask, 64);
    }
    if (m == 0) {
      int rb = r0 + q * 4;
      if (rb < gend) out[rb] = sigm(v0 + w2b);
      if (rb + 1 < gend) out[rb + 1] = sigm(v1 + w2b);
      if (rb + 2 < gend) out[rb + 2] = sigm(v2 + w2b);
      if (rb + 3 < gend) out[rb + 3] = sigm(v3 + w2b);
    }
  }
}

extern "C" void kernel_launch(void* const* d_in, const int* in_sizes, int n_in,
                              void* d_out, int out_size, void* d_ws, size_t ws_size,
                              hipStream_t stream) {
  const float* h_in = (const float*)d_in[0];
  const float* e_in = (const float*)d_in[1];
  const int* src = (const int*)d_in[2];
  const int* dst = (const int*)d_in[3];
  const int* node_graph = (const int*)d_in[4];
  const int* edge_graph = (const int*)d_in[5];
  const float* emb_n_w = (const float*)d_in[6];
  const float* emb_n_b = (const float*)d_in[7];
  const float* emb_e_w = (const float*)d_in[8];
  const float* emb_e_b = (const float*)d_in[9];
  const float* Us = (const float*)d_in[10];
  const float* Vs = (const float*)d_in[11];
  const float* As = (const float*)d_in[12];
  const float* Bs = (const float*)d_in[13];
  const float* Cs = (const float*)d_in[14];
  const float* gat_src_w = (const float*)d_in[15];
  const float* gat_src_b = (const float*)d_in[16];
  const float* gat_dst_w = (const float*)d_in[17];
  const float* gat_dst_b = (const float*)d_in[18];
  const float* gat_attn = (const float*)d_in[19];
  const float* gat_bias = (const float*)d_in[20];
  const float* O_w = (const float*)d_in[21];
  const float* O_b = (const float*)d_in[22];
  const float* W1_w = (const float*)d_in[23];
  const float* W1_b = (const float*)d_in[24];
  const float* W2_w = (const float*)d_in[25];
  const float* W2_b = (const float*)d_in[26];
  float* out = (float*)d_out;

  const int N = in_sizes[0] / 64;   // 30000
  const int E = in_sizes[1] / 16;   // 360000
  const int Eg = E / NGRAPH;        // 45000

  const size_t sz_e0 = (size_t)E * DF * sizeof(unsigned short);
  const size_t sz_node = (size_t)N * DF * sizeof(float);
  const size_t sz_nodeb = (size_t)N * DF * sizeof(unsigned short);
  const size_t sz_score = (size_t)E * 8 * sizeof(float);
  const size_t sz_n8 = (size_t)N * 8 * sizeof(float);
  const size_t sz_wfrag = 18 * 2048 * 8 * sizeof(short);   // 576 KB
  const size_t sz_w1frag = 6144 * 8 * sizeof(short);       // 96 KB
  const size_t sz_misc = 4096 * sizeof(float);
  const size_t needed = sz_e0 + 3 * sz_node + 4 * sz_nodeb + sz_score + 2 * sz_n8 +
                        sz_wfrag + sz_w1frag + sz_misc;
  if (ws_size < needed) {
    k_fill_u32<<<256, 256, 0, stream>>>((unsigned*)out, 0xBF800000u, (long long)out_size);
    return;
  }

  char* wp = (char*)d_ws;
  auto alloc = [&](size_t bytes) { void* p = wp; wp += bytes; return p; };
  unsigned short* e0u = (unsigned short*)alloc(sz_e0);
  float* h0 = (float*)alloc(sz_node);
  float* hU = (float*)alloc(sz_node);
  unsigned* agg_u = (unsigned*)alloc(sz_node);  // also rst (f32)
  unsigned short* hVb = (unsigned short*)alloc(sz_nodeb);
  unsigned short* hBb = (unsigned short*)alloc(sz_nodeb);
  unsigned short* hCb = (unsigned short*)alloc(sz_nodeb);
  unsigned short* h2b = (unsigned short*)alloc(sz_nodeb);
  float* score = (float*)alloc(sz_score);
  unsigned* smax_u = (unsigned*)alloc(sz_n8);
  float* denom = (float*)alloc(sz_n8);
  short* wfrag = (short*)alloc(sz_wfrag);
  short* w1frag = (short*)alloc(sz_w1frag);
  float* misc = (float*)alloc(sz_misc);
  float* stat = misc;                                     // [0,1024)
  float* bias2 = misc + 1024;                             // [1024,1152)
  float* moy = misc + 1152;                               // [1152,2176)
  float* cnt = misc + 2176;                               // [2176,2184)
  unsigned short* moyb = (unsigned short*)(misc + 2304);  // 1024 bf16

  // frag-weight indices: U_l=l, V_l=3+l, A_l=6+l, B_l=9+l, C_l=12+l, gsw=15, gdw=16, Ow=17
  auto WF = [&](int idx) { return wfrag + (size_t)idx * 2048 * 8; };

  k_wconv<<<18, 512, 0, stream>>>(Us, Vs, As, Bs, Cs, gat_src_w, gat_dst_w, O_w, wfrag);
  k_wconv_w1<<<12, 512, 0, stream>>>(W1_w, w1frag);

  const int gN = (N + 127) / 128;
  k_node_embed<<<2048, 128, 0, stream>>>(h_in, emb_n_w, emb_n_b, h0, N);
  k_edge_embed<<<4096, 128, 0, stream>>>(e_in, emb_e_w, emb_e_b, e0u, E);

  for (int l = 0; l < 3; ++l) {
    k_gemm4_mfma<<<gN, 512, 0, stream>>>(h0, WF(3 + l), WF(l), WF(9 + l), WF(12 + l),
                                         hVb, hU, hBb, hCb, N);
    k_fill_u32<<<4096, 256, 0, stream>>>(agg_u, ENC_NEGINF, (long long)N * DF);
    k_fill_u32<<<4, 256, 0, stream>>>((unsigned*)stat, 0u, 1024);
    k_edge_max<<<512, 256, 0, stream>>>(hVb, e0u, src, dst, agg_u, Eg);
    k_node_pre_bn<<<512, 128, 0, stream>>>(hU, agg_u, stat, N);
    k_edge_mfma<0><<<256, 512, 0, stream>>>(e0u, WF(6 + l), hBb, hCb, src, dst, stat, Eg);
    k_bn_finalize<<<1, 256, 0, stream>>>(stat, (float)N, (float)E);
    k_node_update<<<2048, 256, 0, stream>>>(h0, hU, stat, (long long)N * DF);
    k_edge_mfma<1><<<256, 512, 0, stream>>>(e0u, WF(6 + l), hBb, hCb, src, dst, stat, Eg);
  }

  // GATv2: fs -> hVb, fd -> hBb
  k_gemm_mfma<1><<<gN, 512, 0, stream>>>(h0, WF(15), gat_src_b, hVb, N);
  k_gemm_mfma<1><<<gN, 512, 0, stream>>>(h0, WF(16), gat_dst_b, hBb, N);
  float* rst = (float*)agg_u;
  k_fill_u32<<<256, 256, 0, stream>>>(smax_u, ENC_NEGINF, (long long)N * 8);
  k_fill_u32<<<256, 256, 0, stream>>>((unsigned*)denom, 0u, (long long)N * 8);
  k_fill_u32<<<4096, 256, 0, stream>>>((unsigned*)rst, 0u, (long long)N * DF);
  k_fill_u32<<<2, 256, 0, stream>>>((unsigned*)moy, 0u, 1032);
  k_gat_score<<<512, 256, 0, stream>>>(hVb, hBb, src, dst, gat_attn, score, smax_u, Eg);
  k_gat_p<<<512, 256, 0, stream>>>(score, smax_u, dst, denom, Eg);
  k_gat_rst<<<512, 256, 0, stream>>>(score, denom, hVb, src, dst, rst, Eg);
  k_bias2<<<1, 128, 0, stream>>>(gat_bias, O_w, O_b, bias2);
  k_gemm_mfma<1><<<gN, 512, 0, stream>>>(rst, WF(17), bias2, h2b, N);  // h2

  // readout
  k_moy<<<128, 128, 0, stream>>>(h2b, node_graph, moy, cnt, N);
  k_moy_div<<<8, 128, 0, stream>>>(moy, cnt, moyb);
  k_final_mfma<<<256, 512, 0, stream>>>(h2b, moyb, src, dst, w1frag, W1_b, W2_w,
                                        W2_b, out, Eg);
}

// Round 8
// 2096.071 us; speedup vs baseline: 1.2250x; 1.0806x over previous
//
#include <hip/hip_runtime.h>

#define DF 128
#define NGRAPH 8

typedef __attribute__((ext_vector_type(8))) short bf16x8;
typedef __attribute__((ext_vector_type(4))) float f32x4;

__device__ __forceinline__ float sigm(float x) { return 1.f / (1.f + __expf(-x)); }
__device__ __forceinline__ unsigned short f2bf(float f) {  // RNE f32->bf16
  unsigned u = __float_as_uint(f);
  u += 0x7FFFu + ((u >> 16) & 1u);
  return (unsigned short)(u >> 16);
}
__device__ __forceinline__ float bf2f(unsigned short u) {
  return __uint_as_float(((unsigned)u) << 16);
}

// load 8 consecutive f32 (32B-aligned) -> bf16x8
__device__ __forceinline__ bf16x8 cvt8(const float* __restrict__ p) {
  float4 a = *(const float4*)p;
  float4 b = *(const float4*)(p + 4);
  bf16x8 r;
  r[0] = (short)f2bf(a.x); r[1] = (short)f2bf(a.y);
  r[2] = (short)f2bf(a.z); r[3] = (short)f2bf(a.w);
  r[4] = (short)f2bf(b.x); r[5] = (short)f2bf(b.y);
  r[6] = (short)f2bf(b.z); r[7] = (short)f2bf(b.w);
  return r;
}

// ---------------- generic fill ----------------
__global__ void k_fill_u32(unsigned* __restrict__ p, unsigned v, long long n) {
  long long i = (long long)blockIdx.x * blockDim.x + threadIdx.x;
  long long st = (long long)gridDim.x * blockDim.x;
  for (; i < n; i += st) p[i] = v;
}

// ---------------- CSR build (dst-sorted edge lists) ----------------
__global__ void k_deg(const int* __restrict__ dst, unsigned* __restrict__ deg, int E) {
  int i = blockIdx.x * blockDim.x + threadIdx.x;
  int st = gridDim.x * blockDim.x;
  for (; i < E; i += st) atomicAdd(&deg[dst[i]], 1u);
}

__global__ __launch_bounds__(1024) void k_scan(
    const unsigned* __restrict__ deg, unsigned* __restrict__ rowptr,
    unsigned* __restrict__ cursor, int N) {
  __shared__ unsigned part[1024];
  int t = threadIdx.x;
  int per = (N + 1023) >> 10;
  int s0 = t * per, s1 = min(N, s0 + per);
  unsigned s = 0;
  for (int i = s0; i < s1; ++i) s += deg[i];
  part[t] = s;
  __syncthreads();
  for (int off = 1; off < 1024; off <<= 1) {
    unsigned v = (t >= off) ? part[t - off] : 0u;
    __syncthreads();
    part[t] += v;
    __syncthreads();
  }
  unsigned base = (t == 0) ? 0u : part[t - 1];
  for (int i = s0; i < s1; ++i) {
    rowptr[i] = base;
    cursor[i] = base;
    base += deg[i];
  }
  if (t == 1023) rowptr[N] = part[1023];
}

__global__ void k_scatter(const int* __restrict__ dst, unsigned* __restrict__ cursor,
                          int* __restrict__ eidb, int E) {
  int i = blockIdx.x * blockDim.x + threadIdx.x;
  int st = gridDim.x * blockDim.x;
  for (; i < E; i += st) {
    unsigned p = atomicAdd(&cursor[dst[i]], 1u);
    eidb[p] = i;
  }
}

// ---------------- weight pre-conversion to MFMA fragment order ----------------
__global__ __launch_bounds__(512) void k_wconv(
    const float* __restrict__ Us, const float* __restrict__ Vs,
    const float* __restrict__ As, const float* __restrict__ Bs,
    const float* __restrict__ Cs, const float* __restrict__ gsw,
    const float* __restrict__ gdw, const float* __restrict__ Ow,
    short* __restrict__ out) {
  int b = blockIdx.x;
  const float* W;
  if (b < 3) W = Us + b * 16384;
  else if (b < 6) W = Vs + (b - 3) * 16384;
  else if (b < 9) W = As + (b - 6) * 16384;
  else if (b < 12) W = Bs + (b - 9) * 16384;
  else if (b < 15) W = Cs + (b - 12) * 16384;
  else if (b == 15) W = gsw;
  else if (b == 16) W = gdw;
  else W = Ow;
  short* o = out + (size_t)b * 2048 * 8;
  for (int s = threadIdx.x; s < 2048; s += 512) {
    int ct = s >> 8, ks = (s >> 6) & 3, l = s & 63;
    int row = ct * 16 + (l & 15), k0 = ks * 32 + (l >> 4) * 8;
    *(bf16x8*)&o[s * 8] = cvt8(W + (size_t)row * DF + k0);
  }
}

__global__ __launch_bounds__(512) void k_wconv_w1(const float* __restrict__ W1,
                                                  short* __restrict__ out) {
  int s = blockIdx.x * 512 + threadIdx.x;  // grid 12 -> 6144 slots
  int ct = s / 768, ks = (s >> 6) % 12, l = s & 63;
  int row = ct * 16 + (l & 15), k0 = ks * 32 + (l >> 4) * 8;
  *(bf16x8*)&out[(size_t)s * 8] = cvt8(W1 + (size_t)row * 384 + k0);
}

// ---------------- embeddings ----------------
__global__ __launch_bounds__(128) void k_node_embed(
    const float* __restrict__ hin, const float* __restrict__ w,
    const float* __restrict__ b, float* __restrict__ h0, int rows) {
  __shared__ float Wt[64 * DF];
  __shared__ float ar[4][64];
  int tid = threadIdx.x;
  for (int i = tid; i < 64 * DF; i += 128) Wt[(i & 63) * DF + (i >> 6)] = w[i];
  float bb = b[tid];
  __syncthreads();
  for (int r0 = blockIdx.x * 4; r0 < rows; r0 += gridDim.x * 4) {
    for (int i = tid; i < 256; i += 128) ar[i >> 6][i & 63] = hin[(size_t)r0 * 64 + i];
    __syncthreads();
    float a0 = bb, a1 = bb, a2 = bb, a3 = bb;
#pragma unroll 8
    for (int k = 0; k < 64; ++k) {
      float wv = Wt[k * DF + tid];
      a0 = fmaf(ar[0][k], wv, a0); a1 = fmaf(ar[1][k], wv, a1);
      a2 = fmaf(ar[2][k], wv, a2); a3 = fmaf(ar[3][k], wv, a3);
    }
    h0[(size_t)r0 * DF + tid] = a0;
    h0[(size_t)(r0 + 1) * DF + tid] = a1;
    h0[(size_t)(r0 + 2) * DF + tid] = a2;
    h0[(size_t)(r0 + 3) * DF + tid] = a3;
    __syncthreads();
  }
}

__global__ __launch_bounds__(128) void k_edge_embed(
    const float* __restrict__ ein, const float* __restrict__ w,
    const float* __restrict__ b, unsigned short* __restrict__ e0u, int rows) {
  __shared__ float Wt[16 * DF];
  __shared__ float ar[4][16];
  int tid = threadIdx.x;
  for (int i = tid; i < 16 * DF; i += 128) Wt[(i & 15) * DF + (i >> 4)] = w[i];
  float bb = b[tid];
  __syncthreads();
  for (int r0 = blockIdx.x * 4; r0 < rows; r0 += gridDim.x * 4) {
    if (tid < 64) ar[tid >> 4][tid & 15] = ein[(size_t)r0 * 16 + tid];
    __syncthreads();
    float a0 = bb, a1 = bb, a2 = bb, a3 = bb;
#pragma unroll
    for (int k = 0; k < 16; ++k) {
      float wv = Wt[k * DF + tid];
      a0 = fmaf(ar[0][k], wv, a0); a1 = fmaf(ar[1][k], wv, a1);
      a2 = fmaf(ar[2][k], wv, a2); a3 = fmaf(ar[3][k], wv, a3);
    }
    e0u[(size_t)r0 * DF + tid] = f2bf(a0);
    e0u[(size_t)(r0 + 1) * DF + tid] = f2bf(a1);
    e0u[(size_t)(r0 + 2) * DF + tid] = f2bf(a2);
    e0u[(size_t)(r0 + 3) * DF + tid] = f2bf(a3);
    __syncthreads();
  }
}

// ---------------- MFMA [rows,128] @ W^T (+bias), frag weights ----------------
template <int OUTBF>
__global__ __launch_bounds__(512) void k_gemm_mfma(
    const float* __restrict__ A, const short* __restrict__ Wf,
    const float* __restrict__ bias, void* __restrict__ outv, int rows) {
  __shared__ short Wb[2048 * 8];  // 32 KB
  int tid = threadIdx.x;
  for (int s = tid; s < 2048; s += 512)
    *(bf16x8*)&Wb[s * 8] = *(const bf16x8*)&Wf[(size_t)s * 8];
  __syncthreads();
  float* outf = (float*)outv;
  unsigned short* outb = (unsigned short*)outv;
  int wid = tid >> 6, lane = tid & 63, q = lane >> 4, m = lane & 15;
  int ntiles = (rows + 127) >> 7;
  for (int t = blockIdx.x; t < ntiles; t += gridDim.x) {
    int r0 = t * 128 + wid * 16;
    int rr = r0 + m;
    if (rr >= rows) rr = rows - 1;
    const float* ap = A + (size_t)rr * DF + q * 8;
    bf16x8 a[4];
#pragma unroll
    for (int ks = 0; ks < 4; ++ks) a[ks] = cvt8(ap + 32 * ks);
#pragma unroll
    for (int ct = 0; ct < 8; ++ct) {
      f32x4 acc = {0.f, 0.f, 0.f, 0.f};
#pragma unroll
      for (int ks = 0; ks < 4; ++ks) {
        bf16x8 b = *(const bf16x8*)&Wb[((ct * 4 + ks) * 64 + lane) * 8];
        acc = __builtin_amdgcn_mfma_f32_16x16x32_bf16(a[ks], b, acc, 0, 0, 0);
      }
      int col = ct * 16 + m;
      float bb = bias ? bias[col] : 0.f;
#pragma unroll
      for (int j = 0; j < 4; ++j) {
        int row = r0 + q * 4 + j;
        if (row < rows) {
          if (OUTBF) outb[(size_t)row * DF + col] = f2bf(acc[j] + bb);
          else outf[(size_t)row * DF + col] = acc[j] + bb;
        }
      }
    }
  }
}

// ---------------- fused 4-output node GEMM (V,U,B,C) ----------------
__global__ __launch_bounds__(512) void k_gemm4_mfma(
    const float* __restrict__ h0, const short* __restrict__ Vf,
    const short* __restrict__ Uf, const short* __restrict__ Bf,
    const short* __restrict__ Cf, unsigned short* __restrict__ hVb,
    float* __restrict__ hU, unsigned short* __restrict__ hBb,
    unsigned short* __restrict__ hCb, int rows) {
  __shared__ short Wl[4 * 2048 * 8];  // 128 KB
  int tid = threadIdx.x;
  for (int s = tid; s < 2048; s += 512) {
    *(bf16x8*)&Wl[(size_t)s * 8] = *(const bf16x8*)&Vf[(size_t)s * 8];
    *(bf16x8*)&Wl[(size_t)(2048 + s) * 8] = *(const bf16x8*)&Uf[(size_t)s * 8];
    *(bf16x8*)&Wl[(size_t)(4096 + s) * 8] = *(const bf16x8*)&Bf[(size_t)s * 8];
    *(bf16x8*)&Wl[(size_t)(6144 + s) * 8] = *(const bf16x8*)&Cf[(size_t)s * 8];
  }
  __syncthreads();
  int wid = tid >> 6, lane = tid & 63, q = lane >> 4, m = lane & 15;
  int ntiles = (rows + 127) >> 7;
  for (int t = blockIdx.x; t < ntiles; t += gridDim.x) {
    int r0 = t * 128 + wid * 16;
    int rr = r0 + m;
    if (rr >= rows) rr = rows - 1;
    const float* ap = h0 + (size_t)rr * DF + q * 8;
    bf16x8 a[4];
#pragma unroll
    for (int ks = 0; ks < 4; ++ks) a[ks] = cvt8(ap + 32 * ks);
#pragma unroll
    for (int w = 0; w < 4; ++w) {
#pragma unroll
      for (int ct = 0; ct < 8; ++ct) {
        f32x4 acc = {0.f, 0.f, 0.f, 0.f};
#pragma unroll
        for (int ks = 0; ks < 4; ++ks) {
          bf16x8 b = *(const bf16x8*)&Wl[((w * 2048) + (ct * 4 + ks) * 64 + lane) * 8];
          acc = __builtin_amdgcn_mfma_f32_16x16x32_bf16(a[ks], b, acc, 0, 0, 0);
        }
        int col = ct * 16 + m;
#pragma unroll
        for (int j = 0; j < 4; ++j) {
          int row = r0 + q * 4 + j;
          if (row < rows) {
            if (w == 1) hU[(size_t)row * DF + col] = acc[j];
            else {
              unsigned short v = f2bf(acc[j]);
              unsigned short* o = (w == 0) ? hVb : ((w == 2) ? hBb : hCb);
              o[(size_t)row * DF + col] = v;
            }
          }
        }
      }
    }
  }
}

// ---------------- MFMA edge pass (graph-local): x = e@As^T + hB[dst] + hC[src] ----------------
template <int APPLY>
__global__ __launch_bounds__(512) void k_edge_mfma(
    unsigned short* __restrict__ e0u, const short* __restrict__ Af,
    const unsigned short* __restrict__ hBb, const unsigned short* __restrict__ hCb,
    const int* __restrict__ src, const int* __restrict__ dst,
    float* __restrict__ stat, int Eg) {
  __shared__ short Wb[2048 * 8];     // 32 KB
  __shared__ float xt[8][16 * 132];  // 66 KB
  int tid = threadIdx.x;
  for (int s = tid; s < 2048; s += 512)
    *(bf16x8*)&Wb[s * 8] = *(const bf16x8*)&Af[(size_t)s * 8];
  int wid = tid >> 6, lane = tid & 63, q = lane >> 4, m = lane & 15;
  int g = blockIdx.x & 7, sub = blockIdx.x >> 3, nsub = gridDim.x >> 3;
  int gbase = g * Eg, gend = gbase + Eg;
  int tpg = (Eg + 127) >> 7;
  float* xw = xt[wid];
  float ps0 = 0.f, ps1 = 0.f, pq0 = 0.f, pq1 = 0.f;
  __syncthreads();
  for (int t = sub; t < tpg; t += nsub) {
    int r0 = gbase + t * 128 + wid * 16;
    int edge = r0 + m;
    bool ok = edge < gend;
    int ec = ok ? edge : gend - 1;
    const unsigned short* ep = e0u + (size_t)ec * DF + q * 8;
    bf16x8 a[4];
#pragma unroll
    for (int ks = 0; ks < 4; ++ks) a[ks] = *(const bf16x8*)(ep + 32 * ks);
#pragma unroll
    for (int ct = 0; ct < 8; ++ct) {
      f32x4 acc = {0.f, 0.f, 0.f, 0.f};
#pragma unroll
      for (int ks = 0; ks < 4; ++ks) {
        bf16x8 b = *(const bf16x8*)&Wb[((ct * 4 + ks) * 64 + lane) * 8];
        acc = __builtin_amdgcn_mfma_f32_16x16x32_bf16(a[ks], b, acc, 0, 0, 0);
      }
#pragma unroll
      for (int j = 0; j < 4; ++j) xw[(q * 4 + j) * 132 + ct * 16 + m] = acc[j];
    }
    __syncthreads();
    int sidx = src[ec], didx = dst[ec];
    const unsigned short* pb = hBb + (size_t)didx * DF;
    const unsigned short* pc = hCb + (size_t)sidx * DF;
#pragma unroll
    for (int ks = 0; ks < 4; ++ks) {
      int c0 = q * 8 + 32 * ks;
      float* xp = &xw[m * 132 + c0];
      bf16x8 gb = *(const bf16x8*)(pb + c0);
      bf16x8 gc = *(const bf16x8*)(pc + c0);
      float x[8];
#pragma unroll
      for (int i = 0; i < 8; ++i)
        x[i] = xp[i] + bf2f((unsigned short)gb[i]) + bf2f((unsigned short)gc[i]);
      if (APPLY) {
        bf16x8 nv;
#pragma unroll
        for (int i = 0; i < 8; ++i) {
          float mm = stat[768 + c0 + i], iv = stat[896 + c0 + i];
          nv[i] = (short)f2bf(bf2f((unsigned short)a[ks][i]) + fmaxf((x[i] - mm) * iv, 0.f));
        }
        if (ok) *(bf16x8*)(e0u + (size_t)ec * DF + c0) = nv;
      } else {
#pragma unroll
        for (int i = 0; i < 8; ++i) xp[i] = ok ? x[i] : 0.f;
      }
    }
    if (!APPLY) {
      __syncthreads();
#pragma unroll 4
      for (int r = 0; r < 16; ++r) {
        float2 v = *(float2*)&xw[r * 132 + 2 * lane];
        ps0 += v.x; ps1 += v.y;
        pq0 += v.x * v.x; pq1 += v.y * v.y;
      }
    }
    __syncthreads();
  }
  if (!APPLY) {
    atomicAdd(&stat[512 + 2 * lane], ps0);
    atomicAdd(&stat[512 + 2 * lane + 1], ps1);
    atomicAdd(&stat[640 + 2 * lane], pq0);
    atomicAdd(&stat[640 + 2 * lane + 1], pq1);
  }
}

// ---------------- node-major segment max + hU update + BN stats (no atomics) ----------------
// wave per node; lane owns feats 2*lane, 2*lane+1.
__global__ __launch_bounds__(256) void k_node_agg(
    float* __restrict__ hU, const unsigned short* __restrict__ hVb,
    const unsigned short* __restrict__ e0u, const int* __restrict__ src,
    const unsigned* __restrict__ rowptr, const int* __restrict__ eidb,
    float* __restrict__ stat, int Ngr) {
  int tid = threadIdx.x, wid = tid >> 6, lane = tid & 63;
  int g = blockIdx.x & 7, sub = blockIdx.x >> 3, nsub = gridDim.x >> 3;
  float ps0 = 0.f, ps1 = 0.f, pq0 = 0.f, pq1 = 0.f;
  for (int nn = sub * 4 + wid; nn < Ngr; nn += nsub * 4) {
    int n = g * Ngr + nn;
    unsigned r0 = rowptr[n], r1 = rowptr[n + 1];
    float m0 = -3.4e38f, m1 = -3.4e38f;
    for (unsigned r = r0; r < r1; ++r) {
      int e = eidb[r];
      unsigned hv2 = *(const unsigned*)&hVb[(size_t)src[e] * DF + 2 * lane];
      unsigned ev2 = *(const unsigned*)&e0u[(size_t)e * DF + 2 * lane];
      float v0 = bf2f((unsigned short)(hv2 & 0xffffu)) * sigm(bf2f((unsigned short)(ev2 & 0xffffu)));
      float v1 = bf2f((unsigned short)(hv2 >> 16)) * sigm(bf2f((unsigned short)(ev2 >> 16)));
      m0 = fmaxf(m0, v0);
      m1 = fmaxf(m1, v1);
    }
    if (r1 == r0) { m0 = 0.f; m1 = 0.f; }
    size_t idx = (size_t)n * DF + 2 * lane;
    float2 hu = *(float2*)&hU[idx];
    float t0 = hu.x + m0, t1 = hu.y + m1;
    hu.x = t0; hu.y = t1;
    *(float2*)&hU[idx] = hu;
    ps0 += t0; ps1 += t1;
    pq0 += t0 * t0; pq1 += t1 * t1;
  }
  atomicAdd(&stat[2 * lane], ps0);
  atomicAdd(&stat[2 * lane + 1], ps1);
  atomicAdd(&stat[128 + 2 * lane], pq0);
  atomicAdd(&stat[128 + 2 * lane + 1], pq1);
}

// finalize BN stats
__global__ void k_bn_finalize(float* __restrict__ stat, float nN, float nE) {
  int tid = threadIdx.x;
  if (tid < 128) {
    float mean = stat[tid] / nN;
    float var = stat[128 + tid] / nN - mean * mean;
    stat[256 + tid] = mean;
    stat[384 + tid] = rsqrtf(fmaxf(var, 0.f) + 1e-5f);
  } else {
    int d = tid - 128;
    float mean = stat[512 + d] / nE;
    float var = stat[640 + d] / nE - mean * mean;
    stat[768 + d] = mean;
    stat[896 + d] = rsqrtf(fmaxf(var, 0.f) + 1e-5f);
  }
}

__global__ __launch_bounds__(256) void k_node_update(
    float* __restrict__ h0, const float* __restrict__ hU,
    const float* __restrict__ stat, long long total) {
  long long i = (long long)blockIdx.x * blockDim.x + threadIdx.x;
  long long st = (long long)gridDim.x * blockDim.x;
  for (; i < total; i += st) {
    int d = (int)(i & 127);
    float t = (hU[i] - stat[256 + d]) * stat[384 + d];
    h0[i] += fmaxf(t, 0.f);
  }
}

// ---------------- GATv2 score (edge-major, no atomics) ----------------
__global__ __launch_bounds__(256) void k_gat_score(
    const unsigned short* __restrict__ fsb, const unsigned short* __restrict__ fdb,
    const int* __restrict__ src, const int* __restrict__ dst,
    const float* __restrict__ attn, float* __restrict__ score, int Eg) {
  int g = blockIdx.x & 7, sub = blockIdx.x >> 3, nsub = gridDim.x >> 3;
  int gbase = g * Eg, gend = gbase + Eg;
  int tpg = (Eg + 127) >> 7;
  int tid = threadIdx.x;
  for (int t = sub; t < tpg; t += nsub) {
    int ebase = gbase + t * 128;
    for (int k = tid; k < 1024; k += 256) {
      int e = ebase + (k >> 3);
      if (e >= gend) break;
      int mh = k & 7;
      int s = src[e], dn = dst[e];
      const unsigned short* ps = fsb + (size_t)s * DF + mh * 16;
      const unsigned short* pd = fdb + (size_t)dn * DF + mh * 16;
      const float* pa = attn + mh * 16;
      bf16x8 s0 = *(const bf16x8*)ps;
      bf16x8 s1 = *(const bf16x8*)(ps + 8);
      bf16x8 d0 = *(const bf16x8*)pd;
      bf16x8 d1 = *(const bf16x8*)(pd + 8);
      float acc = 0.f;
#pragma unroll
      for (int kk = 0; kk < 8; ++kk) {
        float z = bf2f((unsigned short)s0[kk]) + bf2f((unsigned short)d0[kk]);
        z = (z > 0.f) ? z : 0.2f * z;
        acc = fmaf(z, pa[kk], acc);
        float z2 = bf2f((unsigned short)s1[kk]) + bf2f((unsigned short)d1[kk]);
        z2 = (z2 > 0.f) ? z2 : 0.2f * z2;
        acc = fmaf(z2, pa[kk + 8], acc);
      }
      score[(size_t)e * 8 + mh] = acc;
    }
  }
}

// ---------------- GATv2 node reduction: softmax + weighted sum (no atomics) ----------------
// wave per node. heads: lane>>3; slots: lane&7. feats 2*lane,2*lane+1 (head = lane>>3).
__global__ __launch_bounds__(256) void k_gat_node(
    const float* __restrict__ score, const unsigned short* __restrict__ fsb,
    const int* __restrict__ src, const unsigned* __restrict__ rowptr,
    const int* __restrict__ eidb, float* __restrict__ rst, int Ngr) {
  int tid = threadIdx.x, wid = tid >> 6, lane = tid & 63;
  int g = blockIdx.x & 7, sub = blockIdx.x >> 3, nsub = gridDim.x >> 3;
  int head = lane >> 3, slot = lane & 7;
  for (int nn = sub * 4 + wid; nn < Ngr; nn += nsub * 4) {
    int n = g * Ngr + nn;
    unsigned r0 = rowptr[n], r1 = rowptr[n + 1];
    float hm = -3.4e38f;
    for (unsigned r = r0 + slot; r < r1; r += 8)
      hm = fmaxf(hm, score[(size_t)eidb[r] * 8 + head]);
#pragma unroll
    for (int mk = 1; mk < 8; mk <<= 1) hm = fmaxf(hm, __shfl_xor(hm, mk, 64));
    float dn = 0.f;
    for (unsigned r = r0 + slot; r < r1; r += 8)
      dn += __expf(score[(size_t)eidb[r] * 8 + head] - hm);
#pragma unroll
    for (int mk = 1; mk < 8; mk <<= 1) dn += __shfl_xor(dn, mk, 64);
    float inv = (r1 > r0) ? 1.f / dn : 0.f;
    float a0 = 0.f, a1 = 0.f;
    for (unsigned r = r0; r < r1; ++r) {
      int e = eidb[r];
      float a = __expf(score[(size_t)e * 8 + head] - hm) * inv;
      unsigned fs2 = *(const unsigned*)&fsb[(size_t)src[e] * DF + 2 * lane];
      a0 = fmaf(a, bf2f((unsigned short)(fs2 & 0xffffu)), a0);
      a1 = fmaf(a, bf2f((unsigned short)(fs2 >> 16)), a1);
    }
    float2 o;
    o.x = a0; o.y = a1;
    *(float2*)&rst[(size_t)n * DF + 2 * lane] = o;
  }
}

// bias2 = O_b + gat_bias @ O_w^T
__global__ void k_bias2(const float* __restrict__ gat_bias,
                        const float* __restrict__ O_w,
                        const float* __restrict__ O_b, float* __restrict__ bias2) {
  int d = threadIdx.x;
  float acc = O_b[d];
  for (int k = 0; k < DF; ++k) acc = fmaf(gat_bias[k], O_w[(size_t)d * DF + k], acc);
  bias2[d] = acc;
}

// ---------------- readout ----------------
__global__ __launch_bounds__(128) void k_moy(
    const unsigned short* __restrict__ h2b, const int* __restrict__ ng,
    float* __restrict__ moy, float* __restrict__ cnt, int rows) {
  int tid = threadIdx.x;
  int per = (rows + gridDim.x - 1) / gridDim.x;
  int n0 = blockIdx.x * per;
  int n1 = min(rows, n0 + per);
  if (n0 >= n1) return;
  int cur = ng[n0];
  float acc = 0.f; int c = 0;
  for (int n = n0; n < n1; ++n) {
    int g = ng[n];
    if (g != cur) {
      atomicAdd(&moy[cur * DF + tid], acc);
      if (tid == 0) atomicAdd(&cnt[cur], (float)c);
      acc = 0.f; c = 0; cur = g;
    }
    acc += bf2f(h2b[(size_t)n * DF + tid]);
    ++c;
  }
  atomicAdd(&moy[cur * DF + tid], acc);
  if (tid == 0) atomicAdd(&cnt[cur], (float)c);
}

__global__ void k_moy_div(const float* __restrict__ moy, const float* __restrict__ cnt,
                          unsigned short* __restrict__ moyb) {
  int i = blockIdx.x * DF + threadIdx.x;
  moyb[i] = f2bf(moy[i] / cnt[blockIdx.x]);
}

// ---------------- fused MFMA head (graph-local, low register demand) ----------------
__global__ __launch_bounds__(512, 2) void k_final_mfma(
    const unsigned short* __restrict__ h2b, const unsigned short* __restrict__ moyb,
    const int* __restrict__ src, const int* __restrict__ dst,
    const short* __restrict__ W1f, const float* __restrict__ W1b,
    const float* __restrict__ W2, const float* __restrict__ W2b,
    float* __restrict__ out, int Eg) {
  __shared__ short Wb[6144 * 8];  // 96 KB
  int tid = threadIdx.x;
  for (int s = tid; s < 6144; s += 512)
    *(bf16x8*)&Wb[s * 8] = *(const bf16x8*)&W1f[(size_t)s * 8];
  __syncthreads();
  int wid = tid >> 6, lane = tid & 63, q = lane >> 4, m = lane & 15;
  int g = blockIdx.x & 7, sub = blockIdx.x >> 3, nsub = gridDim.x >> 3;
  int gbase = g * Eg, gend = gbase + Eg;
  int tpg = (Eg + 127) >> 7;
  const unsigned short* mrow = moyb + (size_t)g * DF + q * 8;
  float w2b = W2b[0];
  for (int t = sub; t < tpg; t += nsub) {
    int r0 = gbase + t * 128 + wid * 16;
    int edge = r0 + m;
    int ec = (edge < gend) ? edge : gend - 1;
    int s = src[ec], d = dst[ec];
    const unsigned short* rs = h2b + (size_t)s * DF + q * 8;
    const unsigned short* rd = h2b + (size_t)d * DF + q * 8;
    f32x4 c0 = {0.f, 0.f, 0.f, 0.f}, c1 = c0, c2 = c0, c3 = c0;
    f32x4 c4 = c0, c5 = c0, c6 = c0, c7 = c0;
#pragma unroll
    for (int seg = 0; seg < 3; ++seg) {
      const unsigned short* base = (seg == 0) ? mrow : ((seg == 1) ? rs : rd);
#pragma unroll
      for (int kk = 0; kk < 4; ++kk) {
        int ks = seg * 4 + kk;
        bf16x8 av = *(const bf16x8*)(base + kk * 32);
        const short* wrow = &Wb[(ks * 64 + lane) * 8];
        c0 = __builtin_amdgcn_mfma_f32_16x16x32_bf16(av, *(const bf16x8*)(wrow + 0 * 12 * 64 * 8), c0, 0, 0, 0);
        c1 = __builtin_amdgcn_mfma_f32_16x16x32_bf16(av, *(const bf16x8*)(wrow + 1 * 12 * 64 * 8), c1, 0, 0, 0);
        c2 = __builtin_amdgcn_mfma_f32_16x16x32_bf16(av, *(const bf16x8*)(wrow + 2 * 12 * 64 * 8), c2, 0, 0, 0);
        c3 = __builtin_amdgcn_mfma_f32_16x16x32_bf16(av, *(const bf16x8*)(wrow + 3 * 12 * 64 * 8), c3, 0, 0, 0);
        c4 = __builtin_amdgcn_mfma_f32_16x16x32_bf16(av, *(const bf16x8*)(wrow + 4 * 12 * 64 * 8), c4, 0, 0, 0);
        c5 = __builtin_amdgcn_mfma_f32_16x16x32_bf16(av, *(const bf16x8*)(wrow + 5 * 12 * 64 * 8), c5, 0, 0, 0);
        c6 = __builtin_amdgcn_mfma_f32_16x16x32_bf16(av, *(const bf16x8*)(wrow + 6 * 12 * 64 * 8), c6, 0, 0, 0);
        c7 = __builtin_amdgcn_mfma_f32_16x16x32_bf16(av, *(const bf16x8*)(wrow + 7 * 12 * 64 * 8), c7, 0, 0, 0);
      }
    }
    float v0 = 0.f, v1 = 0.f, v2 = 0.f, v3 = 0.f;
#pragma unroll
    for (int ct = 0; ct < 8; ++ct) {
      f32x4 cc = (ct == 0) ? c0 : (ct == 1) ? c1 : (ct == 2) ? c2 : (ct == 3) ? c3
                 : (ct == 4) ? c4 : (ct == 5) ? c5 : (ct == 6) ? c6 : c7;
      int col = ct * 16 + m;
      float bb = W1b[col], ww = W2[col];
      v0 += fmaxf(cc[0] + bb, 0.f) * ww;
      v1 += fmaxf(cc[1] + bb, 0.f) * ww;
      v2 += fmaxf(cc[2] + bb, 0.f) * ww;
      v3 += fmaxf(cc[3] + bb, 0.f) * ww;
    }
#pragma unroll
    for (int mask = 1; mask <= 8; mask <<= 1) {
      v0 += __shfl_xor(v0, mask, 64);
      v1 += __shfl_xor(v1, mask, 64);
      v2 += __shfl_xor(v2, mask, 64);
      v3 += __shfl_xor(v3, mask, 64);
    }
    if (m == 0) {
      int rb = r0 + q * 4;
      if (rb < gend) out[rb] = sigm(v0 + w2b);
      if (rb + 1 < gend) out[rb + 1] = sigm(v1 + w2b);
      if (rb + 2 < gend) out[rb + 2] = sigm(v2 + w2b);
      if (rb + 3 < gend) out[rb + 3] = sigm(v3 + w2b);
    }
  }
}

extern "C" void kernel_launch(void* const* d_in, const int* in_sizes, int n_in,
                              void* d_out, int out_size, void* d_ws, size_t ws_size,
                              hipStream_t stream) {
  const float* h_in = (const float*)d_in[0];
  const float* e_in = (const float*)d_in[1];
  const int* src = (const int*)d_in[2];
  const int* dst = (const int*)d_in[3];
  const int* node_graph = (const int*)d_in[4];
  const int* edge_graph = (const int*)d_in[5];
  const float* emb_n_w = (const float*)d_in[6];
  const float* emb_n_b = (const float*)d_in[7];
  const float* emb_e_w = (const float*)d_in[8];
  const float* emb_e_b = (const float*)d_in[9];
  const float* Us = (const float*)d_in[10];
  const float* Vs = (const float*)d_in[11];
  const float* As = (const float*)d_in[12];
  const float* Bs = (const float*)d_in[13];
  const float* Cs = (const float*)d_in[14];
  const float* gat_src_w = (const float*)d_in[15];
  const float* gat_src_b = (const float*)d_in[16];
  const float* gat_dst_w = (const float*)d_in[17];
  const float* gat_dst_b = (const float*)d_in[18];
  const float* gat_attn = (const float*)d_in[19];
  const float* gat_bias = (const float*)d_in[20];
  const float* O_w = (const float*)d_in[21];
  const float* O_b = (const float*)d_in[22];
  const float* W1_w = (const float*)d_in[23];
  const float* W1_b = (const float*)d_in[24];
  const float* W2_w = (const float*)d_in[25];
  const float* W2_b = (const float*)d_in[26];
  float* out = (float*)d_out;

  const int N = in_sizes[0] / 64;   // 30000
  const int E = in_sizes[1] / 16;   // 360000
  const int Eg = E / NGRAPH;        // 45000
  const int Ngr = N / NGRAPH;       // 3750

  auto rnd = [](size_t b) { return (b + 255) & ~(size_t)255; };
  const size_t sz_e0 = rnd((size_t)E * DF * 2);
  const size_t sz_node = rnd((size_t)N * DF * 4);
  const size_t sz_nodeb = rnd((size_t)N * DF * 2);
  const size_t sz_score = rnd((size_t)E * 8 * 4);
  const size_t sz_wfrag = rnd(18 * 2048 * 8 * 2);
  const size_t sz_w1frag = rnd(6144 * 8 * 2);
  const size_t sz_rp = rnd((size_t)(N + 1) * 4);
  const size_t sz_eid = rnd((size_t)E * 4);
  const size_t sz_misc = rnd(4096 * 4);
  const size_t needed = sz_e0 + 3 * sz_node + 4 * sz_nodeb + sz_score + sz_wfrag +
                        sz_w1frag + 3 * sz_rp + sz_eid + sz_misc;
  if (ws_size < needed) {
    k_fill_u32<<<256, 256, 0, stream>>>((unsigned*)out, 0xBF800000u, (long long)out_size);
    return;
  }

  char* wp = (char*)d_ws;
  auto alloc = [&](size_t bytes) { void* p = wp; wp += bytes; return p; };
  unsigned short* e0u = (unsigned short*)alloc(sz_e0);
  float* h0 = (float*)alloc(sz_node);
  float* hU = (float*)alloc(sz_node);
  float* rst = (float*)alloc(sz_node);
  unsigned short* hVb = (unsigned short*)alloc(sz_nodeb);
  unsigned short* hBb = (unsigned short*)alloc(sz_nodeb);
  unsigned short* hCb = (unsigned short*)alloc(sz_nodeb);
  unsigned short* h2b = (unsigned short*)alloc(sz_nodeb);
  float* score = (float*)alloc(sz_score);
  short* wfrag = (short*)alloc(sz_wfrag);
  short* w1frag = (short*)alloc(sz_w1frag);
  unsigned* rowptr = (unsigned*)alloc(sz_rp);
  unsigned* cursor = (unsigned*)alloc(sz_rp);
  unsigned* deg = (unsigned*)alloc(sz_rp);
  int* eidb = (int*)alloc(sz_eid);
  float* misc = (float*)alloc(sz_misc);
  float* stat = misc;                                     // [0,1024)
  float* bias2 = misc + 1024;                             // [1024,1152)
  float* moy = misc + 1152;                               // [1152,2176)
  float* cnt = misc + 2176;                               // [2176,2184)
  unsigned short* moyb = (unsigned short*)(misc + 2304);  // 1024 bf16

  auto WF = [&](int idx) { return wfrag + (size_t)idx * 2048 * 8; };

  // CSR build (dst lists; reused by all 3 layers + GAT)
  k_fill_u32<<<64, 256, 0, stream>>>(deg, 0u, N);
  k_deg<<<512, 256, 0, stream>>>(dst, deg, E);
  k_scan<<<1, 1024, 0, stream>>>(deg, rowptr, cursor, N);
  k_scatter<<<512, 256, 0, stream>>>(dst, cursor, eidb, E);

  k_wconv<<<18, 512, 0, stream>>>(Us, Vs, As, Bs, Cs, gat_src_w, gat_dst_w, O_w, wfrag);
  k_wconv_w1<<<12, 512, 0, stream>>>(W1_w, w1frag);

  const int gN = (N + 127) / 128;
  k_node_embed<<<2048, 128, 0, stream>>>(h_in, emb_n_w, emb_n_b, h0, N);
  k_edge_embed<<<4096, 128, 0, stream>>>(e_in, emb_e_w, emb_e_b, e0u, E);

  for (int l = 0; l < 3; ++l) {
    k_gemm4_mfma<<<gN, 512, 0, stream>>>(h0, WF(3 + l), WF(l), WF(9 + l), WF(12 + l),
                                         hVb, hU, hBb, hCb, N);
    k_fill_u32<<<4, 256, 0, stream>>>((unsigned*)stat, 0u, 1024);
    k_node_agg<<<512, 256, 0, stream>>>(hU, hVb, e0u, src, rowptr, eidb, stat, Ngr);
    k_edge_mfma<0><<<256, 512, 0, stream>>>(e0u, WF(6 + l), hBb, hCb, src, dst, stat, Eg);
    k_bn_finalize<<<1, 256, 0, stream>>>(stat, (float)N, (float)E);
    k_node_update<<<2048, 256, 0, stream>>>(h0, hU, stat, (long long)N * DF);
    k_edge_mfma<1><<<256, 512, 0, stream>>>(e0u, WF(6 + l), hBb, hCb, src, dst, stat, Eg);
  }

  // GATv2: fs -> hVb, fd -> hBb
  k_gemm_mfma<1><<<gN, 512, 0, stream>>>(h0, WF(15), gat_src_b, hVb, N);
  k_gemm_mfma<1><<<gN, 512, 0, stream>>>(h0, WF(16), gat_dst_b, hBb, N);
  k_gat_score<<<512, 256, 0, stream>>>(hVb, hBb, src, dst, gat_attn, score, Eg);
  k_gat_node<<<512, 256, 0, stream>>>(score, hVb, src, rowptr, eidb, rst, Ngr);
  k_bias2<<<1, 128, 0, stream>>>(gat_bias, O_w, O_b, bias2);
  k_gemm_mfma<1><<<gN, 512, 0, stream>>>(rst, WF(17), bias2, h2b, N);  // h2

  // readout
  k_fill_u32<<<2, 256, 0, stream>>>((unsigned*)moy, 0u, 1032);
  k_moy<<<128, 128, 0, stream>>>(h2b, node_graph, moy, cnt, N);
  k_moy_div<<<8, 128, 0, stream>>>(moy, cnt, moyb);
  k_final_mfma<<<256, 512, 0, stream>>>(h2b, moyb, src, dst, w1frag, W1_b, W2_w,
                                        W2_b, out, Eg);
}

// Round 9
// 1888.172 us; speedup vs baseline: 1.3599x; 1.1101x over previous
//
#include <hip/hip_runtime.h>

#define DF 128
#define NGRAPH 8

typedef __attribute__((ext_vector_type(8))) short bf16x8;
typedef __attribute__((ext_vector_type(4))) float f32x4;

__device__ __forceinline__ float sigm(float x) { return 1.f / (1.f + __expf(-x)); }
__device__ __forceinline__ unsigned short f2bf(float f) {  // RNE f32->bf16
  unsigned u = __float_as_uint(f);
  u += 0x7FFFu + ((u >> 16) & 1u);
  return (unsigned short)(u >> 16);
}
__device__ __forceinline__ float bf2f(unsigned short u) {
  return __uint_as_float(((unsigned)u) << 16);
}

// load 8 consecutive f32 (32B-aligned) -> bf16x8
__device__ __forceinline__ bf16x8 cvt8(const float* __restrict__ p) {
  float4 a = *(const float4*)p;
  float4 b = *(const float4*)(p + 4);
  bf16x8 r;
  r[0] = (short)f2bf(a.x); r[1] = (short)f2bf(a.y);
  r[2] = (short)f2bf(a.z); r[3] = (short)f2bf(a.w);
  r[4] = (short)f2bf(b.x); r[5] = (short)f2bf(b.y);
  r[6] = (short)f2bf(b.z); r[7] = (short)f2bf(b.w);
  return r;
}

// ---------------- generic fill ----------------
__global__ void k_fill_u32(unsigned* __restrict__ p, unsigned v, long long n) {
  long long i = (long long)blockIdx.x * blockDim.x + threadIdx.x;
  long long st = (long long)gridDim.x * blockDim.x;
  for (; i < n; i += st) p[i] = v;
}

// ---------------- CSR build (dst-sorted edge lists) ----------------
__global__ void k_deg(const int* __restrict__ dst, unsigned* __restrict__ deg, int E) {
  int i = blockIdx.x * blockDim.x + threadIdx.x;
  int st = gridDim.x * blockDim.x;
  for (; i < E; i += st) atomicAdd(&deg[dst[i]], 1u);
}

__global__ __launch_bounds__(1024) void k_scan(
    const unsigned* __restrict__ deg, unsigned* __restrict__ rowptr,
    unsigned* __restrict__ cursor, int N) {
  __shared__ unsigned part[1024];
  int t = threadIdx.x;
  int per = (N + 1023) >> 10;
  int s0 = t * per, s1 = min(N, s0 + per);
  unsigned s = 0;
  for (int i = s0; i < s1; ++i) s += deg[i];
  part[t] = s;
  __syncthreads();
  for (int off = 1; off < 1024; off <<= 1) {
    unsigned v = (t >= off) ? part[t - off] : 0u;
    __syncthreads();
    part[t] += v;
    __syncthreads();
  }
  unsigned base = (t == 0) ? 0u : part[t - 1];
  for (int i = s0; i < s1; ++i) {
    rowptr[i] = base;
    cursor[i] = base;
    base += deg[i];
  }
  if (t == 1023) rowptr[N] = part[1023];
}

__global__ void k_scatter(const int* __restrict__ dst, unsigned* __restrict__ cursor,
                          int* __restrict__ eidb, int E) {
  int i = blockIdx.x * blockDim.x + threadIdx.x;
  int st = gridDim.x * blockDim.x;
  for (; i < E; i += st) {
    unsigned p = atomicAdd(&cursor[dst[i]], 1u);
    eidb[p] = i;
  }
}

// ---------------- weight pre-conversion to MFMA fragment order ----------------
// 0-2 U, 3-5 V, 6-8 A, 9-11 B, 12-14 C, 15 gsw, 16 gdw, 17 Ow, 18 W1[:,128:256], 19 W1[:,256:384]
__global__ __launch_bounds__(512) void k_wconv(
    const float* __restrict__ Us, const float* __restrict__ Vs,
    const float* __restrict__ As, const float* __restrict__ Bs,
    const float* __restrict__ Cs, const float* __restrict__ gsw,
    const float* __restrict__ gdw, const float* __restrict__ Ow,
    const float* __restrict__ W1, short* __restrict__ out) {
  int b = blockIdx.x;
  const float* W;
  int ldw = DF;
  if (b < 3) W = Us + b * 16384;
  else if (b < 6) W = Vs + (b - 3) * 16384;
  else if (b < 9) W = As + (b - 6) * 16384;
  else if (b < 12) W = Bs + (b - 9) * 16384;
  else if (b < 15) W = Cs + (b - 12) * 16384;
  else if (b == 15) W = gsw;
  else if (b == 16) W = gdw;
  else if (b == 17) W = Ow;
  else if (b == 18) { W = W1 + 128; ldw = 384; }
  else { W = W1 + 256; ldw = 384; }
  short* o = out + (size_t)b * 2048 * 8;
  for (int s = threadIdx.x; s < 2048; s += 512) {
    int ct = s >> 8, ks = (s >> 6) & 3, l = s & 63;
    int row = ct * 16 + (l & 15), k0 = ks * 32 + (l >> 4) * 8;
    *(bf16x8*)&o[s * 8] = cvt8(W + (size_t)row * ldw + k0);
  }
}

// ---------------- embeddings ----------------
__global__ __launch_bounds__(128) void k_node_embed(
    const float* __restrict__ hin, const float* __restrict__ w,
    const float* __restrict__ b, float* __restrict__ h0, int rows) {
  __shared__ float Wt[64 * DF];
  __shared__ float ar[4][64];
  int tid = threadIdx.x;
  for (int i = tid; i < 64 * DF; i += 128) Wt[(i & 63) * DF + (i >> 6)] = w[i];
  float bb = b[tid];
  __syncthreads();
  for (int r0 = blockIdx.x * 4; r0 < rows; r0 += gridDim.x * 4) {
    for (int i = tid; i < 256; i += 128) ar[i >> 6][i & 63] = hin[(size_t)r0 * 64 + i];
    __syncthreads();
    float a0 = bb, a1 = bb, a2 = bb, a3 = bb;
#pragma unroll 8
    for (int k = 0; k < 64; ++k) {
      float wv = Wt[k * DF + tid];
      a0 = fmaf(ar[0][k], wv, a0); a1 = fmaf(ar[1][k], wv, a1);
      a2 = fmaf(ar[2][k], wv, a2); a3 = fmaf(ar[3][k], wv, a3);
    }
    h0[(size_t)r0 * DF + tid] = a0;
    h0[(size_t)(r0 + 1) * DF + tid] = a1;
    h0[(size_t)(r0 + 2) * DF + tid] = a2;
    h0[(size_t)(r0 + 3) * DF + tid] = a3;
    __syncthreads();
  }
}

__global__ __launch_bounds__(128) void k_edge_embed(
    const float* __restrict__ ein, const float* __restrict__ w,
    const float* __restrict__ b, unsigned short* __restrict__ e0u, int rows) {
  __shared__ float Wt[16 * DF];
  __shared__ float ar[4][16];
  int tid = threadIdx.x;
  for (int i = tid; i < 16 * DF; i += 128) Wt[(i & 15) * DF + (i >> 4)] = w[i];
  float bb = b[tid];
  __syncthreads();
  for (int r0 = blockIdx.x * 4; r0 < rows; r0 += gridDim.x * 4) {
    if (tid < 64) ar[tid >> 4][tid & 15] = ein[(size_t)r0 * 16 + tid];
    __syncthreads();
    float a0 = bb, a1 = bb, a2 = bb, a3 = bb;
#pragma unroll
    for (int k = 0; k < 16; ++k) {
      float wv = Wt[k * DF + tid];
      a0 = fmaf(ar[0][k], wv, a0); a1 = fmaf(ar[1][k], wv, a1);
      a2 = fmaf(ar[2][k], wv, a2); a3 = fmaf(ar[3][k], wv, a3);
    }
    e0u[(size_t)r0 * DF + tid] = f2bf(a0);
    e0u[(size_t)(r0 + 1) * DF + tid] = f2bf(a1);
    e0u[(size_t)(r0 + 2) * DF + tid] = f2bf(a2);
    e0u[(size_t)(r0 + 3) * DF + tid] = f2bf(a3);
    __syncthreads();
  }
}

// ---------------- MFMA [rows,128] @ W^T (+bias), frag weights, f32 input ----------------
template <int OUTBF>
__global__ __launch_bounds__(512) void k_gemm_mfma(
    const float* __restrict__ A, const short* __restrict__ Wf,
    const float* __restrict__ bias, void* __restrict__ outv, int rows) {
  __shared__ short Wb[2048 * 8];  // 32 KB
  int tid = threadIdx.x;
  for (int s = tid; s < 2048; s += 512)
    *(bf16x8*)&Wb[s * 8] = *(const bf16x8*)&Wf[(size_t)s * 8];
  __syncthreads();
  float* outf = (float*)outv;
  unsigned short* outb = (unsigned short*)outv;
  int wid = tid >> 6, lane = tid & 63, q = lane >> 4, m = lane & 15;
  int ntiles = (rows + 127) >> 7;
  for (int t = blockIdx.x; t < ntiles; t += gridDim.x) {
    int r0 = t * 128 + wid * 16;
    int rr = r0 + m;
    if (rr >= rows) rr = rows - 1;
    const float* ap = A + (size_t)rr * DF + q * 8;
    bf16x8 a[4];
#pragma unroll
    for (int ks = 0; ks < 4; ++ks) a[ks] = cvt8(ap + 32 * ks);
#pragma unroll
    for (int ct = 0; ct < 8; ++ct) {
      f32x4 acc = {0.f, 0.f, 0.f, 0.f};
#pragma unroll
      for (int ks = 0; ks < 4; ++ks) {
        bf16x8 b = *(const bf16x8*)&Wb[((ct * 4 + ks) * 64 + lane) * 8];
        acc = __builtin_amdgcn_mfma_f32_16x16x32_bf16(a[ks], b, acc, 0, 0, 0);
      }
      int col = ct * 16 + m;
      float bb = bias ? bias[col] : 0.f;
#pragma unroll
      for (int j = 0; j < 4; ++j) {
        int row = r0 + q * 4 + j;
        if (row < rows) {
          if (OUTBF) outb[(size_t)row * DF + col] = f2bf(acc[j] + bb);
          else outf[(size_t)row * DF + col] = acc[j] + bb;
        }
      }
    }
  }
}

// same, bf16 input
__global__ __launch_bounds__(512) void k_gemmb_mfma(
    const unsigned short* __restrict__ A, const short* __restrict__ Wf,
    unsigned short* __restrict__ outb, int rows) {
  __shared__ short Wb[2048 * 8];
  int tid = threadIdx.x;
  for (int s = tid; s < 2048; s += 512)
    *(bf16x8*)&Wb[s * 8] = *(const bf16x8*)&Wf[(size_t)s * 8];
  __syncthreads();
  int wid = tid >> 6, lane = tid & 63, q = lane >> 4, m = lane & 15;
  int ntiles = (rows + 127) >> 7;
  for (int t = blockIdx.x; t < ntiles; t += gridDim.x) {
    int r0 = t * 128 + wid * 16;
    int rr = r0 + m;
    if (rr >= rows) rr = rows - 1;
    const unsigned short* ap = A + (size_t)rr * DF + q * 8;
    bf16x8 a[4];
#pragma unroll
    for (int ks = 0; ks < 4; ++ks) a[ks] = *(const bf16x8*)(ap + 32 * ks);
#pragma unroll
    for (int ct = 0; ct < 8; ++ct) {
      f32x4 acc = {0.f, 0.f, 0.f, 0.f};
#pragma unroll
      for (int ks = 0; ks < 4; ++ks) {
        bf16x8 b = *(const bf16x8*)&Wb[((ct * 4 + ks) * 64 + lane) * 8];
        acc = __builtin_amdgcn_mfma_f32_16x16x32_bf16(a[ks], b, acc, 0, 0, 0);
      }
      int col = ct * 16 + m;
#pragma unroll
      for (int j = 0; j < 4; ++j) {
        int row = r0 + q * 4 + j;
        if (row < rows) outb[(size_t)row * DF + col] = f2bf(acc[j]);
      }
    }
  }
}

// ---------------- fused 4-output node GEMM (V,U,B,C) ----------------
__global__ __launch_bounds__(512) void k_gemm4_mfma(
    const float* __restrict__ h0, const short* __restrict__ Vf,
    const short* __restrict__ Uf, const short* __restrict__ Bf,
    const short* __restrict__ Cf, unsigned short* __restrict__ hVb,
    float* __restrict__ hU, unsigned short* __restrict__ hBb,
    unsigned short* __restrict__ hCb, int rows) {
  __shared__ short Wl[4 * 2048 * 8];  // 128 KB
  int tid = threadIdx.x;
  for (int s = tid; s < 2048; s += 512) {
    *(bf16x8*)&Wl[(size_t)s * 8] = *(const bf16x8*)&Vf[(size_t)s * 8];
    *(bf16x8*)&Wl[(size_t)(2048 + s) * 8] = *(const bf16x8*)&Uf[(size_t)s * 8];
    *(bf16x8*)&Wl[(size_t)(4096 + s) * 8] = *(const bf16x8*)&Bf[(size_t)s * 8];
    *(bf16x8*)&Wl[(size_t)(6144 + s) * 8] = *(const bf16x8*)&Cf[(size_t)s * 8];
  }
  __syncthreads();
  int wid = tid >> 6, lane = tid & 63, q = lane >> 4, m = lane & 15;
  int ntiles = (rows + 127) >> 7;
  for (int t = blockIdx.x; t < ntiles; t += gridDim.x) {
    int r0 = t * 128 + wid * 16;
    int rr = r0 + m;
    if (rr >= rows) rr = rows - 1;
    const float* ap = h0 + (size_t)rr * DF + q * 8;
    bf16x8 a[4];
#pragma unroll
    for (int ks = 0; ks < 4; ++ks) a[ks] = cvt8(ap + 32 * ks);
#pragma unroll
    for (int w = 0; w < 4; ++w) {
#pragma unroll
      for (int ct = 0; ct < 8; ++ct) {
        f32x4 acc = {0.f, 0.f, 0.f, 0.f};
#pragma unroll
        for (int ks = 0; ks < 4; ++ks) {
          bf16x8 b = *(const bf16x8*)&Wl[((w * 2048) + (ct * 4 + ks) * 64 + lane) * 8];
          acc = __builtin_amdgcn_mfma_f32_16x16x32_bf16(a[ks], b, acc, 0, 0, 0);
        }
        int col = ct * 16 + m;
#pragma unroll
        for (int j = 0; j < 4; ++j) {
          int row = r0 + q * 4 + j;
          if (row < rows) {
            if (w == 1) hU[(size_t)row * DF + col] = acc[j];
            else {
              unsigned short v = f2bf(acc[j]);
              unsigned short* o = (w == 0) ? hVb : ((w == 2) ? hBb : hCb);
              o[(size_t)row * DF + col] = v;
            }
          }
        }
      }
    }
  }
}

// ---------------- MFMA edge pass: x = e@As^T + hB[dst] + hC[src] ----------------
// MODE 0: stats only. MODE 1: apply w/ recompute. MODE 2: stats + store x (bf16).
template <int MODE>
__global__ __launch_bounds__(512) void k_edge_mfma(
    unsigned short* __restrict__ e0u, const short* __restrict__ Af,
    const unsigned short* __restrict__ hBb, const unsigned short* __restrict__ hCb,
    const int* __restrict__ src, const int* __restrict__ dst,
    float* __restrict__ stat, unsigned short* __restrict__ xe, int Eg) {
  __shared__ short Wb[2048 * 8];     // 32 KB
  __shared__ float xt[8][16 * 132];  // 66 KB
  int tid = threadIdx.x;
  for (int s = tid; s < 2048; s += 512)
    *(bf16x8*)&Wb[s * 8] = *(const bf16x8*)&Af[(size_t)s * 8];
  int wid = tid >> 6, lane = tid & 63, q = lane >> 4, m = lane & 15;
  int g = blockIdx.x & 7, sub = blockIdx.x >> 3, nsub = gridDim.x >> 3;
  int gbase = g * Eg, gend = gbase + Eg;
  int tpg = (Eg + 127) >> 7;
  float* xw = xt[wid];
  float ps0 = 0.f, ps1 = 0.f, pq0 = 0.f, pq1 = 0.f;
  __syncthreads();
  for (int t = sub; t < tpg; t += nsub) {
    int r0 = gbase + t * 128 + wid * 16;
    int edge = r0 + m;
    bool ok = edge < gend;
    int ec = ok ? edge : gend - 1;
    const unsigned short* ep = e0u + (size_t)ec * DF + q * 8;
    bf16x8 a[4];
#pragma unroll
    for (int ks = 0; ks < 4; ++ks) a[ks] = *(const bf16x8*)(ep + 32 * ks);
#pragma unroll
    for (int ct = 0; ct < 8; ++ct) {
      f32x4 acc = {0.f, 0.f, 0.f, 0.f};
#pragma unroll
      for (int ks = 0; ks < 4; ++ks) {
        bf16x8 b = *(const bf16x8*)&Wb[((ct * 4 + ks) * 64 + lane) * 8];
        acc = __builtin_amdgcn_mfma_f32_16x16x32_bf16(a[ks], b, acc, 0, 0, 0);
      }
#pragma unroll
      for (int j = 0; j < 4; ++j) xw[(q * 4 + j) * 132 + ct * 16 + m] = acc[j];
    }
    __syncthreads();
    int sidx = src[ec], didx = dst[ec];
    const unsigned short* pb = hBb + (size_t)didx * DF;
    const unsigned short* pc = hCb + (size_t)sidx * DF;
#pragma unroll
    for (int ks = 0; ks < 4; ++ks) {
      int c0 = q * 8 + 32 * ks;
      float* xp = &xw[m * 132 + c0];
      bf16x8 gb = *(const bf16x8*)(pb + c0);
      bf16x8 gc = *(const bf16x8*)(pc + c0);
      float x[8];
#pragma unroll
      for (int i = 0; i < 8; ++i)
        x[i] = xp[i] + bf2f((unsigned short)gb[i]) + bf2f((unsigned short)gc[i]);
      if (MODE == 1) {
        bf16x8 nv;
#pragma unroll
        for (int i = 0; i < 8; ++i) {
          float mm = stat[768 + c0 + i], iv = stat[896 + c0 + i];
          nv[i] = (short)f2bf(bf2f((unsigned short)a[ks][i]) + fmaxf((x[i] - mm) * iv, 0.f));
        }
        if (ok) *(bf16x8*)(e0u + (size_t)ec * DF + c0) = nv;
      } else {
        if (MODE == 2 && ok) {
          bf16x8 xv;
#pragma unroll
          for (int i = 0; i < 8; ++i) xv[i] = (short)f2bf(x[i]);
          *(bf16x8*)(xe + (size_t)ec * DF + c0) = xv;
        }
#pragma unroll
        for (int i = 0; i < 8; ++i) xp[i] = ok ? x[i] : 0.f;
      }
    }
    if (MODE != 1) {
      __syncthreads();
#pragma unroll 4
      for (int r = 0; r < 16; ++r) {
        float2 v = *(float2*)&xw[r * 132 + 2 * lane];
        ps0 += v.x; ps1 += v.y;
        pq0 += v.x * v.x; pq1 += v.y * v.y;
      }
    }
    __syncthreads();
  }
  if (MODE != 1) {
    atomicAdd(&stat[512 + 2 * lane], ps0);
    atomicAdd(&stat[512 + 2 * lane + 1], ps1);
    atomicAdd(&stat[640 + 2 * lane], pq0);
    atomicAdd(&stat[640 + 2 * lane + 1], pq1);
  }
}

// streaming apply: e += relu((x - m)*iv), all bf16
__global__ __launch_bounds__(256) void k_edge_apply(
    unsigned short* __restrict__ e0u, const unsigned short* __restrict__ xe,
    const float* __restrict__ stat, long long n8) {
  long long i = (long long)blockIdx.x * blockDim.x + threadIdx.x;
  long long st = (long long)gridDim.x * blockDim.x;
  for (; i < n8; i += st) {
    int c0 = (int)(i & 15) * 8;
    bf16x8 ev = *(const bf16x8*)(e0u + i * 8);
    bf16x8 xv = *(const bf16x8*)(xe + i * 8);
    bf16x8 nv;
#pragma unroll
    for (int k = 0; k < 8; ++k) {
      float mm = stat[768 + c0 + k], iv = stat[896 + c0 + k];
      nv[k] = (short)f2bf(bf2f((unsigned short)ev[k]) +
                          fmaxf((bf2f((unsigned short)xv[k]) - mm) * iv, 0.f));
    }
    *(bf16x8*)(e0u + i * 8) = nv;
  }
}

// ---------------- node-major segment max + hU update + BN stats ----------------
__global__ __launch_bounds__(256) void k_node_agg(
    float* __restrict__ hU, const unsigned short* __restrict__ hVb,
    const unsigned short* __restrict__ e0u, const int* __restrict__ src,
    const unsigned* __restrict__ rowptr, const int* __restrict__ eidb,
    float* __restrict__ stat, int Ngr) {
  int tid = threadIdx.x, wid = tid >> 6, lane = tid & 63;
  int g = blockIdx.x & 7, sub = blockIdx.x >> 3, nsub = gridDim.x >> 3;
  float ps0 = 0.f, ps1 = 0.f, pq0 = 0.f, pq1 = 0.f;
  for (int nn = sub * 4 + wid; nn < Ngr; nn += nsub * 4) {
    int n = g * Ngr + nn;
    unsigned r0 = rowptr[n], r1 = rowptr[n + 1];
    float m0 = -3.4e38f, m1 = -3.4e38f;
    for (unsigned r = r0; r < r1; ++r) {
      int e = eidb[r];
      unsigned hv2 = *(const unsigned*)&hVb[(size_t)src[e] * DF + 2 * lane];
      unsigned ev2 = *(const unsigned*)&e0u[(size_t)e * DF + 2 * lane];
      float v0 = bf2f((unsigned short)(hv2 & 0xffffu)) * sigm(bf2f((unsigned short)(ev2 & 0xffffu)));
      float v1 = bf2f((unsigned short)(hv2 >> 16)) * sigm(bf2f((unsigned short)(ev2 >> 16)));
      m0 = fmaxf(m0, v0);
      m1 = fmaxf(m1, v1);
    }
    if (r1 == r0) { m0 = 0.f; m1 = 0.f; }
    size_t idx = (size_t)n * DF + 2 * lane;
    float2 hu = *(float2*)&hU[idx];
    float t0 = hu.x + m0, t1 = hu.y + m1;
    hu.x = t0; hu.y = t1;
    *(float2*)&hU[idx] = hu;
    ps0 += t0; ps1 += t1;
    pq0 += t0 * t0; pq1 += t1 * t1;
  }
  atomicAdd(&stat[2 * lane], ps0);
  atomicAdd(&stat[2 * lane + 1], ps1);
  atomicAdd(&stat[128 + 2 * lane], pq0);
  atomicAdd(&stat[128 + 2 * lane + 1], pq1);
}

// finalize BN stats
__global__ void k_bn_finalize(float* __restrict__ stat, float nN, float nE) {
  int tid = threadIdx.x;
  if (tid < 128) {
    float mean = stat[tid] / nN;
    float var = stat[128 + tid] / nN - mean * mean;
    stat[256 + tid] = mean;
    stat[384 + tid] = rsqrtf(fmaxf(var, 0.f) + 1e-5f);
  } else {
    int d = tid - 128;
    float mean = stat[512 + d] / nE;
    float var = stat[640 + d] / nE - mean * mean;
    stat[768 + d] = mean;
    stat[896 + d] = rsqrtf(fmaxf(var, 0.f) + 1e-5f);
  }
}

__global__ __launch_bounds__(256) void k_node_update(
    float* __restrict__ h0, const float* __restrict__ hU,
    const float* __restrict__ stat, long long total) {
  long long i = (long long)blockIdx.x * blockDim.x + threadIdx.x;
  long long st = (long long)gridDim.x * blockDim.x;
  for (; i < total; i += st) {
    int d = (int)(i & 127);
    float t = (hU[i] - stat[256 + d]) * stat[384 + d];
    h0[i] += fmaxf(t, 0.f);
  }
}

// ---------------- GATv2 score (edge-major) ----------------
__global__ __launch_bounds__(256) void k_gat_score(
    const unsigned short* __restrict__ fsb, const unsigned short* __restrict__ fdb,
    const int* __restrict__ src, const int* __restrict__ dst,
    const float* __restrict__ attn, float* __restrict__ score, int Eg) {
  int g = blockIdx.x & 7, sub = blockIdx.x >> 3, nsub = gridDim.x >> 3;
  int gbase = g * Eg, gend = gbase + Eg;
  int tpg = (Eg + 127) >> 7;
  int tid = threadIdx.x;
  for (int t = sub; t < tpg; t += nsub) {
    int ebase = gbase + t * 128;
    for (int k = tid; k < 1024; k += 256) {
      int e = ebase + (k >> 3);
      if (e >= gend) break;
      int mh = k & 7;
      int s = src[e], dn = dst[e];
      const unsigned short* ps = fsb + (size_t)s * DF + mh * 16;
      const unsigned short* pd = fdb + (size_t)dn * DF + mh * 16;
      const float* pa = attn + mh * 16;
      bf16x8 s0 = *(const bf16x8*)ps;
      bf16x8 s1 = *(const bf16x8*)(ps + 8);
      bf16x8 d0 = *(const bf16x8*)pd;
      bf16x8 d1 = *(const bf16x8*)(pd + 8);
      float acc = 0.f;
#pragma unroll
      for (int kk = 0; kk < 8; ++kk) {
        float z = bf2f((unsigned short)s0[kk]) + bf2f((unsigned short)d0[kk]);
        z = (z > 0.f) ? z : 0.2f * z;
        acc = fmaf(z, pa[kk], acc);
        float z2 = bf2f((unsigned short)s1[kk]) + bf2f((unsigned short)d1[kk]);
        z2 = (z2 > 0.f) ? z2 : 0.2f * z2;
        acc = fmaf(z2, pa[kk + 8], acc);
      }
      score[(size_t)e * 8 + mh] = acc;
    }
  }
}

// ---------------- GATv2 node reduction ----------------
__global__ __launch_bounds__(256) void k_gat_node(
    const float* __restrict__ score, const unsigned short* __restrict__ fsb,
    const int* __restrict__ src, const unsigned* __restrict__ rowptr,
    const int* __restrict__ eidb, float* __restrict__ rst, int Ngr) {
  int tid = threadIdx.x, wid = tid >> 6, lane = tid & 63;
  int g = blockIdx.x & 7, sub = blockIdx.x >> 3, nsub = gridDim.x >> 3;
  int head = lane >> 3, slot = lane & 7;
  for (int nn = sub * 4 + wid; nn < Ngr; nn += nsub * 4) {
    int n = g * Ngr + nn;
    unsigned r0 = rowptr[n], r1 = rowptr[n + 1];
    float hm = -3.4e38f;
    for (unsigned r = r0 + slot; r < r1; r += 8)
      hm = fmaxf(hm, score[(size_t)eidb[r] * 8 + head]);
#pragma unroll
    for (int mk = 1; mk < 8; mk <<= 1) hm = fmaxf(hm, __shfl_xor(hm, mk, 64));
    float dn = 0.f;
    for (unsigned r = r0 + slot; r < r1; r += 8)
      dn += __expf(score[(size_t)eidb[r] * 8 + head] - hm);
#pragma unroll
    for (int mk = 1; mk < 8; mk <<= 1) dn += __shfl_xor(dn, mk, 64);
    float inv = (r1 > r0) ? 1.f / dn : 0.f;
    float a0 = 0.f, a1 = 0.f;
    for (unsigned r = r0; r < r1; ++r) {
      int e = eidb[r];
      float a = __expf(score[(size_t)e * 8 + head] - hm) * inv;
      unsigned fs2 = *(const unsigned*)&fsb[(size_t)src[e] * DF + 2 * lane];
      a0 = fmaf(a, bf2f((unsigned short)(fs2 & 0xffffu)), a0);
      a1 = fmaf(a, bf2f((unsigned short)(fs2 >> 16)), a1);
    }
    float2 o;
    o.x = a0; o.y = a1;
    *(float2*)&rst[(size_t)n * DF + 2 * lane] = o;
  }
}

// bias2 = O_b + gat_bias @ O_w^T
__global__ void k_bias2(const float* __restrict__ gat_bias,
                        const float* __restrict__ O_w,
                        const float* __restrict__ O_b, float* __restrict__ bias2) {
  int d = threadIdx.x;
  float acc = O_b[d];
  for (int k = 0; k < DF; ++k) acc = fmaf(gat_bias[k], O_w[(size_t)d * DF + k], acc);
  bias2[d] = acc;
}

// ---------------- readout ----------------
__global__ __launch_bounds__(128) void k_moy(
    const unsigned short* __restrict__ h2b, const int* __restrict__ ng,
    float* __restrict__ moy, float* __restrict__ cnt, int rows) {
  int tid = threadIdx.x;
  int per = (rows + gridDim.x - 1) / gridDim.x;
  int n0 = blockIdx.x * per;
  int n1 = min(rows, n0 + per);
  if (n0 >= n1) return;
  int cur = ng[n0];
  float acc = 0.f; int c = 0;
  for (int n = n0; n < n1; ++n) {
    int g = ng[n];
    if (g != cur) {
      atomicAdd(&moy[cur * DF + tid], acc);
      if (tid == 0) atomicAdd(&cnt[cur], (float)c);
      acc = 0.f; c = 0; cur = g;
    }
    acc += bf2f(h2b[(size_t)n * DF + tid]);
    ++c;
  }
  atomicAdd(&moy[cur * DF + tid], acc);
  if (tid == 0) atomicAdd(&cnt[cur], (float)c);
}

// P0[g] = W1[:,0:128] @ (moy_sum[g]/cnt[g]) + W1_b
__global__ void k_p0(const float* __restrict__ W1, const float* __restrict__ W1b_,
                     const float* __restrict__ moy, const float* __restrict__ cnt,
                     float* __restrict__ P0) {
  int g = blockIdx.x, d = threadIdx.x;
  float inv = 1.f / cnt[g];
  float acc = W1b_[d];
  for (int k = 0; k < DF; ++k) acc = fmaf(W1[(size_t)d * 384 + k], moy[g * DF + k] * inv, acc);
  P0[g * DF + d] = acc;
}

// ---------------- CSR head: out[e] = sigm(W2 . relu(P0[g]+P1[src]+P2[dst]) + b2) ----------------
__global__ __launch_bounds__(256) void k_head(
    const unsigned short* __restrict__ P1b, const unsigned short* __restrict__ P2b,
    const float* __restrict__ P0, const int* __restrict__ src,
    const unsigned* __restrict__ rowptr, const int* __restrict__ eidb,
    const float* __restrict__ W2, const float* __restrict__ W2b,
    float* __restrict__ out, int Ngr) {
  int tid = threadIdx.x, wid = tid >> 6, lane = tid & 63;
  int g = blockIdx.x & 7, sub = blockIdx.x >> 3, nsub = gridDim.x >> 3;
  float w2b = W2b[0];
  float w20 = W2[2 * lane], w21 = W2[2 * lane + 1];
  float b0 = P0[g * DF + 2 * lane], b1v = P0[g * DF + 2 * lane + 1];
  for (int nn = sub * 4 + wid; nn < Ngr; nn += nsub * 4) {
    int n = g * Ngr + nn;
    unsigned r0 = rowptr[n], r1 = rowptr[n + 1];
    if (r1 == r0) continue;
    unsigned p2 = *(const unsigned*)&P2b[(size_t)n * DF + 2 * lane];
    float base0 = b0 + bf2f((unsigned short)(p2 & 0xffffu));
    float base1 = b1v + bf2f((unsigned short)(p2 >> 16));
    for (unsigned rc = r0; rc < r1; rc += 64) {
      int cnt2 = (int)min(64u, r1 - rc);
      int myE = (lane < cnt2) ? eidb[rc + lane] : 0;
      int myS = (lane < cnt2) ? src[myE] : 0;
      for (int j = 0; j < cnt2; ++j) {
        int e = __shfl(myE, j, 64);
        int s = __shfl(myS, j, 64);
        unsigned p1 = *(const unsigned*)&P1b[(size_t)s * DF + 2 * lane];
        float y0 = fmaxf(base0 + bf2f((unsigned short)(p1 & 0xffffu)), 0.f) * w20;
        float y1 = fmaxf(base1 + bf2f((unsigned short)(p1 >> 16)), 0.f) * w21;
        float v = y0 + y1;
#pragma unroll
        for (int mk = 1; mk < 64; mk <<= 1) v += __shfl_xor(v, mk, 64);
        if (lane == 0) out[e] = sigm(v + w2b);
      }
    }
  }
}

extern "C" void kernel_launch(void* const* d_in, const int* in_sizes, int n_in,
                              void* d_out, int out_size, void* d_ws, size_t ws_size,
                              hipStream_t stream) {
  const float* h_in = (const float*)d_in[0];
  const float* e_in = (const float*)d_in[1];
  const int* src = (const int*)d_in[2];
  const int* dst = (const int*)d_in[3];
  const int* node_graph = (const int*)d_in[4];
  const float* emb_n_w = (const float*)d_in[6];
  const float* emb_n_b = (const float*)d_in[7];
  const float* emb_e_w = (const float*)d_in[8];
  const float* emb_e_b = (const float*)d_in[9];
  const float* Us = (const float*)d_in[10];
  const float* Vs = (const float*)d_in[11];
  const float* As = (const float*)d_in[12];
  const float* Bs = (const float*)d_in[13];
  const float* Cs = (const float*)d_in[14];
  const float* gat_src_w = (const float*)d_in[15];
  const float* gat_src_b = (const float*)d_in[16];
  const float* gat_dst_w = (const float*)d_in[17];
  const float* gat_dst_b = (const float*)d_in[18];
  const float* gat_attn = (const float*)d_in[19];
  const float* gat_bias = (const float*)d_in[20];
  const float* O_w = (const float*)d_in[21];
  const float* O_b = (const float*)d_in[22];
  const float* W1_w = (const float*)d_in[23];
  const float* W1_b = (const float*)d_in[24];
  const float* W2_w = (const float*)d_in[25];
  const float* W2_b = (const float*)d_in[26];
  float* out = (float*)d_out;

  const int N = in_sizes[0] / 64;   // 30000
  const int E = in_sizes[1] / 16;   // 360000
  const int Eg = E / NGRAPH;        // 45000
  const int Ngr = N / NGRAPH;       // 3750

  auto rnd = [](size_t b) { return (b + 255) & ~(size_t)255; };
  const size_t sz_e0 = rnd((size_t)E * DF * 2);
  const size_t sz_node = rnd((size_t)N * DF * 4);
  const size_t sz_nodeb = rnd((size_t)N * DF * 2);
  const size_t sz_score = rnd((size_t)E * 8 * 4);
  const size_t sz_wfrag = rnd(20 * 2048 * 8 * 2);
  const size_t sz_rp = rnd((size_t)(N + 1) * 4);
  const size_t sz_eid = rnd((size_t)E * 4);
  const size_t sz_misc = rnd(4096 * 4);
  const size_t needed_min = sz_e0 + 3 * sz_node + 4 * sz_nodeb + sz_score + sz_wfrag +
                            3 * sz_rp + sz_eid + sz_misc;
  const size_t needed_full = needed_min + sz_e0;  // + xe
  if (ws_size < needed_min) {
    k_fill_u32<<<256, 256, 0, stream>>>((unsigned*)out, 0xBF800000u, (long long)out_size);
    return;
  }
  const bool have_xe = (ws_size >= needed_full);

  char* wp = (char*)d_ws;
  auto alloc = [&](size_t bytes) { void* p = wp; wp += bytes; return p; };
  unsigned short* e0u = (unsigned short*)alloc(sz_e0);
  float* h0 = (float*)alloc(sz_node);
  float* hU = (float*)alloc(sz_node);
  float* rst = (float*)alloc(sz_node);
  unsigned short* hVb = (unsigned short*)alloc(sz_nodeb);
  unsigned short* hBb = (unsigned short*)alloc(sz_nodeb);
  unsigned short* hCb = (unsigned short*)alloc(sz_nodeb);
  unsigned short* h2b = (unsigned short*)alloc(sz_nodeb);
  float* score = (float*)alloc(sz_score);
  short* wfrag = (short*)alloc(sz_wfrag);
  unsigned* rowptr = (unsigned*)alloc(sz_rp);
  unsigned* cursor = (unsigned*)alloc(sz_rp);
  unsigned* deg = (unsigned*)alloc(sz_rp);
  int* eidb = (int*)alloc(sz_eid);
  float* misc = (float*)alloc(sz_misc);
  unsigned short* xe = have_xe ? (unsigned short*)alloc(sz_e0) : nullptr;
  float* stat = misc;                                     // [0,1024)
  float* bias2 = misc + 1024;                             // [1024,1152)
  float* moy = misc + 1152;                               // [1152,2176)
  float* cnt = misc + 2176;                               // [2176,2184)
  float* P0 = misc + 2304;                                // [2304,3328)
  // P1b/P2b alias e0u (dead after last layer apply)
  unsigned short* P1b = e0u;
  unsigned short* P2b = e0u + (size_t)N * DF;

  auto WF = [&](int idx) { return wfrag + (size_t)idx * 2048 * 8; };

  // CSR build (dst lists; reused by layers + GAT + head)
  k_fill_u32<<<64, 256, 0, stream>>>(deg, 0u, N);
  k_deg<<<512, 256, 0, stream>>>(dst, deg, E);
  k_scan<<<1, 1024, 0, stream>>>(deg, rowptr, cursor, N);
  k_scatter<<<512, 256, 0, stream>>>(dst, cursor, eidb, E);

  k_wconv<<<20, 512, 0, stream>>>(Us, Vs, As, Bs, Cs, gat_src_w, gat_dst_w, O_w,
                                  W1_w, wfrag);

  const int gN = (N + 127) / 128;
  k_node_embed<<<2048, 128, 0, stream>>>(h_in, emb_n_w, emb_n_b, h0, N);
  k_edge_embed<<<4096, 128, 0, stream>>>(e_in, emb_e_w, emb_e_b, e0u, E);

  for (int l = 0; l < 3; ++l) {
    k_gemm4_mfma<<<gN, 512, 0, stream>>>(h0, WF(3 + l), WF(l), WF(9 + l), WF(12 + l),
                                         hVb, hU, hBb, hCb, N);
    k_fill_u32<<<4, 256, 0, stream>>>((unsigned*)stat, 0u, 1024);
    k_node_agg<<<512, 256, 0, stream>>>(hU, hVb, e0u, src, rowptr, eidb, stat, Ngr);
    if (have_xe) {
      k_edge_mfma<2><<<256, 512, 0, stream>>>(e0u, WF(6 + l), hBb, hCb, src, dst,
                                              stat, xe, Eg);
      k_bn_finalize<<<1, 256, 0, stream>>>(stat, (float)N, (float)E);
      k_node_update<<<2048, 256, 0, stream>>>(h0, hU, stat, (long long)N * DF);
      k_edge_apply<<<2048, 256, 0, stream>>>(e0u, xe, stat, (long long)E * DF / 8);
    } else {
      k_edge_mfma<0><<<256, 512, 0, stream>>>(e0u, WF(6 + l), hBb, hCb, src, dst,
                                              stat, nullptr, Eg);
      k_bn_finalize<<<1, 256, 0, stream>>>(stat, (float)N, (float)E);
      k_node_update<<<2048, 256, 0, stream>>>(h0, hU, stat, (long long)N * DF);
      k_edge_mfma<1><<<256, 512, 0, stream>>>(e0u, WF(6 + l), hBb, hCb, src, dst,
                                              stat, nullptr, Eg);
    }
  }

  // GATv2: fs -> hVb, fd -> hBb
  k_gemm_mfma<1><<<gN, 512, 0, stream>>>(h0, WF(15), gat_src_b, hVb, N);
  k_gemm_mfma<1><<<gN, 512, 0, stream>>>(h0, WF(16), gat_dst_b, hBb, N);
  k_gat_score<<<512, 256, 0, stream>>>(hVb, hBb, src, dst, gat_attn, score, Eg);
  k_gat_node<<<512, 256, 0, stream>>>(score, hVb, src, rowptr, eidb, rst, Ngr);
  k_bias2<<<1, 128, 0, stream>>>(gat_bias, O_w, O_b, bias2);
  k_gemm_mfma<1><<<gN, 512, 0, stream>>>(rst, WF(17), bias2, h2b, N);  // h2

  // readout + decomposed head
  k_fill_u32<<<2, 256, 0, stream>>>((unsigned*)moy, 0u, 1032);
  k_moy<<<128, 128, 0, stream>>>(h2b, node_graph, moy, cnt, N);
  k_p0<<<8, 128, 0, stream>>>(W1_w, W1_b, moy, cnt, P0);
  k_gemmb_mfma<<<gN, 512, 0, stream>>>(h2b, WF(18), P1b, N);
  k_gemmb_mfma<<<gN, 512, 0, stream>>>(h2b, WF(19), P2b, N);
  k_head<<<1024, 256, 0, stream>>>(P1b, P2b, P0, src, rowptr, eidb, W2_w, W2_b,
                                   out, Ngr);
}

// Round 10
// 1477.780 us; speedup vs baseline: 1.7376x; 1.2777x over previous
//
#include <hip/hip_runtime.h>

#define DF 128
#define NGRAPH 8

typedef __attribute__((ext_vector_type(8))) short bf16x8;
typedef __attribute__((ext_vector_type(4))) float f32x4;

__device__ __forceinline__ float sigm(float x) { return 1.f / (1.f + __expf(-x)); }
__device__ __forceinline__ unsigned short f2bf(float f) {  // RNE f32->bf16
  unsigned u = __float_as_uint(f);
  u += 0x7FFFu + ((u >> 16) & 1u);
  return (unsigned short)(u >> 16);
}
__device__ __forceinline__ float bf2f(unsigned short u) {
  return __uint_as_float(((unsigned)u) << 16);
}
__device__ __forceinline__ float bflo(unsigned u) { return __uint_as_float(u << 16); }
__device__ __forceinline__ float bfhi(unsigned u) { return __uint_as_float(u & 0xffff0000u); }

// load 8 consecutive f32 (32B-aligned) -> bf16x8
__device__ __forceinline__ bf16x8 cvt8(const float* __restrict__ p) {
  float4 a = *(const float4*)p;
  float4 b = *(const float4*)(p + 4);
  bf16x8 r;
  r[0] = (short)f2bf(a.x); r[1] = (short)f2bf(a.y);
  r[2] = (short)f2bf(a.z); r[3] = (short)f2bf(a.w);
  r[4] = (short)f2bf(b.x); r[5] = (short)f2bf(b.y);
  r[6] = (short)f2bf(b.z); r[7] = (short)f2bf(b.w);
  return r;
}

__device__ __forceinline__ void agg_max(unsigned hv, unsigned ev, float& m0, float& m1) {
  m0 = fmaxf(m0, bflo(hv) * sigm(bflo(ev)));
  m1 = fmaxf(m1, bfhi(hv) * sigm(bfhi(ev)));
}

// ---------------- generic fill ----------------
__global__ void k_fill_u32(unsigned* __restrict__ p, unsigned v, long long n) {
  long long i = (long long)blockIdx.x * blockDim.x + threadIdx.x;
  long long st = (long long)gridDim.x * blockDim.x;
  for (; i < n; i += st) p[i] = v;
}

// ---------------- CSR build (dst-sorted edge lists) ----------------
__global__ void k_deg(const int* __restrict__ dst, unsigned* __restrict__ deg, int E) {
  int i = blockIdx.x * blockDim.x + threadIdx.x;
  int st = gridDim.x * blockDim.x;
  for (; i < E; i += st) atomicAdd(&deg[dst[i]], 1u);
}

__global__ __launch_bounds__(1024) void k_scan(
    const unsigned* __restrict__ deg, unsigned* __restrict__ rowptr,
    unsigned* __restrict__ cursor, int N) {
  __shared__ unsigned part[1024];
  int t = threadIdx.x;
  int per = (N + 1023) >> 10;
  int s0 = t * per, s1 = min(N, s0 + per);
  unsigned s = 0;
  for (int i = s0; i < s1; ++i) s += deg[i];
  part[t] = s;
  __syncthreads();
  for (int off = 1; off < 1024; off <<= 1) {
    unsigned v = (t >= off) ? part[t - off] : 0u;
    __syncthreads();
    part[t] += v;
    __syncthreads();
  }
  unsigned base = (t == 0) ? 0u : part[t - 1];
  for (int i = s0; i < s1; ++i) {
    rowptr[i] = base;
    cursor[i] = base;
    base += deg[i];
  }
  if (t == 1023) rowptr[N] = part[1023];
}

__global__ void k_scatter(const int* __restrict__ dst, unsigned* __restrict__ cursor,
                          int* __restrict__ eidb, int E) {
  int i = blockIdx.x * blockDim.x + threadIdx.x;
  int st = gridDim.x * blockDim.x;
  for (; i < E; i += st) {
    unsigned p = atomicAdd(&cursor[dst[i]], 1u);
    eidb[p] = i;
  }
}

// ---------------- weight pre-conversion to MFMA fragment order ----------------
// 0-2 U, 3-5 V, 6-8 A, 9-11 B, 12-14 C, 15 gsw, 16 gdw, 17 Ow, 18 W1[:,128:256], 19 W1[:,256:384]
__global__ __launch_bounds__(512) void k_wconv(
    const float* __restrict__ Us, const float* __restrict__ Vs,
    const float* __restrict__ As, const float* __restrict__ Bs,
    const float* __restrict__ Cs, const float* __restrict__ gsw,
    const float* __restrict__ gdw, const float* __restrict__ Ow,
    const float* __restrict__ W1, short* __restrict__ out) {
  int b = blockIdx.x;
  const float* W;
  int ldw = DF;
  if (b < 3) W = Us + b * 16384;
  else if (b < 6) W = Vs + (b - 3) * 16384;
  else if (b < 9) W = As + (b - 6) * 16384;
  else if (b < 12) W = Bs + (b - 9) * 16384;
  else if (b < 15) W = Cs + (b - 12) * 16384;
  else if (b == 15) W = gsw;
  else if (b == 16) W = gdw;
  else if (b == 17) W = Ow;
  else if (b == 18) { W = W1 + 128; ldw = 384; }
  else { W = W1 + 256; ldw = 384; }
  short* o = out + (size_t)b * 2048 * 8;
  for (int s = threadIdx.x; s < 2048; s += 512) {
    int ct = s >> 8, ks = (s >> 6) & 3, l = s & 63;
    int row = ct * 16 + (l & 15), k0 = ks * 32 + (l >> 4) * 8;
    *(bf16x8*)&o[s * 8] = cvt8(W + (size_t)row * ldw + k0);
  }
}

// ---------------- embeddings ----------------
__global__ __launch_bounds__(128) void k_node_embed(
    const float* __restrict__ hin, const float* __restrict__ w,
    const float* __restrict__ b, float* __restrict__ h0, int rows) {
  __shared__ float Wt[64 * DF];
  __shared__ float ar[4][64];
  int tid = threadIdx.x;
  for (int i = tid; i < 64 * DF; i += 128) Wt[(i & 63) * DF + (i >> 6)] = w[i];
  float bb = b[tid];
  __syncthreads();
  for (int r0 = blockIdx.x * 4; r0 < rows; r0 += gridDim.x * 4) {
    for (int i = tid; i < 256; i += 128) ar[i >> 6][i & 63] = hin[(size_t)r0 * 64 + i];
    __syncthreads();
    float a0 = bb, a1 = bb, a2 = bb, a3 = bb;
#pragma unroll 8
    for (int k = 0; k < 64; ++k) {
      float wv = Wt[k * DF + tid];
      a0 = fmaf(ar[0][k], wv, a0); a1 = fmaf(ar[1][k], wv, a1);
      a2 = fmaf(ar[2][k], wv, a2); a3 = fmaf(ar[3][k], wv, a3);
    }
    h0[(size_t)r0 * DF + tid] = a0;
    h0[(size_t)(r0 + 1) * DF + tid] = a1;
    h0[(size_t)(r0 + 2) * DF + tid] = a2;
    h0[(size_t)(r0 + 3) * DF + tid] = a3;
    __syncthreads();
  }
}

__global__ __launch_bounds__(128) void k_edge_embed(
    const float* __restrict__ ein, const float* __restrict__ w,
    const float* __restrict__ b, unsigned short* __restrict__ e0u, int rows) {
  __shared__ float Wt[16 * DF];
  __shared__ float ar[4][16];
  int tid = threadIdx.x;
  for (int i = tid; i < 16 * DF; i += 128) Wt[(i & 15) * DF + (i >> 4)] = w[i];
  float bb = b[tid];
  __syncthreads();
  for (int r0 = blockIdx.x * 4; r0 < rows; r0 += gridDim.x * 4) {
    if (tid < 64) ar[tid >> 4][tid & 15] = ein[(size_t)r0 * 16 + tid];
    __syncthreads();
    float a0 = bb, a1 = bb, a2 = bb, a3 = bb;
#pragma unroll
    for (int k = 0; k < 16; ++k) {
      float wv = Wt[k * DF + tid];
      a0 = fmaf(ar[0][k], wv, a0); a1 = fmaf(ar[1][k], wv, a1);
      a2 = fmaf(ar[2][k], wv, a2); a3 = fmaf(ar[3][k], wv, a3);
    }
    e0u[(size_t)r0 * DF + tid] = f2bf(a0);
    e0u[(size_t)(r0 + 1) * DF + tid] = f2bf(a1);
    e0u[(size_t)(r0 + 2) * DF + tid] = f2bf(a2);
    e0u[(size_t)(r0 + 3) * DF + tid] = f2bf(a3);
    __syncthreads();
  }
}

// ---------------- MFMA [rows,128] @ W^T (+bias), frag weights, f32 input ----------------
template <int OUTBF>
__global__ __launch_bounds__(512) void k_gemm_mfma(
    const float* __restrict__ A, const short* __restrict__ Wf,
    const float* __restrict__ bias, void* __restrict__ outv, int rows) {
  __shared__ short Wb[2048 * 8];  // 32 KB
  int tid = threadIdx.x;
  for (int s = tid; s < 2048; s += 512)
    *(bf16x8*)&Wb[s * 8] = *(const bf16x8*)&Wf[(size_t)s * 8];
  __syncthreads();
  float* outf = (float*)outv;
  unsigned short* outb = (unsigned short*)outv;
  int wid = tid >> 6, lane = tid & 63, q = lane >> 4, m = lane & 15;
  int ntiles = (rows + 127) >> 7;
  for (int t = blockIdx.x; t < ntiles; t += gridDim.x) {
    int r0 = t * 128 + wid * 16;
    int rr = r0 + m;
    if (rr >= rows) rr = rows - 1;
    const float* ap = A + (size_t)rr * DF + q * 8;
    bf16x8 a[4];
#pragma unroll
    for (int ks = 0; ks < 4; ++ks) a[ks] = cvt8(ap + 32 * ks);
#pragma unroll
    for (int ct = 0; ct < 8; ++ct) {
      f32x4 acc = {0.f, 0.f, 0.f, 0.f};
#pragma unroll
      for (int ks = 0; ks < 4; ++ks) {
        bf16x8 b = *(const bf16x8*)&Wb[((ct * 4 + ks) * 64 + lane) * 8];
        acc = __builtin_amdgcn_mfma_f32_16x16x32_bf16(a[ks], b, acc, 0, 0, 0);
      }
      int col = ct * 16 + m;
      float bb = bias ? bias[col] : 0.f;
#pragma unroll
      for (int j = 0; j < 4; ++j) {
        int row = r0 + q * 4 + j;
        if (row < rows) {
          if (OUTBF) outb[(size_t)row * DF + col] = f2bf(acc[j] + bb);
          else outf[(size_t)row * DF + col] = acc[j] + bb;
        }
      }
    }
  }
}

// same, bf16 input
__global__ __launch_bounds__(512) void k_gemmb_mfma(
    const unsigned short* __restrict__ A, const short* __restrict__ Wf,
    unsigned short* __restrict__ outb, int rows) {
  __shared__ short Wb[2048 * 8];
  int tid = threadIdx.x;
  for (int s = tid; s < 2048; s += 512)
    *(bf16x8*)&Wb[s * 8] = *(const bf16x8*)&Wf[(size_t)s * 8];
  __syncthreads();
  int wid = tid >> 6, lane = tid & 63, q = lane >> 4, m = lane & 15;
  int ntiles = (rows + 127) >> 7;
  for (int t = blockIdx.x; t < ntiles; t += gridDim.x) {
    int r0 = t * 128 + wid * 16;
    int rr = r0 + m;
    if (rr >= rows) rr = rows - 1;
    const unsigned short* ap = A + (size_t)rr * DF + q * 8;
    bf16x8 a[4];
#pragma unroll
    for (int ks = 0; ks < 4; ++ks) a[ks] = *(const bf16x8*)(ap + 32 * ks);
#pragma unroll
    for (int ct = 0; ct < 8; ++ct) {
      f32x4 acc = {0.f, 0.f, 0.f, 0.f};
#pragma unroll
      for (int ks = 0; ks < 4; ++ks) {
        bf16x8 b = *(const bf16x8*)&Wb[((ct * 4 + ks) * 64 + lane) * 8];
        acc = __builtin_amdgcn_mfma_f32_16x16x32_bf16(a[ks], b, acc, 0, 0, 0);
      }
      int col = ct * 16 + m;
#pragma unroll
      for (int j = 0; j < 4; ++j) {
        int row = r0 + q * 4 + j;
        if (row < rows) outb[(size_t)row * DF + col] = f2bf(acc[j]);
      }
    }
  }
}

// ---------------- fused 4-output node GEMM (V,U,B,C) ----------------
__global__ __launch_bounds__(512) void k_gemm4_mfma(
    const float* __restrict__ h0, const short* __restrict__ Vf,
    const short* __restrict__ Uf, const short* __restrict__ Bf,
    const short* __restrict__ Cf, unsigned short* __restrict__ hVb,
    float* __restrict__ hU, unsigned short* __restrict__ hBb,
    unsigned short* __restrict__ hCb, int rows) {
  __shared__ short Wl[4 * 2048 * 8];  // 128 KB
  int tid = threadIdx.x;
  for (int s = tid; s < 2048; s += 512) {
    *(bf16x8*)&Wl[(size_t)s * 8] = *(const bf16x8*)&Vf[(size_t)s * 8];
    *(bf16x8*)&Wl[(size_t)(2048 + s) * 8] = *(const bf16x8*)&Uf[(size_t)s * 8];
    *(bf16x8*)&Wl[(size_t)(4096 + s) * 8] = *(const bf16x8*)&Bf[(size_t)s * 8];
    *(bf16x8*)&Wl[(size_t)(6144 + s) * 8] = *(const bf16x8*)&Cf[(size_t)s * 8];
  }
  __syncthreads();
  int wid = tid >> 6, lane = tid & 63, q = lane >> 4, m = lane & 15;
  int ntiles = (rows + 127) >> 7;
  for (int t = blockIdx.x; t < ntiles; t += gridDim.x) {
    int r0 = t * 128 + wid * 16;
    int rr = r0 + m;
    if (rr >= rows) rr = rows - 1;
    const float* ap = h0 + (size_t)rr * DF + q * 8;
    bf16x8 a[4];
#pragma unroll
    for (int ks = 0; ks < 4; ++ks) a[ks] = cvt8(ap + 32 * ks);
#pragma unroll
    for (int w = 0; w < 4; ++w) {
#pragma unroll
      for (int ct = 0; ct < 8; ++ct) {
        f32x4 acc = {0.f, 0.f, 0.f, 0.f};
#pragma unroll
        for (int ks = 0; ks < 4; ++ks) {
          bf16x8 b = *(const bf16x8*)&Wl[((w * 2048) + (ct * 4 + ks) * 64 + lane) * 8];
          acc = __builtin_amdgcn_mfma_f32_16x16x32_bf16(a[ks], b, acc, 0, 0, 0);
        }
        int col = ct * 16 + m;
#pragma unroll
        for (int j = 0; j < 4; ++j) {
          int row = r0 + q * 4 + j;
          if (row < rows) {
            if (w == 1) hU[(size_t)row * DF + col] = acc[j];
            else {
              unsigned short v = f2bf(acc[j]);
              unsigned short* o = (w == 0) ? hVb : ((w == 2) ? hBb : hCb);
              o[(size_t)row * DF + col] = v;
            }
          }
        }
      }
    }
  }
}

// ---------------- MFMA edge pass: x = e@As^T + hB[dst] + hC[src] ----------------
// MODE 0: stats only. MODE 1: apply w/ recompute. MODE 2: stats + store x (bf16).
template <int MODE>
__global__ __launch_bounds__(512) void k_edge_mfma(
    unsigned short* __restrict__ e0u, const short* __restrict__ Af,
    const unsigned short* __restrict__ hBb, const unsigned short* __restrict__ hCb,
    const int* __restrict__ src, const int* __restrict__ dst,
    float* __restrict__ stat, unsigned short* __restrict__ xe, int Eg) {
  __shared__ short Wb[2048 * 8];     // 32 KB
  __shared__ float xt[8][16 * 132];  // 66 KB
  int tid = threadIdx.x;
  for (int s = tid; s < 2048; s += 512)
    *(bf16x8*)&Wb[s * 8] = *(const bf16x8*)&Af[(size_t)s * 8];
  int wid = tid >> 6, lane = tid & 63, q = lane >> 4, m = lane & 15;
  int g = blockIdx.x & 7, sub = blockIdx.x >> 3, nsub = gridDim.x >> 3;
  int gbase = g * Eg, gend = gbase + Eg;
  int tpg = (Eg + 127) >> 7;
  float* xw = xt[wid];
  float ps0 = 0.f, ps1 = 0.f, pq0 = 0.f, pq1 = 0.f;
  __syncthreads();
  for (int t = sub; t < tpg; t += nsub) {
    int r0 = gbase + t * 128 + wid * 16;
    int edge = r0 + m;
    bool ok = edge < gend;
    int ec = ok ? edge : gend - 1;
    const unsigned short* ep = e0u + (size_t)ec * DF + q * 8;
    bf16x8 a[4];
#pragma unroll
    for (int ks = 0; ks < 4; ++ks) a[ks] = *(const bf16x8*)(ep + 32 * ks);
#pragma unroll
    for (int ct = 0; ct < 8; ++ct) {
      f32x4 acc = {0.f, 0.f, 0.f, 0.f};
#pragma unroll
      for (int ks = 0; ks < 4; ++ks) {
        bf16x8 b = *(const bf16x8*)&Wb[((ct * 4 + ks) * 64 + lane) * 8];
        acc = __builtin_amdgcn_mfma_f32_16x16x32_bf16(a[ks], b, acc, 0, 0, 0);
      }
#pragma unroll
      for (int j = 0; j < 4; ++j) xw[(q * 4 + j) * 132 + ct * 16 + m] = acc[j];
    }
    __syncthreads();
    int sidx = src[ec], didx = dst[ec];
    const unsigned short* pb = hBb + (size_t)didx * DF;
    const unsigned short* pc = hCb + (size_t)sidx * DF;
#pragma unroll
    for (int ks = 0; ks < 4; ++ks) {
      int c0 = q * 8 + 32 * ks;
      float* xp = &xw[m * 132 + c0];
      bf16x8 gb = *(const bf16x8*)(pb + c0);
      bf16x8 gc = *(const bf16x8*)(pc + c0);
      float x[8];
#pragma unroll
      for (int i = 0; i < 8; ++i)
        x[i] = xp[i] + bf2f((unsigned short)gb[i]) + bf2f((unsigned short)gc[i]);
      if (MODE == 1) {
        bf16x8 nv;
#pragma unroll
        for (int i = 0; i < 8; ++i) {
          float mm = stat[768 + c0 + i], iv = stat[896 + c0 + i];
          nv[i] = (short)f2bf(bf2f((unsigned short)a[ks][i]) + fmaxf((x[i] - mm) * iv, 0.f));
        }
        if (ok) *(bf16x8*)(e0u + (size_t)ec * DF + c0) = nv;
      } else {
        if (MODE == 2 && ok) {
          bf16x8 xv;
#pragma unroll
          for (int i = 0; i < 8; ++i) xv[i] = (short)f2bf(x[i]);
          *(bf16x8*)(xe + (size_t)ec * DF + c0) = xv;
        }
#pragma unroll
        for (int i = 0; i < 8; ++i) xp[i] = ok ? x[i] : 0.f;
      }
    }
    if (MODE != 1) {
      __syncthreads();
#pragma unroll 4
      for (int r = 0; r < 16; ++r) {
        float2 v = *(float2*)&xw[r * 132 + 2 * lane];
        ps0 += v.x; ps1 += v.y;
        pq0 += v.x * v.x; pq1 += v.y * v.y;
      }
    }
    __syncthreads();
  }
  if (MODE != 1) {
    atomicAdd(&stat[512 + 2 * lane], ps0);
    atomicAdd(&stat[512 + 2 * lane + 1], ps1);
    atomicAdd(&stat[640 + 2 * lane], pq0);
    atomicAdd(&stat[640 + 2 * lane + 1], pq1);
  }
}

// streaming apply: e += relu((x - m)*iv), all bf16
__global__ __launch_bounds__(256) void k_edge_apply(
    unsigned short* __restrict__ e0u, const unsigned short* __restrict__ xe,
    const float* __restrict__ stat, long long n8) {
  long long i = (long long)blockIdx.x * blockDim.x + threadIdx.x;
  long long st = (long long)gridDim.x * blockDim.x;
  for (; i < n8; i += st) {
    int c0 = (int)(i & 15) * 8;
    bf16x8 ev = *(const bf16x8*)(e0u + i * 8);
    bf16x8 xv = *(const bf16x8*)(xe + i * 8);
    bf16x8 nv;
#pragma unroll
    for (int k = 0; k < 8; ++k) {
      float mm = stat[768 + c0 + k], iv = stat[896 + c0 + k];
      nv[k] = (short)f2bf(bf2f((unsigned short)ev[k]) +
                          fmaxf((bf2f((unsigned short)xv[k]) - mm) * iv, 0.f));
    }
    *(bf16x8*)(e0u + i * 8) = nv;
  }
}

// ---------------- node-major segment max + hU update + BN stats ----------------
// wave/node; lane owns feats 2*lane,2*lane+1; batch-prefetched CSR, 4-way unrolled.
__global__ __launch_bounds__(256) void k_node_agg(
    float* __restrict__ hU, const unsigned short* __restrict__ hVb,
    const unsigned short* __restrict__ e0u, const int* __restrict__ src,
    const unsigned* __restrict__ rowptr, const int* __restrict__ eidb,
    float* __restrict__ stat, int Ngr) {
  __shared__ float sr[4][256];
  int tid = threadIdx.x, wid = tid >> 6, lane = tid & 63;
  int g = blockIdx.x & 7, sub = blockIdx.x >> 3, nsub = gridDim.x >> 3;
  float ps0 = 0.f, ps1 = 0.f, pq0 = 0.f, pq1 = 0.f;
  for (int nn = sub * 4 + wid; nn < Ngr; nn += nsub * 4) {
    int n = g * Ngr + nn;
    unsigned r0 = rowptr[n], r1 = rowptr[n + 1];
    float m0 = -3.4e38f, m1 = -3.4e38f;
    for (unsigned rc = r0; rc < r1; rc += 64) {
      int batch = (int)min(64u, r1 - rc);
      int myE = eidb[rc + ((lane < batch) ? lane : 0)];
      int myS = src[myE];
      int j = 0;
      for (; j + 4 <= batch; j += 4) {
        int e0 = __shfl(myE, j, 64), e1 = __shfl(myE, j + 1, 64);
        int e2 = __shfl(myE, j + 2, 64), e3 = __shfl(myE, j + 3, 64);
        int s0 = __shfl(myS, j, 64), s1 = __shfl(myS, j + 1, 64);
        int s2 = __shfl(myS, j + 2, 64), s3 = __shfl(myS, j + 3, 64);
        unsigned h0v = *(const unsigned*)&hVb[(size_t)s0 * DF + 2 * lane];
        unsigned h1v = *(const unsigned*)&hVb[(size_t)s1 * DF + 2 * lane];
        unsigned h2v = *(const unsigned*)&hVb[(size_t)s2 * DF + 2 * lane];
        unsigned h3v = *(const unsigned*)&hVb[(size_t)s3 * DF + 2 * lane];
        unsigned v0 = *(const unsigned*)&e0u[(size_t)e0 * DF + 2 * lane];
        unsigned v1 = *(const unsigned*)&e0u[(size_t)e1 * DF + 2 * lane];
        unsigned v2 = *(const unsigned*)&e0u[(size_t)e2 * DF + 2 * lane];
        unsigned v3 = *(const unsigned*)&e0u[(size_t)e3 * DF + 2 * lane];
        agg_max(h0v, v0, m0, m1);
        agg_max(h1v, v1, m0, m1);
        agg_max(h2v, v2, m0, m1);
        agg_max(h3v, v3, m0, m1);
      }
      for (; j < batch; ++j) {
        int e = __shfl(myE, j, 64);
        int s = __shfl(myS, j, 64);
        unsigned hv = *(const unsigned*)&hVb[(size_t)s * DF + 2 * lane];
        unsigned ev = *(const unsigned*)&e0u[(size_t)e * DF + 2 * lane];
        agg_max(hv, ev, m0, m1);
      }
    }
    if (r1 == r0) { m0 = 0.f; m1 = 0.f; }
    size_t idx = (size_t)n * DF + 2 * lane;
    float2 hu = *(float2*)&hU[idx];
    float t0 = hu.x + m0, t1 = hu.y + m1;
    hu.x = t0; hu.y = t1;
    *(float2*)&hU[idx] = hu;
    ps0 += t0; ps1 += t1;
    pq0 += t0 * t0; pq1 += t1 * t1;
  }
  sr[0][tid] = ps0; sr[1][tid] = ps1; sr[2][tid] = pq0; sr[3][tid] = pq1;
  __syncthreads();
  if (tid < 64) {
    float a0 = 0.f, a1 = 0.f, b0 = 0.f, b1 = 0.f;
#pragma unroll
    for (int w = 0; w < 4; ++w) {
      a0 += sr[0][w * 64 + tid]; a1 += sr[1][w * 64 + tid];
      b0 += sr[2][w * 64 + tid]; b1 += sr[3][w * 64 + tid];
    }
    atomicAdd(&stat[2 * tid], a0);
    atomicAdd(&stat[2 * tid + 1], a1);
    atomicAdd(&stat[128 + 2 * tid], b0);
    atomicAdd(&stat[128 + 2 * tid + 1], b1);
  }
}

// finalize BN stats
__global__ void k_bn_finalize(float* __restrict__ stat, float nN, float nE) {
  int tid = threadIdx.x;
  if (tid < 128) {
    float mean = stat[tid] / nN;
    float var = stat[128 + tid] / nN - mean * mean;
    stat[256 + tid] = mean;
    stat[384 + tid] = rsqrtf(fmaxf(var, 0.f) + 1e-5f);
  } else {
    int d = tid - 128;
    float mean = stat[512 + d] / nE;
    float var = stat[640 + d] / nE - mean * mean;
    stat[768 + d] = mean;
    stat[896 + d] = rsqrtf(fmaxf(var, 0.f) + 1e-5f);
  }
}

__global__ __launch_bounds__(256) void k_node_update(
    float* __restrict__ h0, const float* __restrict__ hU,
    const float* __restrict__ stat, long long total) {
  long long i = (long long)blockIdx.x * blockDim.x + threadIdx.x;
  long long st = (long long)gridDim.x * blockDim.x;
  for (; i < total; i += st) {
    int d = (int)(i & 127);
    float t = (hU[i] - stat[256 + d]) * stat[384 + d];
    h0[i] += fmaxf(t, 0.f);
  }
}

// ---------------- GATv2 score (edge-major) ----------------
__global__ __launch_bounds__(256) void k_gat_score(
    const unsigned short* __restrict__ fsb, const unsigned short* __restrict__ fdb,
    const int* __restrict__ src, const int* __restrict__ dst,
    const float* __restrict__ attn, float* __restrict__ score, int Eg) {
  int g = blockIdx.x & 7, sub = blockIdx.x >> 3, nsub = gridDim.x >> 3;
  int gbase = g * Eg, gend = gbase + Eg;
  int tpg = (Eg + 127) >> 7;
  int tid = threadIdx.x;
  for (int t = sub; t < tpg; t += nsub) {
    int ebase = gbase + t * 128;
    for (int k = tid; k < 1024; k += 256) {
      int e = ebase + (k >> 3);
      if (e >= gend) break;
      int mh = k & 7;
      int s = src[e], dn = dst[e];
      const unsigned short* ps = fsb + (size_t)s * DF + mh * 16;
      const unsigned short* pd = fdb + (size_t)dn * DF + mh * 16;
      const float* pa = attn + mh * 16;
      bf16x8 s0 = *(const bf16x8*)ps;
      bf16x8 s1 = *(const bf16x8*)(ps + 8);
      bf16x8 d0 = *(const bf16x8*)pd;
      bf16x8 d1 = *(const bf16x8*)(pd + 8);
      float acc = 0.f;
#pragma unroll
      for (int kk = 0; kk < 8; ++kk) {
        float z = bf2f((unsigned short)s0[kk]) + bf2f((unsigned short)d0[kk]);
        z = (z > 0.f) ? z : 0.2f * z;
        acc = fmaf(z, pa[kk], acc);
        float z2 = bf2f((unsigned short)s1[kk]) + bf2f((unsigned short)d1[kk]);
        z2 = (z2 > 0.f) ? z2 : 0.2f * z2;
        acc = fmaf(z2, pa[kk + 8], acc);
      }
      score[(size_t)e * 8 + mh] = acc;
    }
  }
}

// ---------------- GATv2 node reduction (batched CSR, unrolled) ----------------
// wave/node; head = lane>>3, slot = lane&7; feats 2*lane, 2*lane+1.
__global__ __launch_bounds__(256) void k_gat_node(
    const float* __restrict__ score, const unsigned short* __restrict__ fsb,
    const int* __restrict__ src, const unsigned* __restrict__ rowptr,
    const int* __restrict__ eidb, float* __restrict__ rst, int Ngr) {
  int tid = threadIdx.x, wid = tid >> 6, lane = tid & 63;
  int g = blockIdx.x & 7, sub = blockIdx.x >> 3, nsub = gridDim.x >> 3;
  int head = lane >> 3, slot = lane & 7;
  for (int nn = sub * 4 + wid; nn < Ngr; nn += nsub * 4) {
    int n = g * Ngr + nn;
    unsigned r0 = rowptr[n], r1 = rowptr[n + 1];
    // pass 1: head max (slot-parallel)
    float hm = -3.4e38f;
    for (unsigned rc = r0; rc < r1; rc += 64) {
      int batch = (int)min(64u, r1 - rc);
      int myE = eidb[rc + ((lane < batch) ? lane : 0)];
      for (int k = slot; k < batch; k += 8) {
        int e = __shfl(myE, k, 64);
        hm = fmaxf(hm, score[(size_t)e * 8 + head]);
      }
    }
#pragma unroll
    for (int mk = 1; mk < 8; mk <<= 1) hm = fmaxf(hm, __shfl_xor(hm, mk, 64));
    // pass 2: denom (slot-parallel)
    float dn = 0.f;
    for (unsigned rc = r0; rc < r1; rc += 64) {
      int batch = (int)min(64u, r1 - rc);
      int myE = eidb[rc + ((lane < batch) ? lane : 0)];
      for (int k = slot; k < batch; k += 8) {
        int e = __shfl(myE, k, 64);
        dn += __expf(score[(size_t)e * 8 + head] - hm);
      }
    }
#pragma unroll
    for (int mk = 1; mk < 8; mk <<= 1) dn += __shfl_xor(dn, mk, 64);
    float inv = (r1 > r0) ? 1.f / dn : 0.f;
    // pass 3: weighted sum (4-way unrolled)
    float a0 = 0.f, a1 = 0.f;
    for (unsigned rc = r0; rc < r1; rc += 64) {
      int batch = (int)min(64u, r1 - rc);
      int myE = eidb[rc + ((lane < batch) ? lane : 0)];
      int myS = src[myE];
      int j = 0;
      for (; j + 4 <= batch; j += 4) {
        int e0 = __shfl(myE, j, 64), e1 = __shfl(myE, j + 1, 64);
        int e2 = __shfl(myE, j + 2, 64), e3 = __shfl(myE, j + 3, 64);
        int s0 = __shfl(myS, j, 64), s1 = __shfl(myS, j + 1, 64);
        int s2 = __shfl(myS, j + 2, 64), s3 = __shfl(myS, j + 3, 64);
        float sc0 = score[(size_t)e0 * 8 + head];
        float sc1 = score[(size_t)e1 * 8 + head];
        float sc2 = score[(size_t)e2 * 8 + head];
        float sc3 = score[(size_t)e3 * 8 + head];
        unsigned f0 = *(const unsigned*)&fsb[(size_t)s0 * DF + 2 * lane];
        unsigned f1 = *(const unsigned*)&fsb[(size_t)s1 * DF + 2 * lane];
        unsigned f2 = *(const unsigned*)&fsb[(size_t)s2 * DF + 2 * lane];
        unsigned f3 = *(const unsigned*)&fsb[(size_t)s3 * DF + 2 * lane];
        float w0 = __expf(sc0 - hm) * inv, w1 = __expf(sc1 - hm) * inv;
        float w2 = __expf(sc2 - hm) * inv, w3 = __expf(sc3 - hm) * inv;
        a0 = fmaf(w0, bflo(f0), a0); a1 = fmaf(w0, bfhi(f0), a1);
        a0 = fmaf(w1, bflo(f1), a0); a1 = fmaf(w1, bfhi(f1), a1);
        a0 = fmaf(w2, bflo(f2), a0); a1 = fmaf(w2, bfhi(f2), a1);
        a0 = fmaf(w3, bflo(f3), a0); a1 = fmaf(w3, bfhi(f3), a1);
      }
      for (; j < batch; ++j) {
        int e = __shfl(myE, j, 64);
        int s = __shfl(myS, j, 64);
        float w = __expf(score[(size_t)e * 8 + head] - hm) * inv;
        unsigned fv = *(const unsigned*)&fsb[(size_t)s * DF + 2 * lane];
        a0 = fmaf(w, bflo(fv), a0);
        a1 = fmaf(w, bfhi(fv), a1);
      }
    }
    float2 o;
    o.x = a0; o.y = a1;
    *(float2*)&rst[(size_t)n * DF + 2 * lane] = o;
  }
}

// bias2 = O_b + gat_bias @ O_w^T
__global__ void k_bias2(const float* __restrict__ gat_bias,
                        const float* __restrict__ O_w,
                        const float* __restrict__ O_b, float* __restrict__ bias2) {
  int d = threadIdx.x;
  float acc = O_b[d];
  for (int k = 0; k < DF; ++k) acc = fmaf(gat_bias[k], O_w[(size_t)d * DF + k], acc);
  bias2[d] = acc;
}

// ---------------- readout ----------------
__global__ __launch_bounds__(128) void k_moy(
    const unsigned short* __restrict__ h2b, const int* __restrict__ ng,
    float* __restrict__ moy, float* __restrict__ cnt, int rows) {
  int tid = threadIdx.x;
  int per = (rows + gridDim.x - 1) / gridDim.x;
  int n0 = blockIdx.x * per;
  int n1 = min(rows, n0 + per);
  if (n0 >= n1) return;
  int cur = ng[n0];
  float acc = 0.f; int c = 0;
  for (int n = n0; n < n1; ++n) {
    int g = ng[n];
    if (g != cur) {
      atomicAdd(&moy[cur * DF + tid], acc);
      if (tid == 0) atomicAdd(&cnt[cur], (float)c);
      acc = 0.f; c = 0; cur = g;
    }
    acc += bf2f(h2b[(size_t)n * DF + tid]);
    ++c;
  }
  atomicAdd(&moy[cur * DF + tid], acc);
  if (tid == 0) atomicAdd(&cnt[cur], (float)c);
}

// P0[g] = W1[:,0:128] @ (moy_sum[g]/cnt[g]) + W1_b
__global__ void k_p0(const float* __restrict__ W1, const float* __restrict__ W1b_,
                     const float* __restrict__ moy, const float* __restrict__ cnt,
                     float* __restrict__ P0) {
  int g = blockIdx.x, d = threadIdx.x;
  float inv = 1.f / cnt[g];
  float acc = W1b_[d];
  for (int k = 0; k < DF; ++k) acc = fmaf(W1[(size_t)d * 384 + k], moy[g * DF + k] * inv, acc);
  P0[g * DF + d] = acc;
}

// ---------------- CSR head: out[e] = sigm(W2 . relu(P0[g]+P1[src]+P2[dst]) + b2) ----------------
__global__ __launch_bounds__(256) void k_head(
    const unsigned short* __restrict__ P1b, const unsigned short* __restrict__ P2b,
    const float* __restrict__ P0, const int* __restrict__ src,
    const unsigned* __restrict__ rowptr, const int* __restrict__ eidb,
    const float* __restrict__ W2, const float* __restrict__ W2b,
    float* __restrict__ out, int Ngr) {
  int tid = threadIdx.x, wid = tid >> 6, lane = tid & 63;
  int g = blockIdx.x & 7, sub = blockIdx.x >> 3, nsub = gridDim.x >> 3;
  float w2b = W2b[0];
  float w20 = W2[2 * lane], w21 = W2[2 * lane + 1];
  float b0 = P0[g * DF + 2 * lane], b1v = P0[g * DF + 2 * lane + 1];
  for (int nn = sub * 4 + wid; nn < Ngr; nn += nsub * 4) {
    int n = g * Ngr + nn;
    unsigned r0 = rowptr[n], r1 = rowptr[n + 1];
    if (r1 == r0) continue;
    unsigned p2 = *(const unsigned*)&P2b[(size_t)n * DF + 2 * lane];
    float base0 = b0 + bflo(p2);
    float base1 = b1v + bfhi(p2);
    for (unsigned rc = r0; rc < r1; rc += 64) {
      int cnt2 = (int)min(64u, r1 - rc);
      int myE = eidb[rc + ((lane < cnt2) ? lane : 0)];
      int myS = src[myE];
      int j = 0;
      for (; j + 4 <= cnt2; j += 4) {
        int e0 = __shfl(myE, j, 64), e1 = __shfl(myE, j + 1, 64);
        int e2 = __shfl(myE, j + 2, 64), e3 = __shfl(myE, j + 3, 64);
        int s0 = __shfl(myS, j, 64), s1 = __shfl(myS, j + 1, 64);
        int s2 = __shfl(myS, j + 2, 64), s3 = __shfl(myS, j + 3, 64);
        unsigned u0 = *(const unsigned*)&P1b[(size_t)s0 * DF + 2 * lane];
        unsigned u1 = *(const unsigned*)&P1b[(size_t)s1 * DF + 2 * lane];
        unsigned u2 = *(const unsigned*)&P1b[(size_t)s2 * DF + 2 * lane];
        unsigned u3 = *(const unsigned*)&P1b[(size_t)s3 * DF + 2 * lane];
        float v0 = fmaxf(base0 + bflo(u0), 0.f) * w20 + fmaxf(base1 + bfhi(u0), 0.f) * w21;
        float v1 = fmaxf(base0 + bflo(u1), 0.f) * w20 + fmaxf(base1 + bfhi(u1), 0.f) * w21;
        float v2 = fmaxf(base0 + bflo(u2), 0.f) * w20 + fmaxf(base1 + bfhi(u2), 0.f) * w21;
        float v3 = fmaxf(base0 + bflo(u3), 0.f) * w20 + fmaxf(base1 + bfhi(u3), 0.f) * w21;
#pragma unroll
        for (int mk = 1; mk < 64; mk <<= 1) {
          v0 += __shfl_xor(v0, mk, 64);
          v1 += __shfl_xor(v1, mk, 64);
          v2 += __shfl_xor(v2, mk, 64);
          v3 += __shfl_xor(v3, mk, 64);
        }
        if (lane == 0) {
          out[e0] = sigm(v0 + w2b);
          out[e1] = sigm(v1 + w2b);
          out[e2] = sigm(v2 + w2b);
          out[e3] = sigm(v3 + w2b);
        }
      }
      for (; j < cnt2; ++j) {
        int e = __shfl(myE, j, 64);
        int s = __shfl(myS, j, 64);
        unsigned p1 = *(const unsigned*)&P1b[(size_t)s * DF + 2 * lane];
        float v = fmaxf(base0 + bflo(p1), 0.f) * w20 + fmaxf(base1 + bfhi(p1), 0.f) * w21;
#pragma unroll
        for (int mk = 1; mk < 64; mk <<= 1) v += __shfl_xor(v, mk, 64);
        if (lane == 0) out[e] = sigm(v + w2b);
      }
    }
  }
}

extern "C" void kernel_launch(void* const* d_in, const int* in_sizes, int n_in,
                              void* d_out, int out_size, void* d_ws, size_t ws_size,
                              hipStream_t stream) {
  const float* h_in = (const float*)d_in[0];
  const float* e_in = (const float*)d_in[1];
  const int* src = (const int*)d_in[2];
  const int* dst = (const int*)d_in[3];
  const int* node_graph = (const int*)d_in[4];
  const float* emb_n_w = (const float*)d_in[6];
  const float* emb_n_b = (const float*)d_in[7];
  const float* emb_e_w = (const float*)d_in[8];
  const float* emb_e_b = (const float*)d_in[9];
  const float* Us = (const float*)d_in[10];
  const float* Vs = (const float*)d_in[11];
  const float* As = (const float*)d_in[12];
  const float* Bs = (const float*)d_in[13];
  const float* Cs = (const float*)d_in[14];
  const float* gat_src_w = (const float*)d_in[15];
  const float* gat_src_b = (const float*)d_in[16];
  const float* gat_dst_w = (const float*)d_in[17];
  const float* gat_dst_b = (const float*)d_in[18];
  const float* gat_attn = (const float*)d_in[19];
  const float* gat_bias = (const float*)d_in[20];
  const float* O_w = (const float*)d_in[21];
  const float* O_b = (const float*)d_in[22];
  const float* W1_w = (const float*)d_in[23];
  const float* W1_b = (const float*)d_in[24];
  const float* W2_w = (const float*)d_in[25];
  const float* W2_b = (const float*)d_in[26];
  float* out = (float*)d_out;

  const int N = in_sizes[0] / 64;   // 30000
  const int E = in_sizes[1] / 16;   // 360000
  const int Eg = E / NGRAPH;        // 45000
  const int Ngr = N / NGRAPH;       // 3750

  auto rnd = [](size_t b) { return (b + 255) & ~(size_t)255; };
  const size_t sz_e0 = rnd((size_t)E * DF * 2);
  const size_t sz_node = rnd((size_t)N * DF * 4);
  const size_t sz_nodeb = rnd((size_t)N * DF * 2);
  const size_t sz_score = rnd((size_t)E * 8 * 4);
  const size_t sz_wfrag = rnd(20 * 2048 * 8 * 2);
  const size_t sz_rp = rnd((size_t)(N + 1) * 4);
  const size_t sz_eid = rnd((size_t)E * 4);
  const size_t sz_misc = rnd(4096 * 4);
  const size_t needed_min = sz_e0 + 3 * sz_node + 4 * sz_nodeb + sz_score + sz_wfrag +
                            3 * sz_rp + sz_eid + sz_misc;
  const size_t needed_full = needed_min + sz_e0;  // + xe
  if (ws_size < needed_min) {
    k_fill_u32<<<256, 256, 0, stream>>>((unsigned*)out, 0xBF800000u, (long long)out_size);
    return;
  }
  const bool have_xe = (ws_size >= needed_full);

  char* wp = (char*)d_ws;
  auto alloc = [&](size_t bytes) { void* p = wp; wp += bytes; return p; };
  unsigned short* e0u = (unsigned short*)alloc(sz_e0);
  float* h0 = (float*)alloc(sz_node);
  float* hU = (float*)alloc(sz_node);
  float* rst = (float*)alloc(sz_node);
  unsigned short* hVb = (unsigned short*)alloc(sz_nodeb);
  unsigned short* hBb = (unsigned short*)alloc(sz_nodeb);
  unsigned short* hCb = (unsigned short*)alloc(sz_nodeb);
  unsigned short* h2b = (unsigned short*)alloc(sz_nodeb);
  float* score = (float*)alloc(sz_score);
  short* wfrag = (short*)alloc(sz_wfrag);
  unsigned* rowptr = (unsigned*)alloc(sz_rp);
  unsigned* cursor = (unsigned*)alloc(sz_rp);
  unsigned* deg = (unsigned*)alloc(sz_rp);
  int* eidb = (int*)alloc(sz_eid);
  float* misc = (float*)alloc(sz_misc);
  unsigned short* xe = have_xe ? (unsigned short*)alloc(sz_e0) : nullptr;
  float* stat = misc;                                     // [0,1024)
  float* bias2 = misc + 1024;                             // [1024,1152)
  float* moy = misc + 1152;                               // [1152,2176)
  float* cnt = misc + 2176;                               // [2176,2184)
  float* P0 = misc + 2304;                                // [2304,3328)
  // P1b/P2b alias e0u (dead after last layer apply)
  unsigned short* P1b = e0u;
  unsigned short* P2b = e0u + (size_t)N * DF;

  auto WF = [&](int idx) { return wfrag + (size_t)idx * 2048 * 8; };

  // CSR build (dst lists; reused by layers + GAT + head)
  k_fill_u32<<<64, 256, 0, stream>>>(deg, 0u, N);
  k_deg<<<512, 256, 0, stream>>>(dst, deg, E);
  k_scan<<<1, 1024, 0, stream>>>(deg, rowptr, cursor, N);
  k_scatter<<<512, 256, 0, stream>>>(dst, cursor, eidb, E);

  k_wconv<<<20, 512, 0, stream>>>(Us, Vs, As, Bs, Cs, gat_src_w, gat_dst_w, O_w,
                                  W1_w, wfrag);

  const int gN = (N + 127) / 128;
  k_node_embed<<<2048, 128, 0, stream>>>(h_in, emb_n_w, emb_n_b, h0, N);
  k_edge_embed<<<4096, 128, 0, stream>>>(e_in, emb_e_w, emb_e_b, e0u, E);

  for (int l = 0; l < 3; ++l) {
    k_gemm4_mfma<<<gN, 512, 0, stream>>>(h0, WF(3 + l), WF(l), WF(9 + l), WF(12 + l),
                                         hVb, hU, hBb, hCb, N);
    k_fill_u32<<<4, 256, 0, stream>>>((unsigned*)stat, 0u, 1024);
    k_node_agg<<<2048, 256, 0, stream>>>(hU, hVb, e0u, src, rowptr, eidb, stat, Ngr);
    if (have_xe) {
      k_edge_mfma<2><<<256, 512, 0, stream>>>(e0u, WF(6 + l), hBb, hCb, src, dst,
                                              stat, xe, Eg);
      k_bn_finalize<<<1, 256, 0, stream>>>(stat, (float)N, (float)E);
      k_node_update<<<2048, 256, 0, stream>>>(h0, hU, stat, (long long)N * DF);
      k_edge_apply<<<2048, 256, 0, stream>>>(e0u, xe, stat, (long long)E * DF / 8);
    } else {
      k_edge_mfma<0><<<256, 512, 0, stream>>>(e0u, WF(6 + l), hBb, hCb, src, dst,
                                              stat, nullptr, Eg);
      k_bn_finalize<<<1, 256, 0, stream>>>(stat, (float)N, (float)E);
      k_node_update<<<2048, 256, 0, stream>>>(h0, hU, stat, (long long)N * DF);
      k_edge_mfma<1><<<256, 512, 0, stream>>>(e0u, WF(6 + l), hBb, hCb, src, dst,
                                              stat, nullptr, Eg);
    }
  }

  // GATv2: fs -> hVb, fd -> hBb
  k_gemm_mfma<1><<<gN, 512, 0, stream>>>(h0, WF(15), gat_src_b, hVb, N);
  k_gemm_mfma<1><<<gN, 512, 0, stream>>>(h0, WF(16), gat_dst_b, hBb, N);
  k_gat_score<<<512, 256, 0, stream>>>(hVb, hBb, src, dst, gat_attn, score, Eg);
  k_gat_node<<<2048, 256, 0, stream>>>(score, hVb, src, rowptr, eidb, rst, Ngr);
  k_bias2<<<1, 128, 0, stream>>>(gat_bias, O_w, O_b, bias2);
  k_gemm_mfma<1><<<gN, 512, 0, stream>>>(rst, WF(17), bias2, h2b, N);  // h2

  // readout + decomposed head
  k_fill_u32<<<2, 256, 0, stream>>>((unsigned*)moy, 0u, 1032);
  k_moy<<<128, 128, 0, stream>>>(h2b, node_graph, moy, cnt, N);
  k_p0<<<8, 128, 0, stream>>>(W1_w, W1_b, moy, cnt, P0);
  k_gemmb_mfma<<<gN, 512, 0, stream>>>(h2b, WF(18), P1b, N);
  k_gemmb_mfma<<<gN, 512, 0, stream>>>(h2b, WF(19), P2b, N);
  k_head<<<2048, 256, 0, stream>>>(P1b, P2b, P0, src, rowptr, eidb, W2_w, W2_b,
                                   out, Ngr);
}

// Round 11
// 1477.190 us; speedup vs baseline: 1.7383x; 1.0004x over previous
//
#include <hip/hip_runtime.h>

#define DF 128
#define NGRAPH 8

typedef __attribute__((ext_vector_type(8))) short bf16x8;
typedef __attribute__((ext_vector_type(4))) float f32x4;

__device__ __forceinline__ float sigm(float x) { return 1.f / (1.f + __expf(-x)); }
__device__ __forceinline__ unsigned short f2bf(float f) {  // RNE f32->bf16
  unsigned u = __float_as_uint(f);
  u += 0x7FFFu + ((u >> 16) & 1u);
  return (unsigned short)(u >> 16);
}
__device__ __forceinline__ float bf2f(unsigned short u) {
  return __uint_as_float(((unsigned)u) << 16);
}
__device__ __forceinline__ float bflo(unsigned u) { return __uint_as_float(u << 16); }
__device__ __forceinline__ float bfhi(unsigned u) { return __uint_as_float(u & 0xffff0000u); }

// load 8 consecutive f32 (32B-aligned) -> bf16x8
__device__ __forceinline__ bf16x8 cvt8(const float* __restrict__ p) {
  float4 a = *(const float4*)p;
  float4 b = *(const float4*)(p + 4);
  bf16x8 r;
  r[0] = (short)f2bf(a.x); r[1] = (short)f2bf(a.y);
  r[2] = (short)f2bf(a.z); r[3] = (short)f2bf(a.w);
  r[4] = (short)f2bf(b.x); r[5] = (short)f2bf(b.y);
  r[6] = (short)f2bf(b.z); r[7] = (short)f2bf(b.w);
  return r;
}

__device__ __forceinline__ void agg_max(unsigned hv, unsigned ev, float& m0, float& m1) {
  m0 = fmaxf(m0, bflo(hv) * sigm(bflo(ev)));
  m1 = fmaxf(m1, bfhi(hv) * sigm(bfhi(ev)));
}

// ---------------- generic fill ----------------
__global__ void k_fill_u32(unsigned* __restrict__ p, unsigned v, long long n) {
  long long i = (long long)blockIdx.x * blockDim.x + threadIdx.x;
  long long st = (long long)gridDim.x * blockDim.x;
  for (; i < n; i += st) p[i] = v;
}

// ---------------- CSR build (dst-sorted edge lists) ----------------
__global__ void k_deg(const int* __restrict__ dst, unsigned* __restrict__ deg, int E) {
  int i = blockIdx.x * blockDim.x + threadIdx.x;
  int st = gridDim.x * blockDim.x;
  for (; i < E; i += st) atomicAdd(&deg[dst[i]], 1u);
}

__global__ __launch_bounds__(1024) void k_scan(
    const unsigned* __restrict__ deg, unsigned* __restrict__ rowptr,
    unsigned* __restrict__ cursor, int N) {
  __shared__ unsigned part[1024];
  int t = threadIdx.x;
  int per = (N + 1023) >> 10;
  int s0 = t * per, s1 = min(N, s0 + per);
  unsigned s = 0;
  for (int i = s0; i < s1; ++i) s += deg[i];
  part[t] = s;
  __syncthreads();
  for (int off = 1; off < 1024; off <<= 1) {
    unsigned v = (t >= off) ? part[t - off] : 0u;
    __syncthreads();
    part[t] += v;
    __syncthreads();
  }
  unsigned base = (t == 0) ? 0u : part[t - 1];
  for (int i = s0; i < s1; ++i) {
    rowptr[i] = base;
    cursor[i] = base;
    base += deg[i];
  }
  if (t == 1023) rowptr[N] = part[1023];
}

__global__ void k_scatter(const int* __restrict__ dst, unsigned* __restrict__ cursor,
                          int* __restrict__ eidb, int E) {
  int i = blockIdx.x * blockDim.x + threadIdx.x;
  int st = gridDim.x * blockDim.x;
  for (; i < E; i += st) {
    unsigned p = atomicAdd(&cursor[dst[i]], 1u);
    eidb[p] = i;
  }
}

// ---------------- weight pre-conversion to MFMA fragment order ----------------
// 0-2 U, 3-5 V, 6-8 A, 9-11 B, 12-14 C, 15 gsw, 16 gdw, 17 Ow, 18 W1[:,128:256], 19 W1[:,256:384]
__global__ __launch_bounds__(512) void k_wconv(
    const float* __restrict__ Us, const float* __restrict__ Vs,
    const float* __restrict__ As, const float* __restrict__ Bs,
    const float* __restrict__ Cs, const float* __restrict__ gsw,
    const float* __restrict__ gdw, const float* __restrict__ Ow,
    const float* __restrict__ W1, short* __restrict__ out) {
  int b = blockIdx.x;
  const float* W;
  int ldw = DF;
  if (b < 3) W = Us + b * 16384;
  else if (b < 6) W = Vs + (b - 3) * 16384;
  else if (b < 9) W = As + (b - 6) * 16384;
  else if (b < 12) W = Bs + (b - 9) * 16384;
  else if (b < 15) W = Cs + (b - 12) * 16384;
  else if (b == 15) W = gsw;
  else if (b == 16) W = gdw;
  else if (b == 17) W = Ow;
  else if (b == 18) { W = W1 + 128; ldw = 384; }
  else { W = W1 + 256; ldw = 384; }
  short* o = out + (size_t)b * 2048 * 8;
  for (int s = threadIdx.x; s < 2048; s += 512) {
    int ct = s >> 8, ks = (s >> 6) & 3, l = s & 63;
    int row = ct * 16 + (l & 15), k0 = ks * 32 + (l >> 4) * 8;
    *(bf16x8*)&o[s * 8] = cvt8(W + (size_t)row * ldw + k0);
  }
}

// ---------------- embeddings ----------------
__global__ __launch_bounds__(128) void k_node_embed(
    const float* __restrict__ hin, const float* __restrict__ w,
    const float* __restrict__ b, float* __restrict__ h0, int rows) {
  __shared__ float Wt[64 * DF];
  __shared__ float ar[4][64];
  int tid = threadIdx.x;
  for (int i = tid; i < 64 * DF; i += 128) Wt[(i & 63) * DF + (i >> 6)] = w[i];
  float bb = b[tid];
  __syncthreads();
  for (int r0 = blockIdx.x * 4; r0 < rows; r0 += gridDim.x * 4) {
    for (int i = tid; i < 256; i += 128) ar[i >> 6][i & 63] = hin[(size_t)r0 * 64 + i];
    __syncthreads();
    float a0 = bb, a1 = bb, a2 = bb, a3 = bb;
#pragma unroll 8
    for (int k = 0; k < 64; ++k) {
      float wv = Wt[k * DF + tid];
      a0 = fmaf(ar[0][k], wv, a0); a1 = fmaf(ar[1][k], wv, a1);
      a2 = fmaf(ar[2][k], wv, a2); a3 = fmaf(ar[3][k], wv, a3);
    }
    h0[(size_t)r0 * DF + tid] = a0;
    h0[(size_t)(r0 + 1) * DF + tid] = a1;
    h0[(size_t)(r0 + 2) * DF + tid] = a2;
    h0[(size_t)(r0 + 3) * DF + tid] = a3;
    __syncthreads();
  }
}

__global__ __launch_bounds__(128) void k_edge_embed(
    const float* __restrict__ ein, const float* __restrict__ w,
    const float* __restrict__ b, unsigned short* __restrict__ e0u, int rows) {
  __shared__ float Wt[16 * DF];
  __shared__ float ar[4][16];
  int tid = threadIdx.x;
  for (int i = tid; i < 16 * DF; i += 128) Wt[(i & 15) * DF + (i >> 4)] = w[i];
  float bb = b[tid];
  __syncthreads();
  for (int r0 = blockIdx.x * 4; r0 < rows; r0 += gridDim.x * 4) {
    if (tid < 64) ar[tid >> 4][tid & 15] = ein[(size_t)r0 * 16 + tid];
    __syncthreads();
    float a0 = bb, a1 = bb, a2 = bb, a3 = bb;
#pragma unroll
    for (int k = 0; k < 16; ++k) {
      float wv = Wt[k * DF + tid];
      a0 = fmaf(ar[0][k], wv, a0); a1 = fmaf(ar[1][k], wv, a1);
      a2 = fmaf(ar[2][k], wv, a2); a3 = fmaf(ar[3][k], wv, a3);
    }
    e0u[(size_t)r0 * DF + tid] = f2bf(a0);
    e0u[(size_t)(r0 + 1) * DF + tid] = f2bf(a1);
    e0u[(size_t)(r0 + 2) * DF + tid] = f2bf(a2);
    e0u[(size_t)(r0 + 3) * DF + tid] = f2bf(a3);
    __syncthreads();
  }
}

// ---------------- MFMA [rows,128] @ W^T (+bias), frag weights, f32 input ----------------
template <int OUTBF>
__global__ __launch_bounds__(512) void k_gemm_mfma(
    const float* __restrict__ A, const short* __restrict__ Wf,
    const float* __restrict__ bias, void* __restrict__ outv, int rows) {
  __shared__ short Wb[2048 * 8];  // 32 KB
  int tid = threadIdx.x;
  for (int s = tid; s < 2048; s += 512)
    *(bf16x8*)&Wb[s * 8] = *(const bf16x8*)&Wf[(size_t)s * 8];
  __syncthreads();
  float* outf = (float*)outv;
  unsigned short* outb = (unsigned short*)outv;
  int wid = tid >> 6, lane = tid & 63, q = lane >> 4, m = lane & 15;
  int ntiles = (rows + 127) >> 7;
  for (int t = blockIdx.x; t < ntiles; t += gridDim.x) {
    int r0 = t * 128 + wid * 16;
    int rr = r0 + m;
    if (rr >= rows) rr = rows - 1;
    const float* ap = A + (size_t)rr * DF + q * 8;
    bf16x8 a[4];
#pragma unroll
    for (int ks = 0; ks < 4; ++ks) a[ks] = cvt8(ap + 32 * ks);
#pragma unroll
    for (int ct = 0; ct < 8; ++ct) {
      f32x4 acc = {0.f, 0.f, 0.f, 0.f};
#pragma unroll
      for (int ks = 0; ks < 4; ++ks) {
        bf16x8 b = *(const bf16x8*)&Wb[((ct * 4 + ks) * 64 + lane) * 8];
        acc = __builtin_amdgcn_mfma_f32_16x16x32_bf16(a[ks], b, acc, 0, 0, 0);
      }
      int col = ct * 16 + m;
      float bb = bias ? bias[col] : 0.f;
#pragma unroll
      for (int j = 0; j < 4; ++j) {
        int row = r0 + q * 4 + j;
        if (row < rows) {
          if (OUTBF) outb[(size_t)row * DF + col] = f2bf(acc[j] + bb);
          else outf[(size_t)row * DF + col] = acc[j] + bb;
        }
      }
    }
  }
}

// same, bf16 input
__global__ __launch_bounds__(512) void k_gemmb_mfma(
    const unsigned short* __restrict__ A, const short* __restrict__ Wf,
    unsigned short* __restrict__ outb, int rows) {
  __shared__ short Wb[2048 * 8];
  int tid = threadIdx.x;
  for (int s = tid; s < 2048; s += 512)
    *(bf16x8*)&Wb[s * 8] = *(const bf16x8*)&Wf[(size_t)s * 8];
  __syncthreads();
  int wid = tid >> 6, lane = tid & 63, q = lane >> 4, m = lane & 15;
  int ntiles = (rows + 127) >> 7;
  for (int t = blockIdx.x; t < ntiles; t += gridDim.x) {
    int r0 = t * 128 + wid * 16;
    int rr = r0 + m;
    if (rr >= rows) rr = rows - 1;
    const unsigned short* ap = A + (size_t)rr * DF + q * 8;
    bf16x8 a[4];
#pragma unroll
    for (int ks = 0; ks < 4; ++ks) a[ks] = *(const bf16x8*)(ap + 32 * ks);
#pragma unroll
    for (int ct = 0; ct < 8; ++ct) {
      f32x4 acc = {0.f, 0.f, 0.f, 0.f};
#pragma unroll
      for (int ks = 0; ks < 4; ++ks) {
        bf16x8 b = *(const bf16x8*)&Wb[((ct * 4 + ks) * 64 + lane) * 8];
        acc = __builtin_amdgcn_mfma_f32_16x16x32_bf16(a[ks], b, acc, 0, 0, 0);
      }
      int col = ct * 16 + m;
#pragma unroll
      for (int j = 0; j < 4; ++j) {
        int row = r0 + q * 4 + j;
        if (row < rows) outb[(size_t)row * DF + col] = f2bf(acc[j]);
      }
    }
  }
}

// ---------------- fused 4-output node GEMM (V,U,B,C) ----------------
__global__ __launch_bounds__(512) void k_gemm4_mfma(
    const float* __restrict__ h0, const short* __restrict__ Vf,
    const short* __restrict__ Uf, const short* __restrict__ Bf,
    const short* __restrict__ Cf, unsigned short* __restrict__ hVb,
    float* __restrict__ hU, unsigned short* __restrict__ hBb,
    unsigned short* __restrict__ hCb, int rows) {
  __shared__ short Wl[4 * 2048 * 8];  // 128 KB
  int tid = threadIdx.x;
  for (int s = tid; s < 2048; s += 512) {
    *(bf16x8*)&Wl[(size_t)s * 8] = *(const bf16x8*)&Vf[(size_t)s * 8];
    *(bf16x8*)&Wl[(size_t)(2048 + s) * 8] = *(const bf16x8*)&Uf[(size_t)s * 8];
    *(bf16x8*)&Wl[(size_t)(4096 + s) * 8] = *(const bf16x8*)&Bf[(size_t)s * 8];
    *(bf16x8*)&Wl[(size_t)(6144 + s) * 8] = *(const bf16x8*)&Cf[(size_t)s * 8];
  }
  __syncthreads();
  int wid = tid >> 6, lane = tid & 63, q = lane >> 4, m = lane & 15;
  int ntiles = (rows + 127) >> 7;
  for (int t = blockIdx.x; t < ntiles; t += gridDim.x) {
    int r0 = t * 128 + wid * 16;
    int rr = r0 + m;
    if (rr >= rows) rr = rows - 1;
    const float* ap = h0 + (size_t)rr * DF + q * 8;
    bf16x8 a[4];
#pragma unroll
    for (int ks = 0; ks < 4; ++ks) a[ks] = cvt8(ap + 32 * ks);
#pragma unroll
    for (int w = 0; w < 4; ++w) {
#pragma unroll
      for (int ct = 0; ct < 8; ++ct) {
        f32x4 acc = {0.f, 0.f, 0.f, 0.f};
#pragma unroll
        for (int ks = 0; ks < 4; ++ks) {
          bf16x8 b = *(const bf16x8*)&Wl[((w * 2048) + (ct * 4 + ks) * 64 + lane) * 8];
          acc = __builtin_amdgcn_mfma_f32_16x16x32_bf16(a[ks], b, acc, 0, 0, 0);
        }
        int col = ct * 16 + m;
#pragma unroll
        for (int j = 0; j < 4; ++j) {
          int row = r0 + q * 4 + j;
          if (row < rows) {
            if (w == 1) hU[(size_t)row * DF + col] = acc[j];
            else {
              unsigned short v = f2bf(acc[j]);
              unsigned short* o = (w == 0) ? hVb : ((w == 2) ? hBb : hCb);
              o[(size_t)row * DF + col] = v;
            }
          }
        }
      }
    }
  }
}

// ---------------- barrier-free edge x (swapped MFMA operands) ----------------
// lane owns ONE edge (col = lane&15), features ct*16 + q*4 + j.
// x = e@As^T + hB[dst] + hC[src] -> xe (bf16). No stats, no barriers in loop.
__global__ __launch_bounds__(512) void k_edge_x(
    const unsigned short* __restrict__ e0u, const short* __restrict__ Af,
    const unsigned short* __restrict__ hBb, const unsigned short* __restrict__ hCb,
    const int* __restrict__ src, const int* __restrict__ dst,
    unsigned short* __restrict__ xe, int Eg) {
  __shared__ short Wb[2048 * 8];  // 32 KB only
  int tid = threadIdx.x;
  for (int s = tid; s < 2048; s += 512)
    *(bf16x8*)&Wb[s * 8] = *(const bf16x8*)&Af[(size_t)s * 8];
  __syncthreads();
  int wid = tid >> 6, lane = tid & 63, q = lane >> 4, m = lane & 15;
  int g = blockIdx.x & 7, sub = blockIdx.x >> 3, nsub = gridDim.x >> 3;
  int gbase = g * Eg, gend = gbase + Eg;
  int tpg = (Eg + 127) >> 7;
  for (int t = sub; t < tpg; t += nsub) {
    int r0 = gbase + t * 128 + wid * 16;
    int edge = r0 + m;
    bool ok = edge < gend;
    int ec = ok ? edge : gend - 1;
    const unsigned short* ep = e0u + (size_t)ec * DF + q * 8;
    bf16x8 b[4];
#pragma unroll
    for (int ks = 0; ks < 4; ++ks) b[ks] = *(const bf16x8*)(ep + 32 * ks);
    f32x4 c0 = {0.f, 0.f, 0.f, 0.f}, c1 = c0, c2 = c0, c3 = c0;
    f32x4 c4 = c0, c5 = c0, c6 = c0, c7 = c0;
#pragma unroll
    for (int ks = 0; ks < 4; ++ks) {
      bf16x8 bv = b[ks];
      c0 = __builtin_amdgcn_mfma_f32_16x16x32_bf16(*(const bf16x8*)&Wb[((0 * 4 + ks) * 64 + lane) * 8], bv, c0, 0, 0, 0);
      c1 = __builtin_amdgcn_mfma_f32_16x16x32_bf16(*(const bf16x8*)&Wb[((1 * 4 + ks) * 64 + lane) * 8], bv, c1, 0, 0, 0);
      c2 = __builtin_amdgcn_mfma_f32_16x16x32_bf16(*(const bf16x8*)&Wb[((2 * 4 + ks) * 64 + lane) * 8], bv, c2, 0, 0, 0);
      c3 = __builtin_amdgcn_mfma_f32_16x16x32_bf16(*(const bf16x8*)&Wb[((3 * 4 + ks) * 64 + lane) * 8], bv, c3, 0, 0, 0);
      c4 = __builtin_amdgcn_mfma_f32_16x16x32_bf16(*(const bf16x8*)&Wb[((4 * 4 + ks) * 64 + lane) * 8], bv, c4, 0, 0, 0);
      c5 = __builtin_amdgcn_mfma_f32_16x16x32_bf16(*(const bf16x8*)&Wb[((5 * 4 + ks) * 64 + lane) * 8], bv, c5, 0, 0, 0);
      c6 = __builtin_amdgcn_mfma_f32_16x16x32_bf16(*(const bf16x8*)&Wb[((6 * 4 + ks) * 64 + lane) * 8], bv, c6, 0, 0, 0);
      c7 = __builtin_amdgcn_mfma_f32_16x16x32_bf16(*(const bf16x8*)&Wb[((7 * 4 + ks) * 64 + lane) * 8], bv, c7, 0, 0, 0);
    }
    if (ok) {
      int sidx = src[ec], didx = dst[ec];
      const unsigned short* pb = hBb + (size_t)didx * DF + q * 4;
      const unsigned short* pc = hCb + (size_t)sidx * DF + q * 4;
      unsigned short* px = xe + (size_t)ec * DF + q * 4;
#pragma unroll
      for (int ct = 0; ct < 8; ++ct) {
        f32x4 cc = (ct == 0) ? c0 : (ct == 1) ? c1 : (ct == 2) ? c2 : (ct == 3) ? c3
                   : (ct == 4) ? c4 : (ct == 5) ? c5 : (ct == 6) ? c6 : c7;
        ushort4 hb = *(const ushort4*)(pb + ct * 16);
        ushort4 hc = *(const ushort4*)(pc + ct * 16);
        ushort4 xv;
        xv.x = f2bf(cc[0] + bf2f(hb.x) + bf2f(hc.x));
        xv.y = f2bf(cc[1] + bf2f(hb.y) + bf2f(hc.y));
        xv.z = f2bf(cc[2] + bf2f(hb.z) + bf2f(hc.z));
        xv.w = f2bf(cc[3] + bf2f(hb.w) + bf2f(hc.w));
        *(ushort4*)(px + ct * 16) = xv;
      }
    }
  }
}

// ---------------- streaming column stats over xe ----------------
__global__ __launch_bounds__(256) void k_xstats(
    const unsigned short* __restrict__ xe, float* __restrict__ stat, long long n8) {
  __shared__ float ls[256];
  int tid = threadIdx.x;
  ls[tid] = 0.f;
  __syncthreads();
  float ps[8] = {0.f, 0.f, 0.f, 0.f, 0.f, 0.f, 0.f, 0.f};
  float pq[8] = {0.f, 0.f, 0.f, 0.f, 0.f, 0.f, 0.f, 0.f};
  long long i = (long long)blockIdx.x * 256 + tid;
  long long st = (long long)gridDim.x * 256;
  for (; i < n8; i += st) {
    bf16x8 v = *(const bf16x8*)(xe + i * 8);
#pragma unroll
    for (int k = 0; k < 8; ++k) {
      float f = bf2f((unsigned short)v[k]);
      ps[k] += f;
      pq[k] += f * f;
    }
  }
  int c0 = (tid & 15) * 8;
#pragma unroll
  for (int k = 0; k < 8; ++k) {
    atomicAdd(&ls[c0 + k], ps[k]);
    atomicAdd(&ls[128 + c0 + k], pq[k]);
  }
  __syncthreads();
  if (tid < 128) {
    atomicAdd(&stat[512 + tid], ls[tid]);
    atomicAdd(&stat[640 + tid], ls[128 + tid]);
  }
}

// ---------------- MFMA edge pass (fallback, small-ws): stats / apply-recompute ----------------
template <int MODE>
__global__ __launch_bounds__(512) void k_edge_mfma(
    unsigned short* __restrict__ e0u, const short* __restrict__ Af,
    const unsigned short* __restrict__ hBb, const unsigned short* __restrict__ hCb,
    const int* __restrict__ src, const int* __restrict__ dst,
    float* __restrict__ stat, int Eg) {
  __shared__ short Wb[2048 * 8];
  __shared__ float xt[8][16 * 132];
  int tid = threadIdx.x;
  for (int s = tid; s < 2048; s += 512)
    *(bf16x8*)&Wb[s * 8] = *(const bf16x8*)&Af[(size_t)s * 8];
  int wid = tid >> 6, lane = tid & 63, q = lane >> 4, m = lane & 15;
  int g = blockIdx.x & 7, sub = blockIdx.x >> 3, nsub = gridDim.x >> 3;
  int gbase = g * Eg, gend = gbase + Eg;
  int tpg = (Eg + 127) >> 7;
  float* xw = xt[wid];
  float ps0 = 0.f, ps1 = 0.f, pq0 = 0.f, pq1 = 0.f;
  __syncthreads();
  for (int t = sub; t < tpg; t += nsub) {
    int r0 = gbase + t * 128 + wid * 16;
    int edge = r0 + m;
    bool ok = edge < gend;
    int ec = ok ? edge : gend - 1;
    const unsigned short* ep = e0u + (size_t)ec * DF + q * 8;
    bf16x8 a[4];
#pragma unroll
    for (int ks = 0; ks < 4; ++ks) a[ks] = *(const bf16x8*)(ep + 32 * ks);
#pragma unroll
    for (int ct = 0; ct < 8; ++ct) {
      f32x4 acc = {0.f, 0.f, 0.f, 0.f};
#pragma unroll
      for (int ks = 0; ks < 4; ++ks) {
        bf16x8 b = *(const bf16x8*)&Wb[((ct * 4 + ks) * 64 + lane) * 8];
        acc = __builtin_amdgcn_mfma_f32_16x16x32_bf16(a[ks], b, acc, 0, 0, 0);
      }
#pragma unroll
      for (int j = 0; j < 4; ++j) xw[(q * 4 + j) * 132 + ct * 16 + m] = acc[j];
    }
    __syncthreads();
    int sidx = src[ec], didx = dst[ec];
    const unsigned short* pb = hBb + (size_t)didx * DF;
    const unsigned short* pc = hCb + (size_t)sidx * DF;
#pragma unroll
    for (int ks = 0; ks < 4; ++ks) {
      int c0 = q * 8 + 32 * ks;
      float* xp = &xw[m * 132 + c0];
      bf16x8 gb = *(const bf16x8*)(pb + c0);
      bf16x8 gc = *(const bf16x8*)(pc + c0);
      float x[8];
#pragma unroll
      for (int i = 0; i < 8; ++i)
        x[i] = xp[i] + bf2f((unsigned short)gb[i]) + bf2f((unsigned short)gc[i]);
      if (MODE == 1) {
        bf16x8 nv;
#pragma unroll
        for (int i = 0; i < 8; ++i) {
          float mm = stat[768 + c0 + i], iv = stat[896 + c0 + i];
          nv[i] = (short)f2bf(bf2f((unsigned short)a[ks][i]) + fmaxf((x[i] - mm) * iv, 0.f));
        }
        if (ok) *(bf16x8*)(e0u + (size_t)ec * DF + c0) = nv;
      } else {
#pragma unroll
        for (int i = 0; i < 8; ++i) xp[i] = ok ? x[i] : 0.f;
      }
    }
    if (MODE != 1) {
      __syncthreads();
#pragma unroll 4
      for (int r = 0; r < 16; ++r) {
        float2 v = *(float2*)&xw[r * 132 + 2 * lane];
        ps0 += v.x; ps1 += v.y;
        pq0 += v.x * v.x; pq1 += v.y * v.y;
      }
    }
    __syncthreads();
  }
  if (MODE != 1) {
    atomicAdd(&stat[512 + 2 * lane], ps0);
    atomicAdd(&stat[512 + 2 * lane + 1], ps1);
    atomicAdd(&stat[640 + 2 * lane], pq0);
    atomicAdd(&stat[640 + 2 * lane + 1], pq1);
  }
}

// streaming apply: e += relu((x - m)*iv), all bf16
__global__ __launch_bounds__(256) void k_edge_apply(
    unsigned short* __restrict__ e0u, const unsigned short* __restrict__ xe,
    const float* __restrict__ stat, long long n8) {
  long long i = (long long)blockIdx.x * blockDim.x + threadIdx.x;
  long long st = (long long)gridDim.x * blockDim.x;
  for (; i < n8; i += st) {
    int c0 = (int)(i & 15) * 8;
    bf16x8 ev = *(const bf16x8*)(e0u + i * 8);
    bf16x8 xv = *(const bf16x8*)(xe + i * 8);
    bf16x8 nv;
#pragma unroll
    for (int k = 0; k < 8; ++k) {
      float mm = stat[768 + c0 + k], iv = stat[896 + c0 + k];
      nv[k] = (short)f2bf(bf2f((unsigned short)ev[k]) +
                          fmaxf((bf2f((unsigned short)xv[k]) - mm) * iv, 0.f));
    }
    *(bf16x8*)(e0u + i * 8) = nv;
  }
}

// ---------------- node-major segment max + hU update + BN stats ----------------
__global__ __launch_bounds__(256) void k_node_agg(
    float* __restrict__ hU, const unsigned short* __restrict__ hVb,
    const unsigned short* __restrict__ e0u, const int* __restrict__ src,
    const unsigned* __restrict__ rowptr, const int* __restrict__ eidb,
    float* __restrict__ stat, int Ngr) {
  __shared__ float sr[4][256];
  int tid = threadIdx.x, wid = tid >> 6, lane = tid & 63;
  int g = blockIdx.x & 7, sub = blockIdx.x >> 3, nsub = gridDim.x >> 3;
  float ps0 = 0.f, ps1 = 0.f, pq0 = 0.f, pq1 = 0.f;
  for (int nn = sub * 4 + wid; nn < Ngr; nn += nsub * 4) {
    int n = g * Ngr + nn;
    unsigned r0 = rowptr[n], r1 = rowptr[n + 1];
    float m0 = -3.4e38f, m1 = -3.4e38f;
    for (unsigned rc = r0; rc < r1; rc += 64) {
      int batch = (int)min(64u, r1 - rc);
      int myE = eidb[rc + ((lane < batch) ? lane : 0)];
      int myS = src[myE];
      int j = 0;
      for (; j + 4 <= batch; j += 4) {
        int e0 = __shfl(myE, j, 64), e1 = __shfl(myE, j + 1, 64);
        int e2 = __shfl(myE, j + 2, 64), e3 = __shfl(myE, j + 3, 64);
        int s0 = __shfl(myS, j, 64), s1 = __shfl(myS, j + 1, 64);
        int s2 = __shfl(myS, j + 2, 64), s3 = __shfl(myS, j + 3, 64);
        unsigned h0v = *(const unsigned*)&hVb[(size_t)s0 * DF + 2 * lane];
        unsigned h1v = *(const unsigned*)&hVb[(size_t)s1 * DF + 2 * lane];
        unsigned h2v = *(const unsigned*)&hVb[(size_t)s2 * DF + 2 * lane];
        unsigned h3v = *(const unsigned*)&hVb[(size_t)s3 * DF + 2 * lane];
        unsigned v0 = *(const unsigned*)&e0u[(size_t)e0 * DF + 2 * lane];
        unsigned v1 = *(const unsigned*)&e0u[(size_t)e1 * DF + 2 * lane];
        unsigned v2 = *(const unsigned*)&e0u[(size_t)e2 * DF + 2 * lane];
        unsigned v3 = *(const unsigned*)&e0u[(size_t)e3 * DF + 2 * lane];
        agg_max(h0v, v0, m0, m1);
        agg_max(h1v, v1, m0, m1);
        agg_max(h2v, v2, m0, m1);
        agg_max(h3v, v3, m0, m1);
      }
      for (; j < batch; ++j) {
        int e = __shfl(myE, j, 64);
        int s = __shfl(myS, j, 64);
        unsigned hv = *(const unsigned*)&hVb[(size_t)s * DF + 2 * lane];
        unsigned ev = *(const unsigned*)&e0u[(size_t)e * DF + 2 * lane];
        agg_max(hv, ev, m0, m1);
      }
    }
    if (r1 == r0) { m0 = 0.f; m1 = 0.f; }
    size_t idx = (size_t)n * DF + 2 * lane;
    float2 hu = *(float2*)&hU[idx];
    float t0 = hu.x + m0, t1 = hu.y + m1;
    hu.x = t0; hu.y = t1;
    *(float2*)&hU[idx] = hu;
    ps0 += t0; ps1 += t1;
    pq0 += t0 * t0; pq1 += t1 * t1;
  }
  sr[0][tid] = ps0; sr[1][tid] = ps1; sr[2][tid] = pq0; sr[3][tid] = pq1;
  __syncthreads();
  if (tid < 64) {
    float a0 = 0.f, a1 = 0.f, b0 = 0.f, b1 = 0.f;
#pragma unroll
    for (int w = 0; w < 4; ++w) {
      a0 += sr[0][w * 64 + tid]; a1 += sr[1][w * 64 + tid];
      b0 += sr[2][w * 64 + tid]; b1 += sr[3][w * 64 + tid];
    }
    atomicAdd(&stat[2 * tid], a0);
    atomicAdd(&stat[2 * tid + 1], a1);
    atomicAdd(&stat[128 + 2 * tid], b0);
    atomicAdd(&stat[128 + 2 * tid + 1], b1);
  }
}

// finalize BN stats
__global__ void k_bn_finalize(float* __restrict__ stat, float nN, float nE) {
  int tid = threadIdx.x;
  if (tid < 128) {
    float mean = stat[tid] / nN;
    float var = stat[128 + tid] / nN - mean * mean;
    stat[256 + tid] = mean;
    stat[384 + tid] = rsqrtf(fmaxf(var, 0.f) + 1e-5f);
  } else {
    int d = tid - 128;
    float mean = stat[512 + d] / nE;
    float var = stat[640 + d] / nE - mean * mean;
    stat[768 + d] = mean;
    stat[896 + d] = rsqrtf(fmaxf(var, 0.f) + 1e-5f);
  }
}

__global__ __launch_bounds__(256) void k_node_update(
    float* __restrict__ h0, const float* __restrict__ hU,
    const float* __restrict__ stat, long long total) {
  long long i = (long long)blockIdx.x * blockDim.x + threadIdx.x;
  long long st = (long long)gridDim.x * blockDim.x;
  for (; i < total; i += st) {
    int d = (int)(i & 127);
    float t = (hU[i] - stat[256 + d]) * stat[384 + d];
    h0[i] += fmaxf(t, 0.f);
  }
}

// ---------------- GATv2 score (edge-major) ----------------
__global__ __launch_bounds__(256) void k_gat_score(
    const unsigned short* __restrict__ fsb, const unsigned short* __restrict__ fdb,
    const int* __restrict__ src, const int* __restrict__ dst,
    const float* __restrict__ attn, float* __restrict__ score, int Eg) {
  int g = blockIdx.x & 7, sub = blockIdx.x >> 3, nsub = gridDim.x >> 3;
  int gbase = g * Eg, gend = gbase + Eg;
  int tpg = (Eg + 127) >> 7;
  int tid = threadIdx.x;
  for (int t = sub; t < tpg; t += nsub) {
    int ebase = gbase + t * 128;
    for (int k = tid; k < 1024; k += 256) {
      int e = ebase + (k >> 3);
      if (e >= gend) break;
      int mh = k & 7;
      int s = src[e], dn = dst[e];
      const unsigned short* ps = fsb + (size_t)s * DF + mh * 16;
      const unsigned short* pd = fdb + (size_t)dn * DF + mh * 16;
      const float* pa = attn + mh * 16;
      bf16x8 s0 = *(const bf16x8*)ps;
      bf16x8 s1 = *(const bf16x8*)(ps + 8);
      bf16x8 d0 = *(const bf16x8*)pd;
      bf16x8 d1 = *(const bf16x8*)(pd + 8);
      float acc = 0.f;
#pragma unroll
      for (int kk = 0; kk < 8; ++kk) {
        float z = bf2f((unsigned short)s0[kk]) + bf2f((unsigned short)d0[kk]);
        z = (z > 0.f) ? z : 0.2f * z;
        acc = fmaf(z, pa[kk], acc);
        float z2 = bf2f((unsigned short)s1[kk]) + bf2f((unsigned short)d1[kk]);
        z2 = (z2 > 0.f) ? z2 : 0.2f * z2;
        acc = fmaf(z2, pa[kk + 8], acc);
      }
      score[(size_t)e * 8 + mh] = acc;
    }
  }
}

// ---------------- GATv2 node reduction (batched CSR, unrolled) ----------------
__global__ __launch_bounds__(256) void k_gat_node(
    const float* __restrict__ score, const unsigned short* __restrict__ fsb,
    const int* __restrict__ src, const unsigned* __restrict__ rowptr,
    const int* __restrict__ eidb, float* __restrict__ rst, int Ngr) {
  int tid = threadIdx.x, wid = tid >> 6, lane = tid & 63;
  int g = blockIdx.x & 7, sub = blockIdx.x >> 3, nsub = gridDim.x >> 3;
  int head = lane >> 3, slot = lane & 7;
  for (int nn = sub * 4 + wid; nn < Ngr; nn += nsub * 4) {
    int n = g * Ngr + nn;
    unsigned r0 = rowptr[n], r1 = rowptr[n + 1];
    float hm = -3.4e38f;
    for (unsigned rc = r0; rc < r1; rc += 64) {
      int batch = (int)min(64u, r1 - rc);
      int myE = eidb[rc + ((lane < batch) ? lane : 0)];
      for (int k = slot; k < batch; k += 8) {
        int e = __shfl(myE, k, 64);
        hm = fmaxf(hm, score[(size_t)e * 8 + head]);
      }
    }
#pragma unroll
    for (int mk = 1; mk < 8; mk <<= 1) hm = fmaxf(hm, __shfl_xor(hm, mk, 64));
    float dn = 0.f;
    for (unsigned rc = r0; rc < r1; rc += 64) {
      int batch = (int)min(64u, r1 - rc);
      int myE = eidb[rc + ((lane < batch) ? lane : 0)];
      for (int k = slot; k < batch; k += 8) {
        int e = __shfl(myE, k, 64);
        dn += __expf(score[(size_t)e * 8 + head] - hm);
      }
    }
#pragma unroll
    for (int mk = 1; mk < 8; mk <<= 1) dn += __shfl_xor(dn, mk, 64);
    float inv = (r1 > r0) ? 1.f / dn : 0.f;
    float a0 = 0.f, a1 = 0.f;
    for (unsigned rc = r0; rc < r1; rc += 64) {
      int batch = (int)min(64u, r1 - rc);
      int myE = eidb[rc + ((lane < batch) ? lane : 0)];
      int myS = src[myE];
      int j = 0;
      for (; j + 4 <= batch; j += 4) {
        int e0 = __shfl(myE, j, 64), e1 = __shfl(myE, j + 1, 64);
        int e2 = __shfl(myE, j + 2, 64), e3 = __shfl(myE, j + 3, 64);
        int s0 = __shfl(myS, j, 64), s1 = __shfl(myS, j + 1, 64);
        int s2 = __shfl(myS, j + 2, 64), s3 = __shfl(myS, j + 3, 64);
        float sc0 = score[(size_t)e0 * 8 + head];
        float sc1 = score[(size_t)e1 * 8 + head];
        float sc2 = score[(size_t)e2 * 8 + head];
        float sc3 = score[(size_t)e3 * 8 + head];
        unsigned f0 = *(const unsigned*)&fsb[(size_t)s0 * DF + 2 * lane];
        unsigned f1 = *(const unsigned*)&fsb[(size_t)s1 * DF + 2 * lane];
        unsigned f2 = *(const unsigned*)&fsb[(size_t)s2 * DF + 2 * lane];
        unsigned f3 = *(const unsigned*)&fsb[(size_t)s3 * DF + 2 * lane];
        float w0 = __expf(sc0 - hm) * inv, w1 = __expf(sc1 - hm) * inv;
        float w2 = __expf(sc2 - hm) * inv, w3 = __expf(sc3 - hm) * inv;
        a0 = fmaf(w0, bflo(f0), a0); a1 = fmaf(w0, bfhi(f0), a1);
        a0 = fmaf(w1, bflo(f1), a0); a1 = fmaf(w1, bfhi(f1), a1);
        a0 = fmaf(w2, bflo(f2), a0); a1 = fmaf(w2, bfhi(f2), a1);
        a0 = fmaf(w3, bflo(f3), a0); a1 = fmaf(w3, bfhi(f3), a1);
      }
      for (; j < batch; ++j) {
        int e = __shfl(myE, j, 64);
        int s = __shfl(myS, j, 64);
        float w = __expf(score[(size_t)e * 8 + head] - hm) * inv;
        unsigned fv = *(const unsigned*)&fsb[(size_t)s * DF + 2 * lane];
        a0 = fmaf(w, bflo(fv), a0);
        a1 = fmaf(w, bfhi(fv), a1);
      }
    }
    float2 o;
    o.x = a0; o.y = a1;
    *(float2*)&rst[(size_t)n * DF + 2 * lane] = o;
  }
}

// bias2 = O_b + gat_bias @ O_w^T
__global__ void k_bias2(const float* __restrict__ gat_bias,
                        const float* __restrict__ O_w,
                        const float* __restrict__ O_b, float* __restrict__ bias2) {
  int d = threadIdx.x;
  float acc = O_b[d];
  for (int k = 0; k < DF; ++k) acc = fmaf(gat_bias[k], O_w[(size_t)d * DF + k], acc);
  bias2[d] = acc;
}

// ---------------- readout ----------------
__global__ __launch_bounds__(128) void k_moy(
    const unsigned short* __restrict__ h2b, const int* __restrict__ ng,
    float* __restrict__ moy, float* __restrict__ cnt, int rows) {
  int tid = threadIdx.x;
  int per = (rows + gridDim.x - 1) / gridDim.x;
  int n0 = blockIdx.x * per;
  int n1 = min(rows, n0 + per);
  if (n0 >= n1) return;
  int cur = ng[n0];
  float acc = 0.f; int c = 0;
  for (int n = n0; n < n1; ++n) {
    int g = ng[n];
    if (g != cur) {
      atomicAdd(&moy[cur * DF + tid], acc);
      if (tid == 0) atomicAdd(&cnt[cur], (float)c);
      acc = 0.f; c = 0; cur = g;
    }
    acc += bf2f(h2b[(size_t)n * DF + tid]);
    ++c;
  }
  atomicAdd(&moy[cur * DF + tid], acc);
  if (tid == 0) atomicAdd(&cnt[cur], (float)c);
}

// P0[g] = W1[:,0:128] @ (moy_sum[g]/cnt[g]) + W1_b
__global__ void k_p0(const float* __restrict__ W1, const float* __restrict__ W1b_,
                     const float* __restrict__ moy, const float* __restrict__ cnt,
                     float* __restrict__ P0) {
  int g = blockIdx.x, d = threadIdx.x;
  float inv = 1.f / cnt[g];
  float acc = W1b_[d];
  for (int k = 0; k < DF; ++k) acc = fmaf(W1[(size_t)d * 384 + k], moy[g * DF + k] * inv, acc);
  P0[g * DF + d] = acc;
}

// ---------------- CSR head ----------------
__global__ __launch_bounds__(256) void k_head(
    const unsigned short* __restrict__ P1b, const unsigned short* __restrict__ P2b,
    const float* __restrict__ P0, const int* __restrict__ src,
    const unsigned* __restrict__ rowptr, const int* __restrict__ eidb,
    const float* __restrict__ W2, const float* __restrict__ W2b,
    float* __restrict__ out, int Ngr) {
  int tid = threadIdx.x, wid = tid >> 6, lane = tid & 63;
  int g = blockIdx.x & 7, sub = blockIdx.x >> 3, nsub = gridDim.x >> 3;
  float w2b = W2b[0];
  float w20 = W2[2 * lane], w21 = W2[2 * lane + 1];
  float b0 = P0[g * DF + 2 * lane], b1v = P0[g * DF + 2 * lane + 1];
  for (int nn = sub * 4 + wid; nn < Ngr; nn += nsub * 4) {
    int n = g * Ngr + nn;
    unsigned r0 = rowptr[n], r1 = rowptr[n + 1];
    if (r1 == r0) continue;
    unsigned p2 = *(const unsigned*)&P2b[(size_t)n * DF + 2 * lane];
    float base0 = b0 + bflo(p2);
    float base1 = b1v + bfhi(p2);
    for (unsigned rc = r0; rc < r1; rc += 64) {
      int cnt2 = (int)min(64u, r1 - rc);
      int myE = eidb[rc + ((lane < cnt2) ? lane : 0)];
      int myS = src[myE];
      int j = 0;
      for (; j + 4 <= cnt2; j += 4) {
        int e0 = __shfl(myE, j, 64), e1 = __shfl(myE, j + 1, 64);
        int e2 = __shfl(myE, j + 2, 64), e3 = __shfl(myE, j + 3, 64);
        int s0 = __shfl(myS, j, 64), s1 = __shfl(myS, j + 1, 64);
        int s2 = __shfl(myS, j + 2, 64), s3 = __shfl(myS, j + 3, 64);
        unsigned u0 = *(const unsigned*)&P1b[(size_t)s0 * DF + 2 * lane];
        unsigned u1 = *(const unsigned*)&P1b[(size_t)s1 * DF + 2 * lane];
        unsigned u2 = *(const unsigned*)&P1b[(size_t)s2 * DF + 2 * lane];
        unsigned u3 = *(const unsigned*)&P1b[(size_t)s3 * DF + 2 * lane];
        float v0 = fmaxf(base0 + bflo(u0), 0.f) * w20 + fmaxf(base1 + bfhi(u0), 0.f) * w21;
        float v1 = fmaxf(base0 + bflo(u1), 0.f) * w20 + fmaxf(base1 + bfhi(u1), 0.f) * w21;
        float v2 = fmaxf(base0 + bflo(u2), 0.f) * w20 + fmaxf(base1 + bfhi(u2), 0.f) * w21;
        float v3 = fmaxf(base0 + bflo(u3), 0.f) * w20 + fmaxf(base1 + bfhi(u3), 0.f) * w21;
#pragma unroll
        for (int mk = 1; mk < 64; mk <<= 1) {
          v0 += __shfl_xor(v0, mk, 64);
          v1 += __shfl_xor(v1, mk, 64);
          v2 += __shfl_xor(v2, mk, 64);
          v3 += __shfl_xor(v3, mk, 64);
        }
        if (lane == 0) {
          out[e0] = sigm(v0 + w2b);
          out[e1] = sigm(v1 + w2b);
          out[e2] = sigm(v2 + w2b);
          out[e3] = sigm(v3 + w2b);
        }
      }
      for (; j < cnt2; ++j) {
        int e = __shfl(myE, j, 64);
        int s = __shfl(myS, j, 64);
        unsigned p1 = *(const unsigned*)&P1b[(size_t)s * DF + 2 * lane];
        float v = fmaxf(base0 + bflo(p1), 0.f) * w20 + fmaxf(base1 + bfhi(p1), 0.f) * w21;
#pragma unroll
        for (int mk = 1; mk < 64; mk <<= 1) v += __shfl_xor(v, mk, 64);
        if (lane == 0) out[e] = sigm(v + w2b);
      }
    }
  }
}

extern "C" void kernel_launch(void* const* d_in, const int* in_sizes, int n_in,
                              void* d_out, int out_size, void* d_ws, size_t ws_size,
                              hipStream_t stream) {
  const float* h_in = (const float*)d_in[0];
  const float* e_in = (const float*)d_in[1];
  const int* src = (const int*)d_in[2];
  const int* dst = (const int*)d_in[3];
  const int* node_graph = (const int*)d_in[4];
  const float* emb_n_w = (const float*)d_in[6];
  const float* emb_n_b = (const float*)d_in[7];
  const float* emb_e_w = (const float*)d_in[8];
  const float* emb_e_b = (const float*)d_in[9];
  const float* Us = (const float*)d_in[10];
  const float* Vs = (const float*)d_in[11];
  const float* As = (const float*)d_in[12];
  const float* Bs = (const float*)d_in[13];
  const float* Cs = (const float*)d_in[14];
  const float* gat_src_w = (const float*)d_in[15];
  const float* gat_src_b = (const float*)d_in[16];
  const float* gat_dst_w = (const float*)d_in[17];
  const float* gat_dst_b = (const float*)d_in[18];
  const float* gat_attn = (const float*)d_in[19];
  const float* gat_bias = (const float*)d_in[20];
  const float* O_w = (const float*)d_in[21];
  const float* O_b = (const float*)d_in[22];
  const float* W1_w = (const float*)d_in[23];
  const float* W1_b = (const float*)d_in[24];
  const float* W2_w = (const float*)d_in[25];
  const float* W2_b = (const float*)d_in[26];
  float* out = (float*)d_out;

  const int N = in_sizes[0] / 64;   // 30000
  const int E = in_sizes[1] / 16;   // 360000
  const int Eg = E / NGRAPH;        // 45000
  const int Ngr = N / NGRAPH;       // 3750

  auto rnd = [](size_t b) { return (b + 255) & ~(size_t)255; };
  const size_t sz_e0 = rnd((size_t)E * DF * 2);
  const size_t sz_node = rnd((size_t)N * DF * 4);
  const size_t sz_nodeb = rnd((size_t)N * DF * 2);
  const size_t sz_score = rnd((size_t)E * 8 * 4);
  const size_t sz_wfrag = rnd(20 * 2048 * 8 * 2);
  const size_t sz_rp = rnd((size_t)(N + 1) * 4);
  const size_t sz_eid = rnd((size_t)E * 4);
  const size_t sz_misc = rnd(4096 * 4);
  const size_t needed_min = sz_e0 + 3 * sz_node + 4 * sz_nodeb + sz_score + sz_wfrag +
                            3 * sz_rp + sz_eid + sz_misc;
  const size_t needed_full = needed_min + sz_e0;  // + xe
  if (ws_size < needed_min) {
    k_fill_u32<<<256, 256, 0, stream>>>((unsigned*)out, 0xBF800000u, (long long)out_size);
    return;
  }
  const bool have_xe = (ws_size >= needed_full);

  char* wp = (char*)d_ws;
  auto alloc = [&](size_t bytes) { void* p = wp; wp += bytes; return p; };
  unsigned short* e0u = (unsigned short*)alloc(sz_e0);
  float* h0 = (float*)alloc(sz_node);
  float* hU = (float*)alloc(sz_node);
  float* rst = (float*)alloc(sz_node);
  unsigned short* hVb = (unsigned short*)alloc(sz_nodeb);
  unsigned short* hBb = (unsigned short*)alloc(sz_nodeb);
  unsigned short* hCb = (unsigned short*)alloc(sz_nodeb);
  unsigned short* h2b = (unsigned short*)alloc(sz_nodeb);
  float* score = (float*)alloc(sz_score);
  short* wfrag = (short*)alloc(sz_wfrag);
  unsigned* rowptr = (unsigned*)alloc(sz_rp);
  unsigned* cursor = (unsigned*)alloc(sz_rp);
  unsigned* deg = (unsigned*)alloc(sz_rp);
  int* eidb = (int*)alloc(sz_eid);
  float* misc = (float*)alloc(sz_misc);
  unsigned short* xe = have_xe ? (unsigned short*)alloc(sz_e0) : nullptr;
  float* stat = misc;                                     // [0,1024)
  float* bias2 = misc + 1024;                             // [1024,1152)
  float* moy = misc + 1152;                               // [1152,2176)
  float* cnt = misc + 2176;                               // [2176,2184)
  float* P0 = misc + 2304;                                // [2304,3328)
  unsigned short* P1b = e0u;
  unsigned short* P2b = e0u + (size_t)N * DF;

  auto WF = [&](int idx) { return wfrag + (size_t)idx * 2048 * 8; };

  // CSR build (dst lists; reused by layers + GAT + head)
  k_fill_u32<<<64, 256, 0, stream>>>(deg, 0u, N);
  k_deg<<<512, 256, 0, stream>>>(dst, deg, E);
  k_scan<<<1, 1024, 0, stream>>>(deg, rowptr, cursor, N);
  k_scatter<<<512, 256, 0, stream>>>(dst, cursor, eidb, E);

  k_wconv<<<20, 512, 0, stream>>>(Us, Vs, As, Bs, Cs, gat_src_w, gat_dst_w, O_w,
                                  W1_w, wfrag);

  const int gN = (N + 127) / 128;
  k_node_embed<<<2048, 128, 0, stream>>>(h_in, emb_n_w, emb_n_b, h0, N);
  k_edge_embed<<<4096, 128, 0, stream>>>(e_in, emb_e_w, emb_e_b, e0u, E);

  for (int l = 0; l < 3; ++l) {
    k_gemm4_mfma<<<gN, 512, 0, stream>>>(h0, WF(3 + l), WF(l), WF(9 + l), WF(12 + l),
                                         hVb, hU, hBb, hCb, N);
    k_fill_u32<<<4, 256, 0, stream>>>((unsigned*)stat, 0u, 1024);
    k_node_agg<<<2048, 256, 0, stream>>>(hU, hVb, e0u, src, rowptr, eidb, stat, Ngr);
    if (have_xe) {
      k_edge_x<<<512, 512, 0, stream>>>(e0u, WF(6 + l), hBb, hCb, src, dst, xe, Eg);
      k_xstats<<<512, 256, 0, stream>>>(xe, stat, (long long)E * DF / 8);
      k_bn_finalize<<<1, 256, 0, stream>>>(stat, (float)N, (float)E);
      k_node_update<<<2048, 256, 0, stream>>>(h0, hU, stat, (long long)N * DF);
      k_edge_apply<<<2048, 256, 0, stream>>>(e0u, xe, stat, (long long)E * DF / 8);
    } else {
      k_edge_mfma<0><<<256, 512, 0, stream>>>(e0u, WF(6 + l), hBb, hCb, src, dst,
                                              stat, Eg);
      k_bn_finalize<<<1, 256, 0, stream>>>(stat, (float)N, (float)E);
      k_node_update<<<2048, 256, 0, stream>>>(h0, hU, stat, (long long)N * DF);
      k_edge_mfma<1><<<256, 512, 0, stream>>>(e0u, WF(6 + l), hBb, hCb, src, dst,
                                              stat, Eg);
    }
  }

  // GATv2: fs -> hVb, fd -> hBb
  k_gemm_mfma<1><<<gN, 512, 0, stream>>>(h0, WF(15), gat_src_b, hVb, N);
  k_gemm_mfma<1><<<gN, 512, 0, stream>>>(h0, WF(16), gat_dst_b, hBb, N);
  k_gat_score<<<512, 256, 0, stream>>>(hVb, hBb, src, dst, gat_attn, score, Eg);
  k_gat_node<<<2048, 256, 0, stream>>>(score, hVb, src, rowptr, eidb, rst, Ngr);
  k_bias2<<<1, 128, 0, stream>>>(gat_bias, O_w, O_b, bias2);
  k_gemm_mfma<1><<<gN, 512, 0, stream>>>(rst, WF(17), bias2, h2b, N);  // h2

  // readout + decomposed head
  k_fill_u32<<<2, 256, 0, stream>>>((unsigned*)moy, 0u, 1032);
  k_moy<<<128, 128, 0, stream>>>(h2b, node_graph, moy, cnt, N);
  k_p0<<<8, 128, 0, stream>>>(W1_w, W1_b, moy, cnt, P0);
  k_gemmb_mfma<<<gN, 512, 0, stream>>>(h2b, WF(18), P1b, N);
  k_gemmb_mfma<<<gN, 512, 0, stream>>>(h2b, WF(19), P2b, N);
  k_head<<<2048, 256, 0, stream>>>(P1b, P2b, P0, src, rowptr, eidb, W2_w, W2_b,
                                   out, Ngr);
}

// Round 12
// 1472.902 us; speedup vs baseline: 1.7433x; 1.0029x over previous
//
#include <hip/hip_runtime.h>

#define DF 128
#define NGRAPH 8

typedef __attribute__((ext_vector_type(8))) short bf16x8;
typedef __attribute__((ext_vector_type(4))) float f32x4;

__device__ __forceinline__ float sigm(float x) { return 1.f / (1.f + __expf(-x)); }
__device__ __forceinline__ unsigned short f2bf(float f) {  // RNE f32->bf16
  unsigned u = __float_as_uint(f);
  u += 0x7FFFu + ((u >> 16) & 1u);
  return (unsigned short)(u >> 16);
}
__device__ __forceinline__ float bf2f(unsigned short u) {
  return __uint_as_float(((unsigned)u) << 16);
}
__device__ __forceinline__ float bflo(unsigned u) { return __uint_as_float(u << 16); }
__device__ __forceinline__ float bfhi(unsigned u) { return __uint_as_float(u & 0xffff0000u); }

// load 8 consecutive f32 (32B-aligned) -> bf16x8
__device__ __forceinline__ bf16x8 cvt8(const float* __restrict__ p) {
  float4 a = *(const float4*)p;
  float4 b = *(const float4*)(p + 4);
  bf16x8 r;
  r[0] = (short)f2bf(a.x); r[1] = (short)f2bf(a.y);
  r[2] = (short)f2bf(a.z); r[3] = (short)f2bf(a.w);
  r[4] = (short)f2bf(b.x); r[5] = (short)f2bf(b.y);
  r[6] = (short)f2bf(b.z); r[7] = (short)f2bf(b.w);
  return r;
}

__device__ __forceinline__ void agg_max(unsigned hv, unsigned ev, float& m0, float& m1) {
  m0 = fmaxf(m0, bflo(hv) * sigm(bflo(ev)));
  m1 = fmaxf(m1, bfhi(hv) * sigm(bfhi(ev)));
}

// ---------------- generic fill ----------------
__global__ void k_fill_u32(unsigned* __restrict__ p, unsigned v, long long n) {
  long long i = (long long)blockIdx.x * blockDim.x + threadIdx.x;
  long long st = (long long)gridDim.x * blockDim.x;
  for (; i < n; i += st) p[i] = v;
}

// ---------------- CSR build (dst-sorted edge lists) ----------------
__global__ void k_deg(const int* __restrict__ dst, unsigned* __restrict__ deg, int E) {
  int i = blockIdx.x * blockDim.x + threadIdx.x;
  int st = gridDim.x * blockDim.x;
  for (; i < E; i += st) atomicAdd(&deg[dst[i]], 1u);
}

__global__ __launch_bounds__(1024) void k_scan(
    const unsigned* __restrict__ deg, unsigned* __restrict__ rowptr,
    unsigned* __restrict__ cursor, int N) {
  __shared__ unsigned part[1024];
  int t = threadIdx.x;
  int per = (N + 1023) >> 10;
  int s0 = t * per, s1 = min(N, s0 + per);
  unsigned s = 0;
  for (int i = s0; i < s1; ++i) s += deg[i];
  part[t] = s;
  __syncthreads();
  for (int off = 1; off < 1024; off <<= 1) {
    unsigned v = (t >= off) ? part[t - off] : 0u;
    __syncthreads();
    part[t] += v;
    __syncthreads();
  }
  unsigned base = (t == 0) ? 0u : part[t - 1];
  for (int i = s0; i < s1; ++i) {
    rowptr[i] = base;
    cursor[i] = base;
    base += deg[i];
  }
  if (t == 1023) rowptr[N] = part[1023];
}

__global__ void k_scatter(const int* __restrict__ dst, unsigned* __restrict__ cursor,
                          int* __restrict__ eidb, int E) {
  int i = blockIdx.x * blockDim.x + threadIdx.x;
  int st = gridDim.x * blockDim.x;
  for (; i < E; i += st) {
    unsigned p = atomicAdd(&cursor[dst[i]], 1u);
    eidb[p] = i;
  }
}

// ---------------- weight pre-conversion to MFMA fragment order ----------------
// 0-2 U, 3-5 V, 6-8 A, 9-11 B, 12-14 C, 15 gsw, 16 gdw, 17 Ow, 18 W1[:,128:256], 19 W1[:,256:384]
__global__ __launch_bounds__(512) void k_wconv(
    const float* __restrict__ Us, const float* __restrict__ Vs,
    const float* __restrict__ As, const float* __restrict__ Bs,
    const float* __restrict__ Cs, const float* __restrict__ gsw,
    const float* __restrict__ gdw, const float* __restrict__ Ow,
    const float* __restrict__ W1, short* __restrict__ out) {
  int b = blockIdx.x;
  const float* W;
  int ldw = DF;
  if (b < 3) W = Us + b * 16384;
  else if (b < 6) W = Vs + (b - 3) * 16384;
  else if (b < 9) W = As + (b - 6) * 16384;
  else if (b < 12) W = Bs + (b - 9) * 16384;
  else if (b < 15) W = Cs + (b - 12) * 16384;
  else if (b == 15) W = gsw;
  else if (b == 16) W = gdw;
  else if (b == 17) W = Ow;
  else if (b == 18) { W = W1 + 128; ldw = 384; }
  else { W = W1 + 256; ldw = 384; }
  short* o = out + (size_t)b * 2048 * 8;
  for (int s = threadIdx.x; s < 2048; s += 512) {
    int ct = s >> 8, ks = (s >> 6) & 3, l = s & 63;
    int row = ct * 16 + (l & 15), k0 = ks * 32 + (l >> 4) * 8;
    *(bf16x8*)&o[s * 8] = cvt8(W + (size_t)row * ldw + k0);
  }
}

// ---------------- embeddings ----------------
__global__ __launch_bounds__(128) void k_node_embed(
    const float* __restrict__ hin, const float* __restrict__ w,
    const float* __restrict__ b, float* __restrict__ h0, int rows) {
  __shared__ float Wt[64 * DF];
  __shared__ float ar[4][64];
  int tid = threadIdx.x;
  for (int i = tid; i < 64 * DF; i += 128) Wt[(i & 63) * DF + (i >> 6)] = w[i];
  float bb = b[tid];
  __syncthreads();
  for (int r0 = blockIdx.x * 4; r0 < rows; r0 += gridDim.x * 4) {
    for (int i = tid; i < 256; i += 128) ar[i >> 6][i & 63] = hin[(size_t)r0 * 64 + i];
    __syncthreads();
    float a0 = bb, a1 = bb, a2 = bb, a3 = bb;
#pragma unroll 8
    for (int k = 0; k < 64; ++k) {
      float wv = Wt[k * DF + tid];
      a0 = fmaf(ar[0][k], wv, a0); a1 = fmaf(ar[1][k], wv, a1);
      a2 = fmaf(ar[2][k], wv, a2); a3 = fmaf(ar[3][k], wv, a3);
    }
    h0[(size_t)r0 * DF + tid] = a0;
    h0[(size_t)(r0 + 1) * DF + tid] = a1;
    h0[(size_t)(r0 + 2) * DF + tid] = a2;
    h0[(size_t)(r0 + 3) * DF + tid] = a3;
    __syncthreads();
  }
}

__global__ __launch_bounds__(128) void k_edge_embed(
    const float* __restrict__ ein, const float* __restrict__ w,
    const float* __restrict__ b, unsigned short* __restrict__ e0u, int rows) {
  __shared__ float Wt[16 * DF];
  __shared__ float ar[4][16];
  int tid = threadIdx.x;
  for (int i = tid; i < 16 * DF; i += 128) Wt[(i & 15) * DF + (i >> 4)] = w[i];
  float bb = b[tid];
  __syncthreads();
  for (int r0 = blockIdx.x * 4; r0 < rows; r0 += gridDim.x * 4) {
    if (tid < 64) ar[tid >> 4][tid & 15] = ein[(size_t)r0 * 16 + tid];
    __syncthreads();
    float a0 = bb, a1 = bb, a2 = bb, a3 = bb;
#pragma unroll
    for (int k = 0; k < 16; ++k) {
      float wv = Wt[k * DF + tid];
      a0 = fmaf(ar[0][k], wv, a0); a1 = fmaf(ar[1][k], wv, a1);
      a2 = fmaf(ar[2][k], wv, a2); a3 = fmaf(ar[3][k], wv, a3);
    }
    e0u[(size_t)r0 * DF + tid] = f2bf(a0);
    e0u[(size_t)(r0 + 1) * DF + tid] = f2bf(a1);
    e0u[(size_t)(r0 + 2) * DF + tid] = f2bf(a2);
    e0u[(size_t)(r0 + 3) * DF + tid] = f2bf(a3);
    __syncthreads();
  }
}

// ---------------- MFMA [rows,128] @ W^T (+bias), frag weights, f32 input ----------------
template <int OUTBF>
__global__ __launch_bounds__(512) void k_gemm_mfma(
    const float* __restrict__ A, const short* __restrict__ Wf,
    const float* __restrict__ bias, void* __restrict__ outv, int rows) {
  __shared__ short Wb[2048 * 8];  // 32 KB
  int tid = threadIdx.x;
  for (int s = tid; s < 2048; s += 512)
    *(bf16x8*)&Wb[s * 8] = *(const bf16x8*)&Wf[(size_t)s * 8];
  __syncthreads();
  float* outf = (float*)outv;
  unsigned short* outb = (unsigned short*)outv;
  int wid = tid >> 6, lane = tid & 63, q = lane >> 4, m = lane & 15;
  int ntiles = (rows + 127) >> 7;
  for (int t = blockIdx.x; t < ntiles; t += gridDim.x) {
    int r0 = t * 128 + wid * 16;
    int rr = r0 + m;
    if (rr >= rows) rr = rows - 1;
    const float* ap = A + (size_t)rr * DF + q * 8;
    bf16x8 a[4];
#pragma unroll
    for (int ks = 0; ks < 4; ++ks) a[ks] = cvt8(ap + 32 * ks);
#pragma unroll
    for (int ct = 0; ct < 8; ++ct) {
      f32x4 acc = {0.f, 0.f, 0.f, 0.f};
#pragma unroll
      for (int ks = 0; ks < 4; ++ks) {
        bf16x8 b = *(const bf16x8*)&Wb[((ct * 4 + ks) * 64 + lane) * 8];
        acc = __builtin_amdgcn_mfma_f32_16x16x32_bf16(a[ks], b, acc, 0, 0, 0);
      }
      int col = ct * 16 + m;
      float bb = bias ? bias[col] : 0.f;
#pragma unroll
      for (int j = 0; j < 4; ++j) {
        int row = r0 + q * 4 + j;
        if (row < rows) {
          if (OUTBF) outb[(size_t)row * DF + col] = f2bf(acc[j] + bb);
          else outf[(size_t)row * DF + col] = acc[j] + bb;
        }
      }
    }
  }
}

// same, bf16 input
__global__ __launch_bounds__(512) void k_gemmb_mfma(
    const unsigned short* __restrict__ A, const short* __restrict__ Wf,
    unsigned short* __restrict__ outb, int rows) {
  __shared__ short Wb[2048 * 8];
  int tid = threadIdx.x;
  for (int s = tid; s < 2048; s += 512)
    *(bf16x8*)&Wb[s * 8] = *(const bf16x8*)&Wf[(size_t)s * 8];
  __syncthreads();
  int wid = tid >> 6, lane = tid & 63, q = lane >> 4, m = lane & 15;
  int ntiles = (rows + 127) >> 7;
  for (int t = blockIdx.x; t < ntiles; t += gridDim.x) {
    int r0 = t * 128 + wid * 16;
    int rr = r0 + m;
    if (rr >= rows) rr = rows - 1;
    const unsigned short* ap = A + (size_t)rr * DF + q * 8;
    bf16x8 a[4];
#pragma unroll
    for (int ks = 0; ks < 4; ++ks) a[ks] = *(const bf16x8*)(ap + 32 * ks);
#pragma unroll
    for (int ct = 0; ct < 8; ++ct) {
      f32x4 acc = {0.f, 0.f, 0.f, 0.f};
#pragma unroll
      for (int ks = 0; ks < 4; ++ks) {
        bf16x8 b = *(const bf16x8*)&Wb[((ct * 4 + ks) * 64 + lane) * 8];
        acc = __builtin_amdgcn_mfma_f32_16x16x32_bf16(a[ks], b, acc, 0, 0, 0);
      }
      int col = ct * 16 + m;
#pragma unroll
      for (int j = 0; j < 4; ++j) {
        int row = r0 + q * 4 + j;
        if (row < rows) outb[(size_t)row * DF + col] = f2bf(acc[j]);
      }
    }
  }
}

// ---------------- fused 4-output node GEMM (V,U,B,C) ----------------
__global__ __launch_bounds__(512) void k_gemm4_mfma(
    const float* __restrict__ h0, const short* __restrict__ Vf,
    const short* __restrict__ Uf, const short* __restrict__ Bf,
    const short* __restrict__ Cf, unsigned short* __restrict__ hVb,
    float* __restrict__ hU, unsigned short* __restrict__ hBb,
    unsigned short* __restrict__ hCb, int rows) {
  __shared__ short Wl[4 * 2048 * 8];  // 128 KB
  int tid = threadIdx.x;
  for (int s = tid; s < 2048; s += 512) {
    *(bf16x8*)&Wl[(size_t)s * 8] = *(const bf16x8*)&Vf[(size_t)s * 8];
    *(bf16x8*)&Wl[(size_t)(2048 + s) * 8] = *(const bf16x8*)&Uf[(size_t)s * 8];
    *(bf16x8*)&Wl[(size_t)(4096 + s) * 8] = *(const bf16x8*)&Bf[(size_t)s * 8];
    *(bf16x8*)&Wl[(size_t)(6144 + s) * 8] = *(const bf16x8*)&Cf[(size_t)s * 8];
  }
  __syncthreads();
  int wid = tid >> 6, lane = tid & 63, q = lane >> 4, m = lane & 15;
  int ntiles = (rows + 127) >> 7;
  for (int t = blockIdx.x; t < ntiles; t += gridDim.x) {
    int r0 = t * 128 + wid * 16;
    int rr = r0 + m;
    if (rr >= rows) rr = rows - 1;
    const float* ap = h0 + (size_t)rr * DF + q * 8;
    bf16x8 a[4];
#pragma unroll
    for (int ks = 0; ks < 4; ++ks) a[ks] = cvt8(ap + 32 * ks);
#pragma unroll
    for (int w = 0; w < 4; ++w) {
#pragma unroll
      for (int ct = 0; ct < 8; ++ct) {
        f32x4 acc = {0.f, 0.f, 0.f, 0.f};
#pragma unroll
        for (int ks = 0; ks < 4; ++ks) {
          bf16x8 b = *(const bf16x8*)&Wl[((w * 2048) + (ct * 4 + ks) * 64 + lane) * 8];
          acc = __builtin_amdgcn_mfma_f32_16x16x32_bf16(a[ks], b, acc, 0, 0, 0);
        }
        int col = ct * 16 + m;
#pragma unroll
        for (int j = 0; j < 4; ++j) {
          int row = r0 + q * 4 + j;
          if (row < rows) {
            if (w == 1) hU[(size_t)row * DF + col] = acc[j];
            else {
              unsigned short v = f2bf(acc[j]);
              unsigned short* o = (w == 0) ? hVb : ((w == 2) ? hBb : hCb);
              o[(size_t)row * DF + col] = v;
            }
          }
        }
      }
    }
  }
}

// ======== barrier-free swapped edge passes (mfma(W, e): lane owns ONE edge) ========
// D: col = lane&15 = edge-in-tile; row = (lane>>4)*4 + j = feature within ct block.
// Feature of acc c_ct[j] = ct*16 + q*4 + j.

#define EDGE_MFMA_BODY                                                                 \
  const unsigned short* ep = e0u + (size_t)ec * DF + q * 8;                            \
  bf16x8 bv0 = *(const bf16x8*)(ep);                                                   \
  bf16x8 bv1 = *(const bf16x8*)(ep + 32);                                              \
  bf16x8 bv2 = *(const bf16x8*)(ep + 64);                                              \
  bf16x8 bv3 = *(const bf16x8*)(ep + 96);                                              \
  f32x4 c0 = {0.f, 0.f, 0.f, 0.f}, c1 = c0, c2 = c0, c3 = c0;                          \
  f32x4 c4 = c0, c5 = c0, c6 = c0, c7 = c0;                                            \
  _Pragma("unroll") for (int ks = 0; ks < 4; ++ks) {                                   \
    bf16x8 bv = (ks == 0) ? bv0 : (ks == 1) ? bv1 : (ks == 2) ? bv2 : bv3;             \
    c0 = __builtin_amdgcn_mfma_f32_16x16x32_bf16(*(const bf16x8*)&Wb[((0 * 4 + ks) * 64 + lane) * 8], bv, c0, 0, 0, 0); \
    c1 = __builtin_amdgcn_mfma_f32_16x16x32_bf16(*(const bf16x8*)&Wb[((1 * 4 + ks) * 64 + lane) * 8], bv, c1, 0, 0, 0); \
    c2 = __builtin_amdgcn_mfma_f32_16x16x32_bf16(*(const bf16x8*)&Wb[((2 * 4 + ks) * 64 + lane) * 8], bv, c2, 0, 0, 0); \
    c3 = __builtin_amdgcn_mfma_f32_16x16x32_bf16(*(const bf16x8*)&Wb[((3 * 4 + ks) * 64 + lane) * 8], bv, c3, 0, 0, 0); \
    c4 = __builtin_amdgcn_mfma_f32_16x16x32_bf16(*(const bf16x8*)&Wb[((4 * 4 + ks) * 64 + lane) * 8], bv, c4, 0, 0, 0); \
    c5 = __builtin_amdgcn_mfma_f32_16x16x32_bf16(*(const bf16x8*)&Wb[((5 * 4 + ks) * 64 + lane) * 8], bv, c5, 0, 0, 0); \
    c6 = __builtin_amdgcn_mfma_f32_16x16x32_bf16(*(const bf16x8*)&Wb[((6 * 4 + ks) * 64 + lane) * 8], bv, c6, 0, 0, 0); \
    c7 = __builtin_amdgcn_mfma_f32_16x16x32_bf16(*(const bf16x8*)&Wb[((7 * 4 + ks) * 64 + lane) * 8], bv, c7, 0, 0, 0); \
  }

// stats pass: per-feature sum / sumsq of x = e@As^T + hB[dst] + hC[src]
__global__ __launch_bounds__(512) void k_edge_xs(
    const unsigned short* __restrict__ e0u, const short* __restrict__ Af,
    const unsigned short* __restrict__ hBb, const unsigned short* __restrict__ hCb,
    const int* __restrict__ src, const int* __restrict__ dst,
    float* __restrict__ stat, int Eg) {
  __shared__ short Wb[2048 * 8];  // 32 KB
  __shared__ float ls[256];
  int tid = threadIdx.x;
  for (int s = tid; s < 2048; s += 512)
    *(bf16x8*)&Wb[s * 8] = *(const bf16x8*)&Af[(size_t)s * 8];
  if (tid < 256) ls[tid] = 0.f;
  int wid = tid >> 6, lane = tid & 63, q = lane >> 4, m = lane & 15;
  int g = blockIdx.x & 7, sub = blockIdx.x >> 3, nsub = gridDim.x >> 3;
  int gbase = g * Eg, gend = gbase + Eg;
  int tpg = (Eg + 127) >> 7;
  float ps[32], pq[32];
#pragma unroll
  for (int i = 0; i < 32; ++i) { ps[i] = 0.f; pq[i] = 0.f; }
  __syncthreads();
  for (int t = sub; t < tpg; t += nsub) {
    int r0 = gbase + t * 128 + wid * 16;
    int edge = r0 + m;
    bool ok = edge < gend;
    int ec = ok ? edge : gend - 1;
    EDGE_MFMA_BODY
    if (ok) {
      int sidx = src[ec], didx = dst[ec];
      const unsigned short* pb = hBb + (size_t)didx * DF + q * 4;
      const unsigned short* pc = hCb + (size_t)sidx * DF + q * 4;
#pragma unroll
      for (int ct = 0; ct < 8; ++ct) {
        f32x4 cc = (ct == 0) ? c0 : (ct == 1) ? c1 : (ct == 2) ? c2 : (ct == 3) ? c3
                   : (ct == 4) ? c4 : (ct == 5) ? c5 : (ct == 6) ? c6 : c7;
        ushort4 hb = *(const ushort4*)(pb + ct * 16);
        ushort4 hc = *(const ushort4*)(pc + ct * 16);
        float x0 = cc[0] + bf2f(hb.x) + bf2f(hc.x);
        float x1 = cc[1] + bf2f(hb.y) + bf2f(hc.y);
        float x2 = cc[2] + bf2f(hb.z) + bf2f(hc.z);
        float x3 = cc[3] + bf2f(hb.w) + bf2f(hc.w);
        ps[ct * 4 + 0] += x0; pq[ct * 4 + 0] += x0 * x0;
        ps[ct * 4 + 1] += x1; pq[ct * 4 + 1] += x1 * x1;
        ps[ct * 4 + 2] += x2; pq[ct * 4 + 2] += x2 * x2;
        ps[ct * 4 + 3] += x3; pq[ct * 4 + 3] += x3 * x3;
      }
    }
  }
  // reduce across the 16 m-lanes of each q group, then LDS, then global
#pragma unroll
  for (int i = 0; i < 32; ++i) {
    float s = ps[i], sq = pq[i];
    s += __shfl_xor(s, 1, 64); sq += __shfl_xor(sq, 1, 64);
    s += __shfl_xor(s, 2, 64); sq += __shfl_xor(sq, 2, 64);
    s += __shfl_xor(s, 4, 64); sq += __shfl_xor(sq, 4, 64);
    s += __shfl_xor(s, 8, 64); sq += __shfl_xor(sq, 8, 64);
    if (m == 0) {
      int feat = (i >> 2) * 16 + q * 4 + (i & 3);
      atomicAdd(&ls[feat], s);
      atomicAdd(&ls[128 + feat], sq);
    }
  }
  __syncthreads();
  if (tid < 128) {
    atomicAdd(&stat[512 + tid], ls[tid]);
    atomicAdd(&stat[640 + tid], ls[128 + tid]);
  }
}

// apply pass: e += relu((x - mean)*inv), recomputing x; barrier-free
__global__ __launch_bounds__(512) void k_edge_xa(
    unsigned short* __restrict__ e0u, const short* __restrict__ Af,
    const unsigned short* __restrict__ hBb, const unsigned short* __restrict__ hCb,
    const int* __restrict__ src, const int* __restrict__ dst,
    const float* __restrict__ stat, int Eg) {
  __shared__ short Wb[2048 * 8];  // 32 KB
  int tid = threadIdx.x;
  for (int s = tid; s < 2048; s += 512)
    *(bf16x8*)&Wb[s * 8] = *(const bf16x8*)&Af[(size_t)s * 8];
  int wid = tid >> 6, lane = tid & 63, q = lane >> 4, m = lane & 15;
  float mm[32], iv[32];
#pragma unroll
  for (int ct = 0; ct < 8; ++ct)
#pragma unroll
    for (int j = 0; j < 4; ++j) {
      int f = ct * 16 + q * 4 + j;
      mm[ct * 4 + j] = stat[768 + f];
      iv[ct * 4 + j] = stat[896 + f];
    }
  int g = blockIdx.x & 7, sub = blockIdx.x >> 3, nsub = gridDim.x >> 3;
  int gbase = g * Eg, gend = gbase + Eg;
  int tpg = (Eg + 127) >> 7;
  __syncthreads();
  for (int t = sub; t < tpg; t += nsub) {
    int r0 = gbase + t * 128 + wid * 16;
    int edge = r0 + m;
    bool ok = edge < gend;
    int ec = ok ? edge : gend - 1;
    EDGE_MFMA_BODY
    if (ok) {
      int sidx = src[ec], didx = dst[ec];
      const unsigned short* pb = hBb + (size_t)didx * DF + q * 4;
      const unsigned short* pc = hCb + (size_t)sidx * DF + q * 4;
      unsigned short* pe = e0u + (size_t)ec * DF + q * 4;
#pragma unroll
      for (int ct = 0; ct < 8; ++ct) {
        f32x4 cc = (ct == 0) ? c0 : (ct == 1) ? c1 : (ct == 2) ? c2 : (ct == 3) ? c3
                   : (ct == 4) ? c4 : (ct == 5) ? c5 : (ct == 6) ? c6 : c7;
        ushort4 hb = *(const ushort4*)(pb + ct * 16);
        ushort4 hc = *(const ushort4*)(pc + ct * 16);
        ushort4 eo = *(const ushort4*)(pe + ct * 16);
        float x0 = cc[0] + bf2f(hb.x) + bf2f(hc.x);
        float x1 = cc[1] + bf2f(hb.y) + bf2f(hc.y);
        float x2 = cc[2] + bf2f(hb.z) + bf2f(hc.z);
        float x3 = cc[3] + bf2f(hb.w) + bf2f(hc.w);
        ushort4 nv;
        nv.x = f2bf(bf2f(eo.x) + fmaxf((x0 - mm[ct * 4 + 0]) * iv[ct * 4 + 0], 0.f));
        nv.y = f2bf(bf2f(eo.y) + fmaxf((x1 - mm[ct * 4 + 1]) * iv[ct * 4 + 1], 0.f));
        nv.z = f2bf(bf2f(eo.z) + fmaxf((x2 - mm[ct * 4 + 2]) * iv[ct * 4 + 2], 0.f));
        nv.w = f2bf(bf2f(eo.w) + fmaxf((x3 - mm[ct * 4 + 3]) * iv[ct * 4 + 3], 0.f));
        *(ushort4*)(pe + ct * 16) = nv;
      }
    }
  }
}

// ---------------- node-major segment max + hU update + BN stats ----------------
__global__ __launch_bounds__(256) void k_node_agg(
    float* __restrict__ hU, const unsigned short* __restrict__ hVb,
    const unsigned short* __restrict__ e0u, const int* __restrict__ src,
    const unsigned* __restrict__ rowptr, const int* __restrict__ eidb,
    float* __restrict__ stat, int Ngr) {
  __shared__ float sr[4][256];
  int tid = threadIdx.x, wid = tid >> 6, lane = tid & 63;
  int g = blockIdx.x & 7, sub = blockIdx.x >> 3, nsub = gridDim.x >> 3;
  float ps0 = 0.f, ps1 = 0.f, pq0 = 0.f, pq1 = 0.f;
  for (int nn = sub * 4 + wid; nn < Ngr; nn += nsub * 4) {
    int n = g * Ngr + nn;
    unsigned r0 = rowptr[n], r1 = rowptr[n + 1];
    float m0 = -3.4e38f, m1 = -3.4e38f;
    for (unsigned rc = r0; rc < r1; rc += 64) {
      int batch = (int)min(64u, r1 - rc);
      int myE = eidb[rc + ((lane < batch) ? lane : 0)];
      int myS = src[myE];
      int j = 0;
      for (; j + 4 <= batch; j += 4) {
        int e0 = __shfl(myE, j, 64), e1 = __shfl(myE, j + 1, 64);
        int e2 = __shfl(myE, j + 2, 64), e3 = __shfl(myE, j + 3, 64);
        int s0 = __shfl(myS, j, 64), s1 = __shfl(myS, j + 1, 64);
        int s2 = __shfl(myS, j + 2, 64), s3 = __shfl(myS, j + 3, 64);
        unsigned h0v = *(const unsigned*)&hVb[(size_t)s0 * DF + 2 * lane];
        unsigned h1v = *(const unsigned*)&hVb[(size_t)s1 * DF + 2 * lane];
        unsigned h2v = *(const unsigned*)&hVb[(size_t)s2 * DF + 2 * lane];
        unsigned h3v = *(const unsigned*)&hVb[(size_t)s3 * DF + 2 * lane];
        unsigned v0 = *(const unsigned*)&e0u[(size_t)e0 * DF + 2 * lane];
        unsigned v1 = *(const unsigned*)&e0u[(size_t)e1 * DF + 2 * lane];
        unsigned v2 = *(const unsigned*)&e0u[(size_t)e2 * DF + 2 * lane];
        unsigned v3 = *(const unsigned*)&e0u[(size_t)e3 * DF + 2 * lane];
        agg_max(h0v, v0, m0, m1);
        agg_max(h1v, v1, m0, m1);
        agg_max(h2v, v2, m0, m1);
        agg_max(h3v, v3, m0, m1);
      }
      for (; j < batch; ++j) {
        int e = __shfl(myE, j, 64);
        int s = __shfl(myS, j, 64);
        unsigned hv = *(const unsigned*)&hVb[(size_t)s * DF + 2 * lane];
        unsigned ev = *(const unsigned*)&e0u[(size_t)e * DF + 2 * lane];
        agg_max(hv, ev, m0, m1);
      }
    }
    if (r1 == r0) { m0 = 0.f; m1 = 0.f; }
    size_t idx = (size_t)n * DF + 2 * lane;
    float2 hu = *(float2*)&hU[idx];
    float t0 = hu.x + m0, t1 = hu.y + m1;
    hu.x = t0; hu.y = t1;
    *(float2*)&hU[idx] = hu;
    ps0 += t0; ps1 += t1;
    pq0 += t0 * t0; pq1 += t1 * t1;
  }
  sr[0][tid] = ps0; sr[1][tid] = ps1; sr[2][tid] = pq0; sr[3][tid] = pq1;
  __syncthreads();
  if (tid < 64) {
    float a0 = 0.f, a1 = 0.f, b0 = 0.f, b1 = 0.f;
#pragma unroll
    for (int w = 0; w < 4; ++w) {
      a0 += sr[0][w * 64 + tid]; a1 += sr[1][w * 64 + tid];
      b0 += sr[2][w * 64 + tid]; b1 += sr[3][w * 64 + tid];
    }
    atomicAdd(&stat[2 * tid], a0);
    atomicAdd(&stat[2 * tid + 1], a1);
    atomicAdd(&stat[128 + 2 * tid], b0);
    atomicAdd(&stat[128 + 2 * tid + 1], b1);
  }
}

// finalize BN stats
__global__ void k_bn_finalize(float* __restrict__ stat, float nN, float nE) {
  int tid = threadIdx.x;
  if (tid < 128) {
    float mean = stat[tid] / nN;
    float var = stat[128 + tid] / nN - mean * mean;
    stat[256 + tid] = mean;
    stat[384 + tid] = rsqrtf(fmaxf(var, 0.f) + 1e-5f);
  } else {
    int d = tid - 128;
    float mean = stat[512 + d] / nE;
    float var = stat[640 + d] / nE - mean * mean;
    stat[768 + d] = mean;
    stat[896 + d] = rsqrtf(fmaxf(var, 0.f) + 1e-5f);
  }
}

__global__ __launch_bounds__(256) void k_node_update(
    float* __restrict__ h0, const float* __restrict__ hU,
    const float* __restrict__ stat, long long total) {
  long long i = (long long)blockIdx.x * blockDim.x + threadIdx.x;
  long long st = (long long)gridDim.x * blockDim.x;
  for (; i < total; i += st) {
    int d = (int)(i & 127);
    float t = (hU[i] - stat[256 + d]) * stat[384 + d];
    h0[i] += fmaxf(t, 0.f);
  }
}

// ---------------- GATv2 score (edge-major) ----------------
__global__ __launch_bounds__(256) void k_gat_score(
    const unsigned short* __restrict__ fsb, const unsigned short* __restrict__ fdb,
    const int* __restrict__ src, const int* __restrict__ dst,
    const float* __restrict__ attn, float* __restrict__ score, int Eg) {
  int g = blockIdx.x & 7, sub = blockIdx.x >> 3, nsub = gridDim.x >> 3;
  int gbase = g * Eg, gend = gbase + Eg;
  int tpg = (Eg + 127) >> 7;
  int tid = threadIdx.x;
  for (int t = sub; t < tpg; t += nsub) {
    int ebase = gbase + t * 128;
    for (int k = tid; k < 1024; k += 256) {
      int e = ebase + (k >> 3);
      if (e >= gend) break;
      int mh = k & 7;
      int s = src[e], dn = dst[e];
      const unsigned short* ps = fsb + (size_t)s * DF + mh * 16;
      const unsigned short* pd = fdb + (size_t)dn * DF + mh * 16;
      const float* pa = attn + mh * 16;
      bf16x8 s0 = *(const bf16x8*)ps;
      bf16x8 s1 = *(const bf16x8*)(ps + 8);
      bf16x8 d0 = *(const bf16x8*)pd;
      bf16x8 d1 = *(const bf16x8*)(pd + 8);
      float acc = 0.f;
#pragma unroll
      for (int kk = 0; kk < 8; ++kk) {
        float z = bf2f((unsigned short)s0[kk]) + bf2f((unsigned short)d0[kk]);
        z = (z > 0.f) ? z : 0.2f * z;
        acc = fmaf(z, pa[kk], acc);
        float z2 = bf2f((unsigned short)s1[kk]) + bf2f((unsigned short)d1[kk]);
        z2 = (z2 > 0.f) ? z2 : 0.2f * z2;
        acc = fmaf(z2, pa[kk + 8], acc);
      }
      score[(size_t)e * 8 + mh] = acc;
    }
  }
}

// ---------------- GATv2 node reduction (batched CSR, unrolled) ----------------
__global__ __launch_bounds__(256) void k_gat_node(
    const float* __restrict__ score, const unsigned short* __restrict__ fsb,
    const int* __restrict__ src, const unsigned* __restrict__ rowptr,
    const int* __restrict__ eidb, float* __restrict__ rst, int Ngr) {
  int tid = threadIdx.x, wid = tid >> 6, lane = tid & 63;
  int g = blockIdx.x & 7, sub = blockIdx.x >> 3, nsub = gridDim.x >> 3;
  int head = lane >> 3, slot = lane & 7;
  for (int nn = sub * 4 + wid; nn < Ngr; nn += nsub * 4) {
    int n = g * Ngr + nn;
    unsigned r0 = rowptr[n], r1 = rowptr[n + 1];
    float hm = -3.4e38f;
    for (unsigned rc = r0; rc < r1; rc += 64) {
      int batch = (int)min(64u, r1 - rc);
      int myE = eidb[rc + ((lane < batch) ? lane : 0)];
      for (int k = slot; k < batch; k += 8) {
        int e = __shfl(myE, k, 64);
        hm = fmaxf(hm, score[(size_t)e * 8 + head]);
      }
    }
#pragma unroll
    for (int mk = 1; mk < 8; mk <<= 1) hm = fmaxf(hm, __shfl_xor(hm, mk, 64));
    float dn = 0.f;
    for (unsigned rc = r0; rc < r1; rc += 64) {
      int batch = (int)min(64u, r1 - rc);
      int myE = eidb[rc + ((lane < batch) ? lane : 0)];
      for (int k = slot; k < batch; k += 8) {
        int e = __shfl(myE, k, 64);
        dn += __expf(score[(size_t)e * 8 + head] - hm);
      }
    }
#pragma unroll
    for (int mk = 1; mk < 8; mk <<= 1) dn += __shfl_xor(dn, mk, 64);
    float inv = (r1 > r0) ? 1.f / dn : 0.f;
    float a0 = 0.f, a1 = 0.f;
    for (unsigned rc = r0; rc < r1; rc += 64) {
      int batch = (int)min(64u, r1 - rc);
      int myE = eidb[rc + ((lane < batch) ? lane : 0)];
      int myS = src[myE];
      int j = 0;
      for (; j + 4 <= batch; j += 4) {
        int e0 = __shfl(myE, j, 64), e1 = __shfl(myE, j + 1, 64);
        int e2 = __shfl(myE, j + 2, 64), e3 = __shfl(myE, j + 3, 64);
        int s0 = __shfl(myS, j, 64), s1 = __shfl(myS, j + 1, 64);
        int s2 = __shfl(myS, j + 2, 64), s3 = __shfl(myS, j + 3, 64);
        float sc0 = score[(size_t)e0 * 8 + head];
        float sc1 = score[(size_t)e1 * 8 + head];
        float sc2 = score[(size_t)e2 * 8 + head];
        float sc3 = score[(size_t)e3 * 8 + head];
        unsigned f0 = *(const unsigned*)&fsb[(size_t)s0 * DF + 2 * lane];
        unsigned f1 = *(const unsigned*)&fsb[(size_t)s1 * DF + 2 * lane];
        unsigned f2 = *(const unsigned*)&fsb[(size_t)s2 * DF + 2 * lane];
        unsigned f3 = *(const unsigned*)&fsb[(size_t)s3 * DF + 2 * lane];
        float w0 = __expf(sc0 - hm) * inv, w1 = __expf(sc1 - hm) * inv;
        float w2 = __expf(sc2 - hm) * inv, w3 = __expf(sc3 - hm) * inv;
        a0 = fmaf(w0, bflo(f0), a0); a1 = fmaf(w0, bfhi(f0), a1);
        a0 = fmaf(w1, bflo(f1), a0); a1 = fmaf(w1, bfhi(f1), a1);
        a0 = fmaf(w2, bflo(f2), a0); a1 = fmaf(w2, bfhi(f2), a1);
        a0 = fmaf(w3, bflo(f3), a0); a1 = fmaf(w3, bfhi(f3), a1);
      }
      for (; j < batch; ++j) {
        int e = __shfl(myE, j, 64);
        int s = __shfl(myS, j, 64);
        float w = __expf(score[(size_t)e * 8 + head] - hm) * inv;
        unsigned fv = *(const unsigned*)&fsb[(size_t)s * DF + 2 * lane];
        a0 = fmaf(w, bflo(fv), a0);
        a1 = fmaf(w, bfhi(fv), a1);
      }
    }
    float2 o;
    o.x = a0; o.y = a1;
    *(float2*)&rst[(size_t)n * DF + 2 * lane] = o;
  }
}

// bias2 = O_b + gat_bias @ O_w^T
__global__ void k_bias2(const float* __restrict__ gat_bias,
                        const float* __restrict__ O_w,
                        const float* __restrict__ O_b, float* __restrict__ bias2) {
  int d = threadIdx.x;
  float acc = O_b[d];
  for (int k = 0; k < DF; ++k) acc = fmaf(gat_bias[k], O_w[(size_t)d * DF + k], acc);
  bias2[d] = acc;
}

// ---------------- readout ----------------
__global__ __launch_bounds__(128) void k_moy(
    const unsigned short* __restrict__ h2b, const int* __restrict__ ng,
    float* __restrict__ moy, float* __restrict__ cnt, int rows) {
  int tid = threadIdx.x;
  int per = (rows + gridDim.x - 1) / gridDim.x;
  int n0 = blockIdx.x * per;
  int n1 = min(rows, n0 + per);
  if (n0 >= n1) return;
  int cur = ng[n0];
  float acc = 0.f; int c = 0;
  for (int n = n0; n < n1; ++n) {
    int g = ng[n];
    if (g != cur) {
      atomicAdd(&moy[cur * DF + tid], acc);
      if (tid == 0) atomicAdd(&cnt[cur], (float)c);
      acc = 0.f; c = 0; cur = g;
    }
    acc += bf2f(h2b[(size_t)n * DF + tid]);
    ++c;
  }
  atomicAdd(&moy[cur * DF + tid], acc);
  if (tid == 0) atomicAdd(&cnt[cur], (float)c);
}

// P0[g] = W1[:,0:128] @ (moy_sum[g]/cnt[g]) + W1_b
__global__ void k_p0(const float* __restrict__ W1, const float* __restrict__ W1b_,
                     const float* __restrict__ moy, const float* __restrict__ cnt,
                     float* __restrict__ P0) {
  int g = blockIdx.x, d = threadIdx.x;
  float inv = 1.f / cnt[g];
  float acc = W1b_[d];
  for (int k = 0; k < DF; ++k) acc = fmaf(W1[(size_t)d * 384 + k], moy[g * DF + k] * inv, acc);
  P0[g * DF + d] = acc;
}

// ---------------- CSR head ----------------
__global__ __launch_bounds__(256) void k_head(
    const unsigned short* __restrict__ P1b, const unsigned short* __restrict__ P2b,
    const float* __restrict__ P0, const int* __restrict__ src,
    const unsigned* __restrict__ rowptr, const int* __restrict__ eidb,
    const float* __restrict__ W2, const float* __restrict__ W2b,
    float* __restrict__ out, int Ngr) {
  int tid = threadIdx.x, wid = tid >> 6, lane = tid & 63;
  int g = blockIdx.x & 7, sub = blockIdx.x >> 3, nsub = gridDim.x >> 3;
  float w2b = W2b[0];
  float w20 = W2[2 * lane], w21 = W2[2 * lane + 1];
  float b0 = P0[g * DF + 2 * lane], b1v = P0[g * DF + 2 * lane + 1];
  for (int nn = sub * 4 + wid; nn < Ngr; nn += nsub * 4) {
    int n = g * Ngr + nn;
    unsigned r0 = rowptr[n], r1 = rowptr[n + 1];
    if (r1 == r0) continue;
    unsigned p2 = *(const unsigned*)&P2b[(size_t)n * DF + 2 * lane];
    float base0 = b0 + bflo(p2);
    float base1 = b1v + bfhi(p2);
    for (unsigned rc = r0; rc < r1; rc += 64) {
      int cnt2 = (int)min(64u, r1 - rc);
      int myE = eidb[rc + ((lane < cnt2) ? lane : 0)];
      int myS = src[myE];
      int j = 0;
      for (; j + 4 <= cnt2; j += 4) {
        int e0 = __shfl(myE, j, 64), e1 = __shfl(myE, j + 1, 64);
        int e2 = __shfl(myE, j + 2, 64), e3 = __shfl(myE, j + 3, 64);
        int s0 = __shfl(myS, j, 64), s1 = __shfl(myS, j + 1, 64);
        int s2 = __shfl(myS, j + 2, 64), s3 = __shfl(myS, j + 3, 64);
        unsigned u0 = *(const unsigned*)&P1b[(size_t)s0 * DF + 2 * lane];
        unsigned u1 = *(const unsigned*)&P1b[(size_t)s1 * DF + 2 * lane];
        unsigned u2 = *(const unsigned*)&P1b[(size_t)s2 * DF + 2 * lane];
        unsigned u3 = *(const unsigned*)&P1b[(size_t)s3 * DF + 2 * lane];
        float v0 = fmaxf(base0 + bflo(u0), 0.f) * w20 + fmaxf(base1 + bfhi(u0), 0.f) * w21;
        float v1 = fmaxf(base0 + bflo(u1), 0.f) * w20 + fmaxf(base1 + bfhi(u1), 0.f) * w21;
        float v2 = fmaxf(base0 + bflo(u2), 0.f) * w20 + fmaxf(base1 + bfhi(u2), 0.f) * w21;
        float v3 = fmaxf(base0 + bflo(u3), 0.f) * w20 + fmaxf(base1 + bfhi(u3), 0.f) * w21;
#pragma unroll
        for (int mk = 1; mk < 64; mk <<= 1) {
          v0 += __shfl_xor(v0, mk, 64);
          v1 += __shfl_xor(v1, mk, 64);
          v2 += __shfl_xor(v2, mk, 64);
          v3 += __shfl_xor(v3, mk, 64);
        }
        if (lane == 0) {
          out[e0] = sigm(v0 + w2b);
          out[e1] = sigm(v1 + w2b);
          out[e2] = sigm(v2 + w2b);
          out[e3] = sigm(v3 + w2b);
        }
      }
      for (; j < cnt2; ++j) {
        int e = __shfl(myE, j, 64);
        int s = __shfl(myS, j, 64);
        unsigned p1 = *(const unsigned*)&P1b[(size_t)s * DF + 2 * lane];
        float v = fmaxf(base0 + bflo(p1), 0.f) * w20 + fmaxf(base1 + bfhi(p1), 0.f) * w21;
#pragma unroll
        for (int mk = 1; mk < 64; mk <<= 1) v += __shfl_xor(v, mk, 64);
        if (lane == 0) out[e] = sigm(v + w2b);
      }
    }
  }
}

extern "C" void kernel_launch(void* const* d_in, const int* in_sizes, int n_in,
                              void* d_out, int out_size, void* d_ws, size_t ws_size,
                              hipStream_t stream) {
  const float* h_in = (const float*)d_in[0];
  const float* e_in = (const float*)d_in[1];
  const int* src = (const int*)d_in[2];
  const int* dst = (const int*)d_in[3];
  const int* node_graph = (const int*)d_in[4];
  const float* emb_n_w = (const float*)d_in[6];
  const float* emb_n_b = (const float*)d_in[7];
  const float* emb_e_w = (const float*)d_in[8];
  const float* emb_e_b = (const float*)d_in[9];
  const float* Us = (const float*)d_in[10];
  const float* Vs = (const float*)d_in[11];
  const float* As = (const float*)d_in[12];
  const float* Bs = (const float*)d_in[13];
  const float* Cs = (const float*)d_in[14];
  const float* gat_src_w = (const float*)d_in[15];
  const float* gat_src_b = (const float*)d_in[16];
  const float* gat_dst_w = (const float*)d_in[17];
  const float* gat_dst_b = (const float*)d_in[18];
  const float* gat_attn = (const float*)d_in[19];
  const float* gat_bias = (const float*)d_in[20];
  const float* O_w = (const float*)d_in[21];
  const float* O_b = (const float*)d_in[22];
  const float* W1_w = (const float*)d_in[23];
  const float* W1_b = (const float*)d_in[24];
  const float* W2_w = (const float*)d_in[25];
  const float* W2_b = (const float*)d_in[26];
  float* out = (float*)d_out;

  const int N = in_sizes[0] / 64;   // 30000
  const int E = in_sizes[1] / 16;   // 360000
  const int Eg = E / NGRAPH;        // 45000
  const int Ngr = N / NGRAPH;       // 3750

  auto rnd = [](size_t b) { return (b + 255) & ~(size_t)255; };
  const size_t sz_e0 = rnd((size_t)E * DF * 2);
  const size_t sz_node = rnd((size_t)N * DF * 4);
  const size_t sz_nodeb = rnd((size_t)N * DF * 2);
  const size_t sz_score = rnd((size_t)E * 8 * 4);
  const size_t sz_wfrag = rnd(20 * 2048 * 8 * 2);
  const size_t sz_rp = rnd((size_t)(N + 1) * 4);
  const size_t sz_eid = rnd((size_t)E * 4);
  const size_t sz_misc = rnd(4096 * 4);
  const size_t needed = sz_e0 + 3 * sz_node + 4 * sz_nodeb + sz_score + sz_wfrag +
                        3 * sz_rp + sz_eid + sz_misc;
  if (ws_size < needed) {
    k_fill_u32<<<256, 256, 0, stream>>>((unsigned*)out, 0xBF800000u, (long long)out_size);
    return;
  }

  char* wp = (char*)d_ws;
  auto alloc = [&](size_t bytes) { void* p = wp; wp += bytes; return p; };
  unsigned short* e0u = (unsigned short*)alloc(sz_e0);
  float* h0 = (float*)alloc(sz_node);
  float* hU = (float*)alloc(sz_node);
  float* rst = (float*)alloc(sz_node);
  unsigned short* hVb = (unsigned short*)alloc(sz_nodeb);
  unsigned short* hBb = (unsigned short*)alloc(sz_nodeb);
  unsigned short* hCb = (unsigned short*)alloc(sz_nodeb);
  unsigned short* h2b = (unsigned short*)alloc(sz_nodeb);
  float* score = (float*)alloc(sz_score);
  short* wfrag = (short*)alloc(sz_wfrag);
  unsigned* rowptr = (unsigned*)alloc(sz_rp);
  unsigned* cursor = (unsigned*)alloc(sz_rp);
  unsigned* deg = (unsigned*)alloc(sz_rp);
  int* eidb = (int*)alloc(sz_eid);
  float* misc = (float*)alloc(sz_misc);
  float* stat = misc;                                     // [0,1024)
  float* bias2 = misc + 1024;                             // [1024,1152)
  float* moy = misc + 1152;                               // [1152,2176)
  float* cnt = misc + 2176;                               // [2176,2184)
  float* P0 = misc + 2304;                                // [2304,3328)
  unsigned short* P1b = e0u;  // alias: e0u dead after last layer
  unsigned short* P2b = e0u + (size_t)N * DF;

  auto WF = [&](int idx) { return wfrag + (size_t)idx * 2048 * 8; };

  // CSR build (dst lists; reused by layers + GAT + head)
  k_fill_u32<<<64, 256, 0, stream>>>(deg, 0u, N);
  k_deg<<<512, 256, 0, stream>>>(dst, deg, E);
  k_scan<<<1, 1024, 0, stream>>>(deg, rowptr, cursor, N);
  k_scatter<<<512, 256, 0, stream>>>(dst, cursor, eidb, E);

  k_wconv<<<20, 512, 0, stream>>>(Us, Vs, As, Bs, Cs, gat_src_w, gat_dst_w, O_w,
                                  W1_w, wfrag);

  const int gN = (N + 127) / 128;
  k_node_embed<<<2048, 128, 0, stream>>>(h_in, emb_n_w, emb_n_b, h0, N);
  k_edge_embed<<<4096, 128, 0, stream>>>(e_in, emb_e_w, emb_e_b, e0u, E);

  for (int l = 0; l < 3; ++l) {
    k_gemm4_mfma<<<gN, 512, 0, stream>>>(h0, WF(3 + l), WF(l), WF(9 + l), WF(12 + l),
                                         hVb, hU, hBb, hCb, N);
    k_fill_u32<<<4, 256, 0, stream>>>((unsigned*)stat, 0u, 1024);
    k_node_agg<<<2048, 256, 0, stream>>>(hU, hVb, e0u, src, rowptr, eidb, stat, Ngr);
    k_edge_xs<<<1024, 512, 0, stream>>>(e0u, WF(6 + l), hBb, hCb, src, dst, stat, Eg);
    k_bn_finalize<<<1, 256, 0, stream>>>(stat, (float)N, (float)E);
    k_node_update<<<2048, 256, 0, stream>>>(h0, hU, stat, (long long)N * DF);
    k_edge_xa<<<1024, 512, 0, stream>>>(e0u, WF(6 + l), hBb, hCb, src, dst, stat, Eg);
  }

  // GATv2: fs -> hVb, fd -> hBb
  k_gemm_mfma<1><<<gN, 512, 0, stream>>>(h0, WF(15), gat_src_b, hVb, N);
  k_gemm_mfma<1><<<gN, 512, 0, stream>>>(h0, WF(16), gat_dst_b, hBb, N);
  k_gat_score<<<512, 256, 0, stream>>>(hVb, hBb, src, dst, gat_attn, score, Eg);
  k_gat_node<<<2048, 256, 0, stream>>>(score, hVb, src, rowptr, eidb, rst, Ngr);
  k_bias2<<<1, 128, 0, stream>>>(gat_bias, O_w, O_b, bias2);
  k_gemm_mfma<1><<<gN, 512, 0, stream>>>(rst, WF(17), bias2, h2b, N);  // h2

  // readout + decomposed head
  k_fill_u32<<<2, 256, 0, stream>>>((unsigned*)moy, 0u, 1032);
  k_moy<<<128, 128, 0, stream>>>(h2b, node_graph, moy, cnt, N);
  k_p0<<<8, 128, 0, stream>>>(W1_w, W1_b, moy, cnt, P0);
  k_gemmb_mfma<<<gN, 512, 0, stream>>>(h2b, WF(18), P1b, N);
  k_gemmb_mfma<<<gN, 512, 0, stream>>>(h2b, WF(19), P2b, N);
  k_head<<<2048, 256, 0, stream>>>(P1b, P2b, P0, src, rowptr, eidb, W2_w, W2_b,
                                   out, Ngr);
}

// Round 13
// 1388.975 us; speedup vs baseline: 1.8487x; 1.0604x over previous
//
#include <hip/hip_runtime.h>

#define DF 128
#define NGRAPH 8

typedef __attribute__((ext_vector_type(8))) short bf16x8;
typedef __attribute__((ext_vector_type(4))) float f32x4;

__device__ __forceinline__ float sigm(float x) { return 1.f / (1.f + __expf(-x)); }
__device__ __forceinline__ unsigned short f2bf(float f) {  // RNE f32->bf16
  unsigned u = __float_as_uint(f);
  u += 0x7FFFu + ((u >> 16) & 1u);
  return (unsigned short)(u >> 16);
}
__device__ __forceinline__ float bf2f(unsigned short u) {
  return __uint_as_float(((unsigned)u) << 16);
}
__device__ __forceinline__ float bflo(unsigned u) { return __uint_as_float(u << 16); }
__device__ __forceinline__ float bfhi(unsigned u) { return __uint_as_float(u & 0xffff0000u); }

// load 8 consecutive f32 (32B-aligned) -> bf16x8
__device__ __forceinline__ bf16x8 cvt8(const float* __restrict__ p) {
  float4 a = *(const float4*)p;
  float4 b = *(const float4*)(p + 4);
  bf16x8 r;
  r[0] = (short)f2bf(a.x); r[1] = (short)f2bf(a.y);
  r[2] = (short)f2bf(a.z); r[3] = (short)f2bf(a.w);
  r[4] = (short)f2bf(b.x); r[5] = (short)f2bf(b.y);
  r[6] = (short)f2bf(b.z); r[7] = (short)f2bf(b.w);
  return r;
}

__device__ __forceinline__ void agg_max(unsigned hv, unsigned ev, float& m0, float& m1) {
  m0 = fmaxf(m0, bflo(hv) * sigm(bflo(ev)));
  m1 = fmaxf(m1, bfhi(hv) * sigm(bfhi(ev)));
}

// ---------------- generic fill ----------------
__global__ void k_fill_u32(unsigned* __restrict__ p, unsigned v, long long n) {
  long long i = (long long)blockIdx.x * blockDim.x + threadIdx.x;
  long long st = (long long)gridDim.x * blockDim.x;
  for (; i < n; i += st) p[i] = v;
}

// ---------------- CSR build (dst-sorted edge lists) ----------------
__global__ void k_deg(const int* __restrict__ dst, unsigned* __restrict__ deg, int E) {
  int i = blockIdx.x * blockDim.x + threadIdx.x;
  int st = gridDim.x * blockDim.x;
  for (; i < E; i += st) atomicAdd(&deg[dst[i]], 1u);
}

__global__ __launch_bounds__(1024) void k_scan(
    const unsigned* __restrict__ deg, unsigned* __restrict__ rowptr,
    unsigned* __restrict__ cursor, int N) {
  __shared__ unsigned part[1024];
  int t = threadIdx.x;
  int per = (N + 1023) >> 10;
  int s0 = t * per, s1 = min(N, s0 + per);
  unsigned s = 0;
  for (int i = s0; i < s1; ++i) s += deg[i];
  part[t] = s;
  __syncthreads();
  for (int off = 1; off < 1024; off <<= 1) {
    unsigned v = (t >= off) ? part[t - off] : 0u;
    __syncthreads();
    part[t] += v;
    __syncthreads();
  }
  unsigned base = (t == 0) ? 0u : part[t - 1];
  for (int i = s0; i < s1; ++i) {
    rowptr[i] = base;
    cursor[i] = base;
    base += deg[i];
  }
  if (t == 1023) rowptr[N] = part[1023];
}

__global__ void k_scatter(const int* __restrict__ dst, unsigned* __restrict__ cursor,
                          int* __restrict__ eidb, int E) {
  int i = blockIdx.x * blockDim.x + threadIdx.x;
  int st = gridDim.x * blockDim.x;
  for (; i < E; i += st) {
    unsigned p = atomicAdd(&cursor[dst[i]], 1u);
    eidb[p] = i;
  }
}

// srcP[r] = src[eidb[r]], dstP[r] = dst[eidb[r]]
__global__ void k_permidx(const int* __restrict__ eidb, const int* __restrict__ src,
                          const int* __restrict__ dst, int* __restrict__ srcP,
                          int* __restrict__ dstP, int E) {
  int i = blockIdx.x * blockDim.x + threadIdx.x;
  int st = gridDim.x * blockDim.x;
  for (; i < E; i += st) {
    int e = eidb[i];
    srcP[i] = src[e];
    dstP[i] = dst[e];
  }
}

// ---------------- weight pre-conversion to MFMA fragment order ----------------
// 0-2 U, 3-5 V, 6-8 A, 9-11 B, 12-14 C, 15 gsw, 16 gdw, 17 Ow, 18 W1[:,128:256], 19 W1[:,256:384]
__global__ __launch_bounds__(512) void k_wconv(
    const float* __restrict__ Us, const float* __restrict__ Vs,
    const float* __restrict__ As, const float* __restrict__ Bs,
    const float* __restrict__ Cs, const float* __restrict__ gsw,
    const float* __restrict__ gdw, const float* __restrict__ Ow,
    const float* __restrict__ W1, short* __restrict__ out) {
  int b = blockIdx.x;
  const float* W;
  int ldw = DF;
  if (b < 3) W = Us + b * 16384;
  else if (b < 6) W = Vs + (b - 3) * 16384;
  else if (b < 9) W = As + (b - 6) * 16384;
  else if (b < 12) W = Bs + (b - 9) * 16384;
  else if (b < 15) W = Cs + (b - 12) * 16384;
  else if (b == 15) W = gsw;
  else if (b == 16) W = gdw;
  else if (b == 17) W = Ow;
  else if (b == 18) { W = W1 + 128; ldw = 384; }
  else { W = W1 + 256; ldw = 384; }
  short* o = out + (size_t)b * 2048 * 8;
  for (int s = threadIdx.x; s < 2048; s += 512) {
    int ct = s >> 8, ks = (s >> 6) & 3, l = s & 63;
    int row = ct * 16 + (l & 15), k0 = ks * 32 + (l >> 4) * 8;
    *(bf16x8*)&o[s * 8] = cvt8(W + (size_t)row * ldw + k0);
  }
}

// ---------------- embeddings ----------------
__global__ __launch_bounds__(128) void k_node_embed(
    const float* __restrict__ hin, const float* __restrict__ w,
    const float* __restrict__ b, float* __restrict__ h0, int rows) {
  __shared__ float Wt[64 * DF];
  __shared__ float ar[4][64];
  int tid = threadIdx.x;
  for (int i = tid; i < 64 * DF; i += 128) Wt[(i & 63) * DF + (i >> 6)] = w[i];
  float bb = b[tid];
  __syncthreads();
  for (int r0 = blockIdx.x * 4; r0 < rows; r0 += gridDim.x * 4) {
    for (int i = tid; i < 256; i += 128) ar[i >> 6][i & 63] = hin[(size_t)r0 * 64 + i];
    __syncthreads();
    float a0 = bb, a1 = bb, a2 = bb, a3 = bb;
#pragma unroll 8
    for (int k = 0; k < 64; ++k) {
      float wv = Wt[k * DF + tid];
      a0 = fmaf(ar[0][k], wv, a0); a1 = fmaf(ar[1][k], wv, a1);
      a2 = fmaf(ar[2][k], wv, a2); a3 = fmaf(ar[3][k], wv, a3);
    }
    h0[(size_t)r0 * DF + tid] = a0;
    h0[(size_t)(r0 + 1) * DF + tid] = a1;
    h0[(size_t)(r0 + 2) * DF + tid] = a2;
    h0[(size_t)(r0 + 3) * DF + tid] = a3;
    __syncthreads();
  }
}

// permuted edge embed: slot r holds edge eidb[r]
__global__ __launch_bounds__(128) void k_edge_embed(
    const float* __restrict__ ein, const int* __restrict__ eidb,
    const float* __restrict__ w, const float* __restrict__ b,
    unsigned short* __restrict__ e0u, int rows) {
  __shared__ float Wt[16 * DF];
  __shared__ float ar[4][16];
  int tid = threadIdx.x;
  for (int i = tid; i < 16 * DF; i += 128) Wt[(i & 15) * DF + (i >> 4)] = w[i];
  float bb = b[tid];
  __syncthreads();
  for (int r0 = blockIdx.x * 4; r0 < rows; r0 += gridDim.x * 4) {
    if (tid < 64) {
      int e = eidb[r0 + (tid >> 4)];
      ar[tid >> 4][tid & 15] = ein[(size_t)e * 16 + (tid & 15)];
    }
    __syncthreads();
    float a0 = bb, a1 = bb, a2 = bb, a3 = bb;
#pragma unroll
    for (int k = 0; k < 16; ++k) {
      float wv = Wt[k * DF + tid];
      a0 = fmaf(ar[0][k], wv, a0); a1 = fmaf(ar[1][k], wv, a1);
      a2 = fmaf(ar[2][k], wv, a2); a3 = fmaf(ar[3][k], wv, a3);
    }
    e0u[(size_t)r0 * DF + tid] = f2bf(a0);
    e0u[(size_t)(r0 + 1) * DF + tid] = f2bf(a1);
    e0u[(size_t)(r0 + 2) * DF + tid] = f2bf(a2);
    e0u[(size_t)(r0 + 3) * DF + tid] = f2bf(a3);
    __syncthreads();
  }
}

// ---------------- MFMA [rows,128] @ W^T (+bias), frag weights, f32 input ----------------
template <int OUTBF>
__global__ __launch_bounds__(512) void k_gemm_mfma(
    const float* __restrict__ A, const short* __restrict__ Wf,
    const float* __restrict__ bias, void* __restrict__ outv, int rows) {
  __shared__ short Wb[2048 * 8];  // 32 KB
  int tid = threadIdx.x;
  for (int s = tid; s < 2048; s += 512)
    *(bf16x8*)&Wb[s * 8] = *(const bf16x8*)&Wf[(size_t)s * 8];
  __syncthreads();
  float* outf = (float*)outv;
  unsigned short* outb = (unsigned short*)outv;
  int wid = tid >> 6, lane = tid & 63, q = lane >> 4, m = lane & 15;
  int ntiles = (rows + 127) >> 7;
  for (int t = blockIdx.x; t < ntiles; t += gridDim.x) {
    int r0 = t * 128 + wid * 16;
    int rr = r0 + m;
    if (rr >= rows) rr = rows - 1;
    const float* ap = A + (size_t)rr * DF + q * 8;
    bf16x8 a[4];
#pragma unroll
    for (int ks = 0; ks < 4; ++ks) a[ks] = cvt8(ap + 32 * ks);
#pragma unroll
    for (int ct = 0; ct < 8; ++ct) {
      f32x4 acc = {0.f, 0.f, 0.f, 0.f};
#pragma unroll
      for (int ks = 0; ks < 4; ++ks) {
        bf16x8 b = *(const bf16x8*)&Wb[((ct * 4 + ks) * 64 + lane) * 8];
        acc = __builtin_amdgcn_mfma_f32_16x16x32_bf16(a[ks], b, acc, 0, 0, 0);
      }
      int col = ct * 16 + m;
      float bb = bias ? bias[col] : 0.f;
#pragma unroll
      for (int j = 0; j < 4; ++j) {
        int row = r0 + q * 4 + j;
        if (row < rows) {
          if (OUTBF) outb[(size_t)row * DF + col] = f2bf(acc[j] + bb);
          else outf[(size_t)row * DF + col] = acc[j] + bb;
        }
      }
    }
  }
}

// same, bf16 input
__global__ __launch_bounds__(512) void k_gemmb_mfma(
    const unsigned short* __restrict__ A, const short* __restrict__ Wf,
    unsigned short* __restrict__ outb, int rows) {
  __shared__ short Wb[2048 * 8];
  int tid = threadIdx.x;
  for (int s = tid; s < 2048; s += 512)
    *(bf16x8*)&Wb[s * 8] = *(const bf16x8*)&Wf[(size_t)s * 8];
  __syncthreads();
  int wid = tid >> 6, lane = tid & 63, q = lane >> 4, m = lane & 15;
  int ntiles = (rows + 127) >> 7;
  for (int t = blockIdx.x; t < ntiles; t += gridDim.x) {
    int r0 = t * 128 + wid * 16;
    int rr = r0 + m;
    if (rr >= rows) rr = rows - 1;
    const unsigned short* ap = A + (size_t)rr * DF + q * 8;
    bf16x8 a[4];
#pragma unroll
    for (int ks = 0; ks < 4; ++ks) a[ks] = *(const bf16x8*)(ap + 32 * ks);
#pragma unroll
    for (int ct = 0; ct < 8; ++ct) {
      f32x4 acc = {0.f, 0.f, 0.f, 0.f};
#pragma unroll
      for (int ks = 0; ks < 4; ++ks) {
        bf16x8 b = *(const bf16x8*)&Wb[((ct * 4 + ks) * 64 + lane) * 8];
        acc = __builtin_amdgcn_mfma_f32_16x16x32_bf16(a[ks], b, acc, 0, 0, 0);
      }
      int col = ct * 16 + m;
#pragma unroll
      for (int j = 0; j < 4; ++j) {
        int row = r0 + q * 4 + j;
        if (row < rows) outb[(size_t)row * DF + col] = f2bf(acc[j]);
      }
    }
  }
}

// ---------------- fused 4-output node GEMM (V,U,B,C) ----------------
__global__ __launch_bounds__(512) void k_gemm4_mfma(
    const float* __restrict__ h0, const short* __restrict__ Vf,
    const short* __restrict__ Uf, const short* __restrict__ Bf,
    const short* __restrict__ Cf, unsigned short* __restrict__ hVb,
    float* __restrict__ hU, unsigned short* __restrict__ hBb,
    unsigned short* __restrict__ hCb, int rows) {
  __shared__ short Wl[4 * 2048 * 8];  // 128 KB
  int tid = threadIdx.x;
  for (int s = tid; s < 2048; s += 512) {
    *(bf16x8*)&Wl[(size_t)s * 8] = *(const bf16x8*)&Vf[(size_t)s * 8];
    *(bf16x8*)&Wl[(size_t)(2048 + s) * 8] = *(const bf16x8*)&Uf[(size_t)s * 8];
    *(bf16x8*)&Wl[(size_t)(4096 + s) * 8] = *(const bf16x8*)&Bf[(size_t)s * 8];
    *(bf16x8*)&Wl[(size_t)(6144 + s) * 8] = *(const bf16x8*)&Cf[(size_t)s * 8];
  }
  __syncthreads();
  int wid = tid >> 6, lane = tid & 63, q = lane >> 4, m = lane & 15;
  int ntiles = (rows + 127) >> 7;
  for (int t = blockIdx.x; t < ntiles; t += gridDim.x) {
    int r0 = t * 128 + wid * 16;
    int rr = r0 + m;
    if (rr >= rows) rr = rows - 1;
    const float* ap = h0 + (size_t)rr * DF + q * 8;
    bf16x8 a[4];
#pragma unroll
    for (int ks = 0; ks < 4; ++ks) a[ks] = cvt8(ap + 32 * ks);
#pragma unroll
    for (int w = 0; w < 4; ++w) {
#pragma unroll
      for (int ct = 0; ct < 8; ++ct) {
        f32x4 acc = {0.f, 0.f, 0.f, 0.f};
#pragma unroll
        for (int ks = 0; ks < 4; ++ks) {
          bf16x8 b = *(const bf16x8*)&Wl[((w * 2048) + (ct * 4 + ks) * 64 + lane) * 8];
          acc = __builtin_amdgcn_mfma_f32_16x16x32_bf16(a[ks], b, acc, 0, 0, 0);
        }
        int col = ct * 16 + m;
#pragma unroll
        for (int j = 0; j < 4; ++j) {
          int row = r0 + q * 4 + j;
          if (row < rows) {
            if (w == 1) hU[(size_t)row * DF + col] = acc[j];
            else {
              unsigned short v = f2bf(acc[j]);
              unsigned short* o = (w == 0) ? hVb : ((w == 2) ? hBb : hCb);
              o[(size_t)row * DF + col] = v;
            }
          }
        }
      }
    }
  }
}

// ======== barrier-free swapped edge passes (mfma(W, e): lane owns ONE edge) ========
#define EDGE_MFMA_BODY                                                                 \
  const unsigned short* ep = e0u + (size_t)ec * DF + q * 8;                            \
  bf16x8 bv0 = *(const bf16x8*)(ep);                                                   \
  bf16x8 bv1 = *(const bf16x8*)(ep + 32);                                              \
  bf16x8 bv2 = *(const bf16x8*)(ep + 64);                                              \
  bf16x8 bv3 = *(const bf16x8*)(ep + 96);                                              \
  f32x4 c0 = {0.f, 0.f, 0.f, 0.f}, c1 = c0, c2 = c0, c3 = c0;                          \
  f32x4 c4 = c0, c5 = c0, c6 = c0, c7 = c0;                                            \
  _Pragma("unroll") for (int ks = 0; ks < 4; ++ks) {                                   \
    bf16x8 bv = (ks == 0) ? bv0 : (ks == 1) ? bv1 : (ks == 2) ? bv2 : bv3;             \
    c0 = __builtin_amdgcn_mfma_f32_16x16x32_bf16(*(const bf16x8*)&Wb[((0 * 4 + ks) * 64 + lane) * 8], bv, c0, 0, 0, 0); \
    c1 = __builtin_amdgcn_mfma_f32_16x16x32_bf16(*(const bf16x8*)&Wb[((1 * 4 + ks) * 64 + lane) * 8], bv, c1, 0, 0, 0); \
    c2 = __builtin_amdgcn_mfma_f32_16x16x32_bf16(*(const bf16x8*)&Wb[((2 * 4 + ks) * 64 + lane) * 8], bv, c2, 0, 0, 0); \
    c3 = __builtin_amdgcn_mfma_f32_16x16x32_bf16(*(const bf16x8*)&Wb[((3 * 4 + ks) * 64 + lane) * 8], bv, c3, 0, 0, 0); \
    c4 = __builtin_amdgcn_mfma_f32_16x16x32_bf16(*(const bf16x8*)&Wb[((4 * 4 + ks) * 64 + lane) * 8], bv, c4, 0, 0, 0); \
    c5 = __builtin_amdgcn_mfma_f32_16x16x32_bf16(*(const bf16x8*)&Wb[((5 * 4 + ks) * 64 + lane) * 8], bv, c5, 0, 0, 0); \
    c6 = __builtin_amdgcn_mfma_f32_16x16x32_bf16(*(const bf16x8*)&Wb[((6 * 4 + ks) * 64 + lane) * 8], bv, c6, 0, 0, 0); \
    c7 = __builtin_amdgcn_mfma_f32_16x16x32_bf16(*(const bf16x8*)&Wb[((7 * 4 + ks) * 64 + lane) * 8], bv, c7, 0, 0, 0); \
  }

// stats pass
__global__ __launch_bounds__(512) void k_edge_xs(
    const unsigned short* __restrict__ e0u, const short* __restrict__ Af,
    const unsigned short* __restrict__ hBb, const unsigned short* __restrict__ hCb,
    const int* __restrict__ srcP, const int* __restrict__ dstP,
    float* __restrict__ stat, int Eg) {
  __shared__ short Wb[2048 * 8];  // 32 KB
  __shared__ float ls[256];
  int tid = threadIdx.x;
  for (int s = tid; s < 2048; s += 512)
    *(bf16x8*)&Wb[s * 8] = *(const bf16x8*)&Af[(size_t)s * 8];
  if (tid < 256) ls[tid] = 0.f;
  int wid = tid >> 6, lane = tid & 63, q = lane >> 4, m = lane & 15;
  int g = blockIdx.x & 7, sub = blockIdx.x >> 3, nsub = gridDim.x >> 3;
  int gbase = g * Eg, gend = gbase + Eg;
  int tpg = (Eg + 127) >> 7;
  float ps[32], pq[32];
#pragma unroll
  for (int i = 0; i < 32; ++i) { ps[i] = 0.f; pq[i] = 0.f; }
  __syncthreads();
  for (int t = sub; t < tpg; t += nsub) {
    int r0 = gbase + t * 128 + wid * 16;
    int edge = r0 + m;
    bool ok = edge < gend;
    int ec = ok ? edge : gend - 1;
    EDGE_MFMA_BODY
    if (ok) {
      int sidx = srcP[ec], didx = dstP[ec];
      const unsigned short* pb = hBb + (size_t)didx * DF + q * 4;
      const unsigned short* pc = hCb + (size_t)sidx * DF + q * 4;
#pragma unroll
      for (int ct = 0; ct < 8; ++ct) {
        f32x4 cc = (ct == 0) ? c0 : (ct == 1) ? c1 : (ct == 2) ? c2 : (ct == 3) ? c3
                   : (ct == 4) ? c4 : (ct == 5) ? c5 : (ct == 6) ? c6 : c7;
        ushort4 hb = *(const ushort4*)(pb + ct * 16);
        ushort4 hc = *(const ushort4*)(pc + ct * 16);
        float x0 = cc[0] + bf2f(hb.x) + bf2f(hc.x);
        float x1 = cc[1] + bf2f(hb.y) + bf2f(hc.y);
        float x2 = cc[2] + bf2f(hb.z) + bf2f(hc.z);
        float x3 = cc[3] + bf2f(hb.w) + bf2f(hc.w);
        ps[ct * 4 + 0] += x0; pq[ct * 4 + 0] += x0 * x0;
        ps[ct * 4 + 1] += x1; pq[ct * 4 + 1] += x1 * x1;
        ps[ct * 4 + 2] += x2; pq[ct * 4 + 2] += x2 * x2;
        ps[ct * 4 + 3] += x3; pq[ct * 4 + 3] += x3 * x3;
      }
    }
  }
#pragma unroll
  for (int i = 0; i < 32; ++i) {
    float s = ps[i], sq = pq[i];
    s += __shfl_xor(s, 1, 64); sq += __shfl_xor(sq, 1, 64);
    s += __shfl_xor(s, 2, 64); sq += __shfl_xor(sq, 2, 64);
    s += __shfl_xor(s, 4, 64); sq += __shfl_xor(sq, 4, 64);
    s += __shfl_xor(s, 8, 64); sq += __shfl_xor(sq, 8, 64);
    if (m == 0) {
      int feat = (i >> 2) * 16 + q * 4 + (i & 3);
      atomicAdd(&ls[feat], s);
      atomicAdd(&ls[128 + feat], sq);
    }
  }
  __syncthreads();
  if (tid < 128) {
    atomicAdd(&stat[512 + tid], ls[tid]);
    atomicAdd(&stat[640 + tid], ls[128 + tid]);
  }
}

// apply pass
__global__ __launch_bounds__(512) void k_edge_xa(
    unsigned short* __restrict__ e0u, const short* __restrict__ Af,
    const unsigned short* __restrict__ hBb, const unsigned short* __restrict__ hCb,
    const int* __restrict__ srcP, const int* __restrict__ dstP,
    const float* __restrict__ stat, int Eg) {
  __shared__ short Wb[2048 * 8];  // 32 KB
  int tid = threadIdx.x;
  for (int s = tid; s < 2048; s += 512)
    *(bf16x8*)&Wb[s * 8] = *(const bf16x8*)&Af[(size_t)s * 8];
  int wid = tid >> 6, lane = tid & 63, q = lane >> 4, m = lane & 15;
  float mm[32], iv[32];
#pragma unroll
  for (int ct = 0; ct < 8; ++ct)
#pragma unroll
    for (int j = 0; j < 4; ++j) {
      int f = ct * 16 + q * 4 + j;
      mm[ct * 4 + j] = stat[768 + f];
      iv[ct * 4 + j] = stat[896 + f];
    }
  int g = blockIdx.x & 7, sub = blockIdx.x >> 3, nsub = gridDim.x >> 3;
  int gbase = g * Eg, gend = gbase + Eg;
  int tpg = (Eg + 127) >> 7;
  __syncthreads();
  for (int t = sub; t < tpg; t += nsub) {
    int r0 = gbase + t * 128 + wid * 16;
    int edge = r0 + m;
    bool ok = edge < gend;
    int ec = ok ? edge : gend - 1;
    EDGE_MFMA_BODY
    if (ok) {
      int sidx = srcP[ec], didx = dstP[ec];
      const unsigned short* pb = hBb + (size_t)didx * DF + q * 4;
      const unsigned short* pc = hCb + (size_t)sidx * DF + q * 4;
      unsigned short* pe = e0u + (size_t)ec * DF + q * 4;
#pragma unroll
      for (int ct = 0; ct < 8; ++ct) {
        f32x4 cc = (ct == 0) ? c0 : (ct == 1) ? c1 : (ct == 2) ? c2 : (ct == 3) ? c3
                   : (ct == 4) ? c4 : (ct == 5) ? c5 : (ct == 6) ? c6 : c7;
        ushort4 hb = *(const ushort4*)(pb + ct * 16);
        ushort4 hc = *(const ushort4*)(pc + ct * 16);
        ushort4 eo = *(const ushort4*)(pe + ct * 16);
        float x0 = cc[0] + bf2f(hb.x) + bf2f(hc.x);
        float x1 = cc[1] + bf2f(hb.y) + bf2f(hc.y);
        float x2 = cc[2] + bf2f(hb.z) + bf2f(hc.z);
        float x3 = cc[3] + bf2f(hb.w) + bf2f(hc.w);
        ushort4 nv;
        nv.x = f2bf(bf2f(eo.x) + fmaxf((x0 - mm[ct * 4 + 0]) * iv[ct * 4 + 0], 0.f));
        nv.y = f2bf(bf2f(eo.y) + fmaxf((x1 - mm[ct * 4 + 1]) * iv[ct * 4 + 1], 0.f));
        nv.z = f2bf(bf2f(eo.z) + fmaxf((x2 - mm[ct * 4 + 2]) * iv[ct * 4 + 2], 0.f));
        nv.w = f2bf(bf2f(eo.w) + fmaxf((x3 - mm[ct * 4 + 3]) * iv[ct * 4 + 3], 0.f));
        *(ushort4*)(pe + ct * 16) = nv;
      }
    }
  }
}

// ---------------- node-major segment max (CSR-streamed e0u) ----------------
__global__ __launch_bounds__(256) void k_node_agg(
    float* __restrict__ hU, const unsigned short* __restrict__ hVb,
    const unsigned short* __restrict__ e0u, const int* __restrict__ srcP,
    const unsigned* __restrict__ rowptr, float* __restrict__ stat, int Ngr) {
  __shared__ float sr[4][256];
  int tid = threadIdx.x, wid = tid >> 6, lane = tid & 63;
  int g = blockIdx.x & 7, sub = blockIdx.x >> 3, nsub = gridDim.x >> 3;
  float ps0 = 0.f, ps1 = 0.f, pq0 = 0.f, pq1 = 0.f;
  for (int nn = sub * 4 + wid; nn < Ngr; nn += nsub * 4) {
    int n = g * Ngr + nn;
    unsigned r0 = rowptr[n], r1 = rowptr[n + 1];
    float m0 = -3.4e38f, m1 = -3.4e38f;
    for (unsigned rc = r0; rc < r1; rc += 64) {
      int batch = (int)min(64u, r1 - rc);
      int myS = srcP[rc + ((lane < batch) ? lane : 0)];
      int j = 0;
      for (; j + 4 <= batch; j += 4) {
        int s0 = __shfl(myS, j, 64), s1 = __shfl(myS, j + 1, 64);
        int s2 = __shfl(myS, j + 2, 64), s3 = __shfl(myS, j + 3, 64);
        unsigned h0v = *(const unsigned*)&hVb[(size_t)s0 * DF + 2 * lane];
        unsigned h1v = *(const unsigned*)&hVb[(size_t)s1 * DF + 2 * lane];
        unsigned h2v = *(const unsigned*)&hVb[(size_t)s2 * DF + 2 * lane];
        unsigned h3v = *(const unsigned*)&hVb[(size_t)s3 * DF + 2 * lane];
        unsigned v0 = *(const unsigned*)&e0u[(size_t)(rc + j) * DF + 2 * lane];
        unsigned v1 = *(const unsigned*)&e0u[(size_t)(rc + j + 1) * DF + 2 * lane];
        unsigned v2 = *(const unsigned*)&e0u[(size_t)(rc + j + 2) * DF + 2 * lane];
        unsigned v3 = *(const unsigned*)&e0u[(size_t)(rc + j + 3) * DF + 2 * lane];
        agg_max(h0v, v0, m0, m1);
        agg_max(h1v, v1, m0, m1);
        agg_max(h2v, v2, m0, m1);
        agg_max(h3v, v3, m0, m1);
      }
      for (; j < batch; ++j) {
        int s = __shfl(myS, j, 64);
        unsigned hv = *(const unsigned*)&hVb[(size_t)s * DF + 2 * lane];
        unsigned ev = *(const unsigned*)&e0u[(size_t)(rc + j) * DF + 2 * lane];
        agg_max(hv, ev, m0, m1);
      }
    }
    if (r1 == r0) { m0 = 0.f; m1 = 0.f; }
    size_t idx = (size_t)n * DF + 2 * lane;
    float2 hu = *(float2*)&hU[idx];
    float t0 = hu.x + m0, t1 = hu.y + m1;
    hu.x = t0; hu.y = t1;
    *(float2*)&hU[idx] = hu;
    ps0 += t0; ps1 += t1;
    pq0 += t0 * t0; pq1 += t1 * t1;
  }
  sr[0][tid] = ps0; sr[1][tid] = ps1; sr[2][tid] = pq0; sr[3][tid] = pq1;
  __syncthreads();
  if (tid < 64) {
    float a0 = 0.f, a1 = 0.f, b0 = 0.f, b1 = 0.f;
#pragma unroll
    for (int w = 0; w < 4; ++w) {
      a0 += sr[0][w * 64 + tid]; a1 += sr[1][w * 64 + tid];
      b0 += sr[2][w * 64 + tid]; b1 += sr[3][w * 64 + tid];
    }
    atomicAdd(&stat[2 * tid], a0);
    atomicAdd(&stat[2 * tid + 1], a1);
    atomicAdd(&stat[128 + 2 * tid], b0);
    atomicAdd(&stat[128 + 2 * tid + 1], b1);
  }
}

// finalize BN stats
__global__ void k_bn_finalize(float* __restrict__ stat, float nN, float nE) {
  int tid = threadIdx.x;
  if (tid < 128) {
    float mean = stat[tid] / nN;
    float var = stat[128 + tid] / nN - mean * mean;
    stat[256 + tid] = mean;
    stat[384 + tid] = rsqrtf(fmaxf(var, 0.f) + 1e-5f);
  } else {
    int d = tid - 128;
    float mean = stat[512 + d] / nE;
    float var = stat[640 + d] / nE - mean * mean;
    stat[768 + d] = mean;
    stat[896 + d] = rsqrtf(fmaxf(var, 0.f) + 1e-5f);
  }
}

__global__ __launch_bounds__(256) void k_node_update(
    float* __restrict__ h0, const float* __restrict__ hU,
    const float* __restrict__ stat, long long total) {
  long long i = (long long)blockIdx.x * blockDim.x + threadIdx.x;
  long long st = (long long)gridDim.x * blockDim.x;
  for (; i < total; i += st) {
    int d = (int)(i & 127);
    float t = (hU[i] - stat[256 + d]) * stat[384 + d];
    h0[i] += fmaxf(t, 0.f);
  }
}

// ---------------- GATv2 score (permuted edge-major) ----------------
__global__ __launch_bounds__(256) void k_gat_score(
    const unsigned short* __restrict__ fsb, const unsigned short* __restrict__ fdb,
    const int* __restrict__ srcP, const int* __restrict__ dstP,
    const float* __restrict__ attn, float* __restrict__ score, int E) {
  long long i = (long long)blockIdx.x * blockDim.x + threadIdx.x;
  long long st = (long long)gridDim.x * blockDim.x;
  long long total = (long long)E * 8;
  for (; i < total; i += st) {
    int e = (int)(i >> 3), mh = (int)(i & 7);
    int s = srcP[e], dn = dstP[e];
    const unsigned short* ps = fsb + (size_t)s * DF + mh * 16;
    const unsigned short* pd = fdb + (size_t)dn * DF + mh * 16;
    const float* pa = attn + mh * 16;
    bf16x8 s0 = *(const bf16x8*)ps;
    bf16x8 s1 = *(const bf16x8*)(ps + 8);
    bf16x8 d0 = *(const bf16x8*)pd;
    bf16x8 d1 = *(const bf16x8*)(pd + 8);
    float acc = 0.f;
#pragma unroll
    for (int kk = 0; kk < 8; ++kk) {
      float z = bf2f((unsigned short)s0[kk]) + bf2f((unsigned short)d0[kk]);
      z = (z > 0.f) ? z : 0.2f * z;
      acc = fmaf(z, pa[kk], acc);
      float z2 = bf2f((unsigned short)s1[kk]) + bf2f((unsigned short)d1[kk]);
      z2 = (z2 > 0.f) ? z2 : 0.2f * z2;
      acc = fmaf(z2, pa[kk + 8], acc);
    }
    score[i] = acc;
  }
}

// ---------------- GATv2 node reduction (streamed scores) ----------------
__global__ __launch_bounds__(256) void k_gat_node(
    const float* __restrict__ score, const unsigned short* __restrict__ fsb,
    const int* __restrict__ srcP, const unsigned* __restrict__ rowptr,
    float* __restrict__ rst, int Ngr) {
  int tid = threadIdx.x, wid = tid >> 6, lane = tid & 63;
  int g = blockIdx.x & 7, sub = blockIdx.x >> 3, nsub = gridDim.x >> 3;
  int head = lane >> 3, slot = lane & 7;
  for (int nn = sub * 4 + wid; nn < Ngr; nn += nsub * 4) {
    int n = g * Ngr + nn;
    unsigned r0 = rowptr[n], r1 = rowptr[n + 1];
    float hm = -3.4e38f;
    for (unsigned r = r0 + slot; r < r1; r += 8)
      hm = fmaxf(hm, score[(size_t)r * 8 + head]);
#pragma unroll
    for (int mk = 1; mk < 8; mk <<= 1) hm = fmaxf(hm, __shfl_xor(hm, mk, 64));
    float dn = 0.f;
    for (unsigned r = r0 + slot; r < r1; r += 8)
      dn += __expf(score[(size_t)r * 8 + head] - hm);
#pragma unroll
    for (int mk = 1; mk < 8; mk <<= 1) dn += __shfl_xor(dn, mk, 64);
    float inv = (r1 > r0) ? 1.f / dn : 0.f;
    float a0 = 0.f, a1 = 0.f;
    for (unsigned rc = r0; rc < r1; rc += 64) {
      int batch = (int)min(64u, r1 - rc);
      int myS = srcP[rc + ((lane < batch) ? lane : 0)];
      int j = 0;
      for (; j + 4 <= batch; j += 4) {
        int s0 = __shfl(myS, j, 64), s1 = __shfl(myS, j + 1, 64);
        int s2 = __shfl(myS, j + 2, 64), s3 = __shfl(myS, j + 3, 64);
        float sc0 = score[(size_t)(rc + j) * 8 + head];
        float sc1 = score[(size_t)(rc + j + 1) * 8 + head];
        float sc2 = score[(size_t)(rc + j + 2) * 8 + head];
        float sc3 = score[(size_t)(rc + j + 3) * 8 + head];
        unsigned f0 = *(const unsigned*)&fsb[(size_t)s0 * DF + 2 * lane];
        unsigned f1 = *(const unsigned*)&fsb[(size_t)s1 * DF + 2 * lane];
        unsigned f2 = *(const unsigned*)&fsb[(size_t)s2 * DF + 2 * lane];
        unsigned f3 = *(const unsigned*)&fsb[(size_t)s3 * DF + 2 * lane];
        float w0 = __expf(sc0 - hm) * inv, w1 = __expf(sc1 - hm) * inv;
        float w2 = __expf(sc2 - hm) * inv, w3 = __expf(sc3 - hm) * inv;
        a0 = fmaf(w0, bflo(f0), a0); a1 = fmaf(w0, bfhi(f0), a1);
        a0 = fmaf(w1, bflo(f1), a0); a1 = fmaf(w1, bfhi(f1), a1);
        a0 = fmaf(w2, bflo(f2), a0); a1 = fmaf(w2, bfhi(f2), a1);
        a0 = fmaf(w3, bflo(f3), a0); a1 = fmaf(w3, bfhi(f3), a1);
      }
      for (; j < batch; ++j) {
        int s = __shfl(myS, j, 64);
        float w = __expf(score[(size_t)(rc + j) * 8 + head] - hm) * inv;
        unsigned fv = *(const unsigned*)&fsb[(size_t)s * DF + 2 * lane];
        a0 = fmaf(w, bflo(fv), a0);
        a1 = fmaf(w, bfhi(fv), a1);
      }
    }
    float2 o;
    o.x = a0; o.y = a1;
    *(float2*)&rst[(size_t)n * DF + 2 * lane] = o;
  }
}

// bias2 = O_b + gat_bias @ O_w^T
__global__ void k_bias2(const float* __restrict__ gat_bias,
                        const float* __restrict__ O_w,
                        const float* __restrict__ O_b, float* __restrict__ bias2) {
  int d = threadIdx.x;
  float acc = O_b[d];
  for (int k = 0; k < DF; ++k) acc = fmaf(gat_bias[k], O_w[(size_t)d * DF + k], acc);
  bias2[d] = acc;
}

// ---------------- readout ----------------
__global__ __launch_bounds__(128) void k_moy(
    const unsigned short* __restrict__ h2b, const int* __restrict__ ng,
    float* __restrict__ moy, float* __restrict__ cnt, int rows) {
  int tid = threadIdx.x;
  int per = (rows + gridDim.x - 1) / gridDim.x;
  int n0 = blockIdx.x * per;
  int n1 = min(rows, n0 + per);
  if (n0 >= n1) return;
  int cur = ng[n0];
  float acc = 0.f; int c = 0;
  for (int n = n0; n < n1; ++n) {
    int g = ng[n];
    if (g != cur) {
      atomicAdd(&moy[cur * DF + tid], acc);
      if (tid == 0) atomicAdd(&cnt[cur], (float)c);
      acc = 0.f; c = 0; cur = g;
    }
    acc += bf2f(h2b[(size_t)n * DF + tid]);
    ++c;
  }
  atomicAdd(&moy[cur * DF + tid], acc);
  if (tid == 0) atomicAdd(&cnt[cur], (float)c);
}

// P0[g] = W1[:,0:128] @ (moy_sum[g]/cnt[g]) + W1_b
__global__ void k_p0(const float* __restrict__ W1, const float* __restrict__ W1b_,
                     const float* __restrict__ moy, const float* __restrict__ cnt,
                     float* __restrict__ P0) {
  int g = blockIdx.x, d = threadIdx.x;
  float inv = 1.f / cnt[g];
  float acc = W1b_[d];
  for (int k = 0; k < DF; ++k) acc = fmaf(W1[(size_t)d * 384 + k], moy[g * DF + k] * inv, acc);
  P0[g * DF + d] = acc;
}

// ---------------- CSR head (permuted; out scatter via eidb) ----------------
__global__ __launch_bounds__(256) void k_head(
    const unsigned short* __restrict__ P1b, const unsigned short* __restrict__ P2b,
    const float* __restrict__ P0, const int* __restrict__ srcP,
    const unsigned* __restrict__ rowptr, const int* __restrict__ eidb,
    const float* __restrict__ W2, const float* __restrict__ W2b,
    float* __restrict__ out, int Ngr) {
  int tid = threadIdx.x, wid = tid >> 6, lane = tid & 63;
  int g = blockIdx.x & 7, sub = blockIdx.x >> 3, nsub = gridDim.x >> 3;
  float w2b = W2b[0];
  float w20 = W2[2 * lane], w21 = W2[2 * lane + 1];
  float b0 = P0[g * DF + 2 * lane], b1v = P0[g * DF + 2 * lane + 1];
  for (int nn = sub * 4 + wid; nn < Ngr; nn += nsub * 4) {
    int n = g * Ngr + nn;
    unsigned r0 = rowptr[n], r1 = rowptr[n + 1];
    if (r1 == r0) continue;
    unsigned p2 = *(const unsigned*)&P2b[(size_t)n * DF + 2 * lane];
    float base0 = b0 + bflo(p2);
    float base1 = b1v + bfhi(p2);
    for (unsigned rc = r0; rc < r1; rc += 64) {
      int cnt2 = (int)min(64u, r1 - rc);
      int myE = eidb[rc + ((lane < cnt2) ? lane : 0)];
      int myS = srcP[rc + ((lane < cnt2) ? lane : 0)];
      int j = 0;
      for (; j + 4 <= cnt2; j += 4) {
        int e0 = __shfl(myE, j, 64), e1 = __shfl(myE, j + 1, 64);
        int e2 = __shfl(myE, j + 2, 64), e3 = __shfl(myE, j + 3, 64);
        int s0 = __shfl(myS, j, 64), s1 = __shfl(myS, j + 1, 64);
        int s2 = __shfl(myS, j + 2, 64), s3 = __shfl(myS, j + 3, 64);
        unsigned u0 = *(const unsigned*)&P1b[(size_t)s0 * DF + 2 * lane];
        unsigned u1 = *(const unsigned*)&P1b[(size_t)s1 * DF + 2 * lane];
        unsigned u2 = *(const unsigned*)&P1b[(size_t)s2 * DF + 2 * lane];
        unsigned u3 = *(const unsigned*)&P1b[(size_t)s3 * DF + 2 * lane];
        float v0 = fmaxf(base0 + bflo(u0), 0.f) * w20 + fmaxf(base1 + bfhi(u0), 0.f) * w21;
        float v1 = fmaxf(base0 + bflo(u1), 0.f) * w20 + fmaxf(base1 + bfhi(u1), 0.f) * w21;
        float v2 = fmaxf(base0 + bflo(u2), 0.f) * w20 + fmaxf(base1 + bfhi(u2), 0.f) * w21;
        float v3 = fmaxf(base0 + bflo(u3), 0.f) * w20 + fmaxf(base1 + bfhi(u3), 0.f) * w21;
#pragma unroll
        for (int mk = 1; mk < 64; mk <<= 1) {
          v0 += __shfl_xor(v0, mk, 64);
          v1 += __shfl_xor(v1, mk, 64);
          v2 += __shfl_xor(v2, mk, 64);
          v3 += __shfl_xor(v3, mk, 64);
        }
        if (lane == 0) {
          out[e0] = sigm(v0 + w2b);
          out[e1] = sigm(v1 + w2b);
          out[e2] = sigm(v2 + w2b);
          out[e3] = sigm(v3 + w2b);
        }
      }
      for (; j < cnt2; ++j) {
        int e = __shfl(myE, j, 64);
        int s = __shfl(myS, j, 64);
        unsigned p1 = *(const unsigned*)&P1b[(size_t)s * DF + 2 * lane];
        float v = fmaxf(base0 + bflo(p1), 0.f) * w20 + fmaxf(base1 + bfhi(p1), 0.f) * w21;
#pragma unroll
        for (int mk = 1; mk < 64; mk <<= 1) v += __shfl_xor(v, mk, 64);
        if (lane == 0) out[e] = sigm(v + w2b);
      }
    }
  }
}

extern "C" void kernel_launch(void* const* d_in, const int* in_sizes, int n_in,
                              void* d_out, int out_size, void* d_ws, size_t ws_size,
                              hipStream_t stream) {
  const float* h_in = (const float*)d_in[0];
  const float* e_in = (const float*)d_in[1];
  const int* src = (const int*)d_in[2];
  const int* dst = (const int*)d_in[3];
  const int* node_graph = (const int*)d_in[4];
  const float* emb_n_w = (const float*)d_in[6];
  const float* emb_n_b = (const float*)d_in[7];
  const float* emb_e_w = (const float*)d_in[8];
  const float* emb_e_b = (const float*)d_in[9];
  const float* Us = (const float*)d_in[10];
  const float* Vs = (const float*)d_in[11];
  const float* As = (const float*)d_in[12];
  const float* Bs = (const float*)d_in[13];
  const float* Cs = (const float*)d_in[14];
  const float* gat_src_w = (const float*)d_in[15];
  const float* gat_src_b = (const float*)d_in[16];
  const float* gat_dst_w = (const float*)d_in[17];
  const float* gat_dst_b = (const float*)d_in[18];
  const float* gat_attn = (const float*)d_in[19];
  const float* gat_bias = (const float*)d_in[20];
  const float* O_w = (const float*)d_in[21];
  const float* O_b = (const float*)d_in[22];
  const float* W1_w = (const float*)d_in[23];
  const float* W1_b = (const float*)d_in[24];
  const float* W2_w = (const float*)d_in[25];
  const float* W2_b = (const float*)d_in[26];
  float* out = (float*)d_out;

  const int N = in_sizes[0] / 64;   // 30000
  const int E = in_sizes[1] / 16;   // 360000
  const int Eg = E / NGRAPH;        // 45000
  const int Ngr = N / NGRAPH;       // 3750

  auto rnd = [](size_t b) { return (b + 255) & ~(size_t)255; };
  const size_t sz_e0 = rnd((size_t)E * DF * 2);
  const size_t sz_node = rnd((size_t)N * DF * 4);
  const size_t sz_nodeb = rnd((size_t)N * DF * 2);
  const size_t sz_score = rnd((size_t)E * 8 * 4);
  const size_t sz_wfrag = rnd(20 * 2048 * 8 * 2);
  const size_t sz_rp = rnd((size_t)(N + 1) * 4);
  const size_t sz_eid = rnd((size_t)E * 4);
  const size_t sz_misc = rnd(4096 * 4);
  const size_t needed = sz_e0 + 3 * sz_node + 4 * sz_nodeb + sz_score + sz_wfrag +
                        3 * sz_rp + 3 * sz_eid + sz_misc;
  if (ws_size < needed) {
    k_fill_u32<<<256, 256, 0, stream>>>((unsigned*)out, 0xBF800000u, (long long)out_size);
    return;
  }

  char* wp = (char*)d_ws;
  auto alloc = [&](size_t bytes) { void* p = wp; wp += bytes; return p; };
  unsigned short* e0u = (unsigned short*)alloc(sz_e0);
  float* h0 = (float*)alloc(sz_node);
  float* hU = (float*)alloc(sz_node);
  float* rst = (float*)alloc(sz_node);
  unsigned short* hVb = (unsigned short*)alloc(sz_nodeb);
  unsigned short* hBb = (unsigned short*)alloc(sz_nodeb);
  unsigned short* hCb = (unsigned short*)alloc(sz_nodeb);
  unsigned short* h2b = (unsigned short*)alloc(sz_nodeb);
  float* score = (float*)alloc(sz_score);
  short* wfrag = (short*)alloc(sz_wfrag);
  unsigned* rowptr = (unsigned*)alloc(sz_rp);
  unsigned* cursor = (unsigned*)alloc(sz_rp);
  unsigned* deg = (unsigned*)alloc(sz_rp);
  int* eidb = (int*)alloc(sz_eid);
  int* srcP = (int*)alloc(sz_eid);
  int* dstP = (int*)alloc(sz_eid);
  float* misc = (float*)alloc(sz_misc);
  float* stat = misc;                                     // [0,1024)
  float* bias2 = misc + 1024;                             // [1024,1152)
  float* moy = misc + 1152;                               // [1152,2176)
  float* cnt = misc + 2176;                               // [2176,2184)
  float* P0 = misc + 2304;                                // [2304,3328)
  unsigned short* P1b = e0u;  // alias: e0u dead after last layer
  unsigned short* P2b = e0u + (size_t)N * DF;

  auto WF = [&](int idx) { return wfrag + (size_t)idx * 2048 * 8; };

  // CSR build + permuted indices
  k_fill_u32<<<64, 256, 0, stream>>>(deg, 0u, N);
  k_deg<<<512, 256, 0, stream>>>(dst, deg, E);
  k_scan<<<1, 1024, 0, stream>>>(deg, rowptr, cursor, N);
  k_scatter<<<512, 256, 0, stream>>>(dst, cursor, eidb, E);
  k_permidx<<<512, 256, 0, stream>>>(eidb, src, dst, srcP, dstP, E);

  k_wconv<<<20, 512, 0, stream>>>(Us, Vs, As, Bs, Cs, gat_src_w, gat_dst_w, O_w,
                                  W1_w, wfrag);

  const int gN = (N + 127) / 128;
  k_node_embed<<<2048, 128, 0, stream>>>(h_in, emb_n_w, emb_n_b, h0, N);
  k_edge_embed<<<4096, 128, 0, stream>>>(e_in, eidb, emb_e_w, emb_e_b, e0u, E);

  for (int l = 0; l < 3; ++l) {
    k_gemm4_mfma<<<gN, 512, 0, stream>>>(h0, WF(3 + l), WF(l), WF(9 + l), WF(12 + l),
                                         hVb, hU, hBb, hCb, N);
    k_fill_u32<<<4, 256, 0, stream>>>((unsigned*)stat, 0u, 1024);
    k_node_agg<<<2048, 256, 0, stream>>>(hU, hVb, e0u, srcP, rowptr, stat, Ngr);
    k_edge_xs<<<1024, 512, 0, stream>>>(e0u, WF(6 + l), hBb, hCb, srcP, dstP, stat, Eg);
    k_bn_finalize<<<1, 256, 0, stream>>>(stat, (float)N, (float)E);
    k_node_update<<<2048, 256, 0, stream>>>(h0, hU, stat, (long long)N * DF);
    k_edge_xa<<<1024, 512, 0, stream>>>(e0u, WF(6 + l), hBb, hCb, srcP, dstP, stat, Eg);
  }

  // GATv2: fs -> hVb, fd -> hBb
  k_gemm_mfma<1><<<gN, 512, 0, stream>>>(h0, WF(15), gat_src_b, hVb, N);
  k_gemm_mfma<1><<<gN, 512, 0, stream>>>(h0, WF(16), gat_dst_b, hBb, N);
  k_gat_score<<<2048, 256, 0, stream>>>(hVb, hBb, srcP, dstP, gat_attn, score, E);
  k_gat_node<<<2048, 256, 0, stream>>>(score, hVb, srcP, rowptr, rst, Ngr);
  k_bias2<<<1, 128, 0, stream>>>(gat_bias, O_w, O_b, bias2);
  k_gemm_mfma<1><<<gN, 512, 0, stream>>>(rst, WF(17), bias2, h2b, N);  // h2

  // readout + decomposed head
  k_fill_u32<<<2, 256, 0, stream>>>((unsigned*)moy, 0u, 1032);
  k_moy<<<128, 128, 0, stream>>>(h2b, node_graph, moy, cnt, N);
  k_p0<<<8, 128, 0, stream>>>(W1_w, W1_b, moy, cnt, P0);
  k_gemmb_mfma<<<gN, 512, 0, stream>>>(h2b, WF(18), P1b, N);
  k_gemmb_mfma<<<gN, 512, 0, stream>>>(h2b, WF(19), P2b, N);
  k_head<<<2048, 256, 0, stream>>>(P1b, P2b, P0, srcP, rowptr, eidb, W2_w, W2_b,
                                   out, Ngr);
}